// Round 9
// baseline (321.700 us; speedup 1.0000x reference)
//
#include <hip/hip_runtime.h>

typedef float f32x4 __attribute__((ext_vector_type(4)));
typedef short s16x8 __attribute__((ext_vector_type(8)));
typedef short s16x4 __attribute__((ext_vector_type(4)));

#define NN 4096
#define NB 32
#define DIN 64
#define DH 128
#define DOUT 32
#define DIM 40
#define KADJ 512   // 6 split-blocks x 80, zero-padded to 512

__device__ __forceinline__ unsigned short f2bf(float f) {
    unsigned int u = __float_as_uint(f);
    unsigned int r = (u + 0x7FFFu + ((u >> 16) & 1u)) >> 16;
    return (unsigned short)r;
}
__device__ __forceinline__ float bf2f(unsigned short h) {
    return __uint_as_float(((unsigned int)h) << 16);
}
__device__ __forceinline__ void gload16(const void* g, void* l) {
    __builtin_amdgcn_global_load_lds(
        (const __attribute__((address_space(1))) unsigned int*)g,
        (__attribute__((address_space(3))) unsigned int*)l, 16, 0, 0);
}
__device__ __forceinline__ void bar() {
    asm volatile("" ::: "memory");
    __builtin_amdgcn_s_barrier();
    asm volatile("" ::: "memory");
}

// ---------------- stage 1: n1/n2 = tanh(3*(emb @ W + b)) ----------------
__global__ __launch_bounds__(256) void k_embed(
    const float* __restrict__ emb1, const float* __restrict__ emb2,
    const float* __restrict__ l1w, const float* __restrict__ l1b,
    const float* __restrict__ l2w, const float* __restrict__ l2b,
    float* __restrict__ n1, float* __restrict__ n2)
{
    __shared__ float w1s[DIM * DIM], w2s[DIM * DIM], b1s[DIM], b2s[DIM];
    int tid = threadIdx.x;
    for (int i = tid; i < DIM * DIM; i += 256) { w1s[i] = l1w[i]; w2s[i] = l2w[i]; }
    if (tid < DIM) { b1s[tid] = l1b[tid]; b2s[tid] = l2b[tid]; }
    __syncthreads();
    int t = blockIdx.x * 256 + tid;          // < 2*4096*40 = 327680
    int half = t >= NN * DIM;
    int r = t - half * (NN * DIM);
    int i = r / DIM, c = r - i * DIM;
    const float* emb = half ? emb2 : emb1;
    const float* ws  = half ? w2s : w1s;
    float acc = half ? b2s[c] : b1s[c];
    for (int k = 0; k < DIM; k++) acc += emb[i * DIM + k] * ws[k * DIM + c];
    (half ? n2 : n1)[r] = tanhf(3.0f * acc);
}

// ---------------- stage 2a: build split operands for the adjacency GEMM ----------------
__global__ __launch_bounds__(256) void k_build_uv(
    const float* __restrict__ n1, const float* __restrict__ n2,
    unsigned short* __restrict__ Ux, unsigned short* __restrict__ Vx)
{
    __shared__ unsigned short Ul[16][KADJ], Vl[16][KADJ];
    const int tid = threadIdx.x;
    const int r = tid >> 4;                 // local node 0..15
    const int node = blockIdx.x * 16 + r;
    const int k0 = (tid & 15) * 5;          // 5 k's per thread (80 total)
    const int PMAP[6] = {0, 0, 1, 1, 0, 2};
    const int QMAP[6] = {0, 1, 0, 1, 2, 0};
    #pragma unroll
    for (int e = 0; e < 5; e++) {
        int k = k0 + e;
        float a = (k < DIM) ? n1[node * DIM + k] : -n2[node * DIM + k - DIM];
        float b = (k < DIM) ? n2[node * DIM + k] : n1[node * DIM + k - DIM];
        unsigned short u0 = f2bf(a); float ra = a - bf2f(u0);
        unsigned short u1 = f2bf(ra); ra -= bf2f(u1);
        unsigned short u2 = f2bf(ra);
        unsigned short v0 = f2bf(b); float rb = b - bf2f(v0);
        unsigned short v1 = f2bf(rb); rb -= bf2f(v1);
        unsigned short v2 = f2bf(rb);
        unsigned short uu[3] = {u0, u1, u2}, vv[3] = {v0, v1, v2};
        #pragma unroll
        for (int bq = 0; bq < 6; bq++) {
            Ul[r][80 * bq + k] = uu[PMAP[bq]];
            Vl[r][80 * bq + k] = vv[QMAP[bq]];
        }
    }
    {   // zero-pad 480..511
        int c = tid & 15;
        Ul[r][480 + c * 2]     = 0; Vl[r][480 + c * 2]     = 0;
        Ul[r][480 + c * 2 + 1] = 0; Vl[r][480 + c * 2 + 1] = 0;
    }
    __syncthreads();
    #pragma unroll
    for (int q = 0; q < 4; q++) {           // 16*512/8 = 1024 chunks
        int idx = q * 256 + tid;
        int rr = idx >> 6, c8 = idx & 63;
        size_t off = ((size_t)(blockIdx.x * 16 + rr)) * KADJ + c8 * 8;
        *(s16x8*)(Ux + off) = *(s16x8*)&Ul[rr][c8 * 8];
        *(s16x8*)(Vx + off) = *(s16x8*)&Vl[rr][c8 * 8];
    }
}

// ---------------- stage 2b: adjacency GEMM -> MT bits (bf16) + deg ----------------
__global__ __launch_bounds__(256) void gemm_adj(
    const unsigned short* __restrict__ V, const unsigned short* __restrict__ U,
    unsigned short* __restrict__ MT, int* __restrict__ deg)
{
    constexpr int K = KADJ;
    constexpr int BK = 64;
    __shared__ __align__(16) unsigned short Asm[128 * BK];
    __shared__ __align__(16) unsigned short Bsm[128 * BK];
    const int tid = threadIdx.x;
    const int lane = tid & 63;
    const int w = tid >> 6;
    const int wm = w >> 1, wn = w & 1;
    const int c0 = blockIdx.x * 128;   // i (cols)
    const int j0 = blockIdx.y * 128;   // j (rows)

    int srcOff[4];
    #pragma unroll
    for (int q = 0; q < 4; q++) {
        int cid = w * 256 + q * 64 + lane;
        int row = cid >> 3, kc = cid & 7;
        srcOff[q] = row * K + ((kc ^ (row & 7)) << 3);
    }
    const int fr = lane & 15;
    const int kg = lane >> 4;

    f32x4 acc[4][4] = {};
    const unsigned short* Abase = V + (size_t)j0 * K;
    const unsigned short* Bbase = U + (size_t)c0 * K;

    for (int kt = 0; kt < K; kt += BK) {
        __syncthreads();
        const unsigned short* Ag = Abase + kt;
        const unsigned short* Bg = Bbase + kt;
        #pragma unroll
        for (int q = 0; q < 4; q++)
            gload16(Ag + srcOff[q], &Asm[(w * 256 + q * 64) * 8]);
        #pragma unroll
        for (int q = 0; q < 4; q++)
            gload16(Bg + srcOff[q], &Bsm[(w * 256 + q * 64) * 8]);
        __syncthreads();

        s16x8 af[2][4], bf[2][4];
        #pragma unroll
        for (int ks = 0; ks < 2; ks++) {
            int kc = ks * 4 + kg;
            #pragma unroll
            for (int m = 0; m < 4; m++) {
                int row = wm * 64 + m * 16 + fr;
                af[ks][m] = *(const s16x8*)((const char*)Asm + row * 128 + ((kc ^ (row & 7)) << 4));
            }
            #pragma unroll
            for (int n = 0; n < 4; n++) {
                int row = wn * 64 + n * 16 + fr;
                bf[ks][n] = *(const s16x8*)((const char*)Bsm + row * 128 + ((kc ^ (row & 7)) << 4));
            }
        }
        #pragma unroll
        for (int ks = 0; ks < 2; ks++)
            #pragma unroll
            for (int m = 0; m < 4; m++)
                #pragma unroll
                for (int n = 0; n < 4; n++)
                    acc[m][n] = __builtin_amdgcn_mfma_f32_16x16x32_bf16(
                        af[ks][m], bf[ks][n], acc[m][n], 0, 0, 0);
    }

    // epilogue: bits + degree
    #pragma unroll
    for (int m = 0; m < 4; m++) {
        int rbase = j0 + wm * 64 + m * 16 + kg * 4;
        #pragma unroll
        for (int r = 0; r < 4; r++) {
            int row = rbase + r;
            int cnt = 0;
            #pragma unroll
            for (int n = 0; n < 4; n++) {
                int col = c0 + wn * 64 + n * 16 + fr;
                bool bit = (acc[m][n][r] > 0.f) || (row == col);
                MT[(size_t)row * NN + col] = bit ? (unsigned short)0x3F80 : (unsigned short)0;
                cnt += bit ? 1 : 0;
            }
            cnt += __shfl_xor(cnt, 1);
            cnt += __shfl_xor(cnt, 2);
            cnt += __shfl_xor(cnt, 4);
            cnt += __shfl_xor(cnt, 8);
            if (fr == 0) atomicAdd(&deg[row], cnt);
        }
    }
}

__global__ void k_dinv(const int* __restrict__ deg, float* __restrict__ dinv) {
    int i = blockIdx.x * 256 + threadIdx.x;
    if (i < NN) dinv[i] = 1.0f / sqrtf((float)deg[i]);
}

// ---------------- YT[c=b*128+f][i] = bf16( dinv_i * (x[b,i,:] @ W1[:,f]) ) ----------------
__global__ __launch_bounds__(256) void k_y1(
    const float* __restrict__ x, const float* __restrict__ W1,
    const float* __restrict__ dinv, unsigned short* __restrict__ YT)
{
    __shared__ __align__(16) float xs[128][DIN];
    __shared__ __align__(16) float w1s[DIN][DH];
    int i0 = blockIdx.x * 128, b = blockIdx.y;
    int tid = threadIdx.x;
    const f32x4* xg = (const f32x4*)(x + ((size_t)(b * NN + i0)) * DIN);
    #pragma unroll
    for (int q = 0; q < 8; q++) {
        int idx = q * 256 + tid;
        int row = idx >> 4, c4 = idx & 15;
        *(f32x4*)&xs[row][c4 * 4] = xg[(size_t)row * 16 + c4];
    }
    #pragma unroll
    for (int q = 0; q < 8; q++) {
        int idx = q * 256 + tid;
        int row = idx >> 5, c4 = idx & 31;
        *(f32x4*)&w1s[row][c4 * 4] = ((const f32x4*)W1)[idx];
    }
    __syncthreads();
    int tf = tid & 15, ti = tid >> 4;
    f32x4 t0[8] = {}, t1[8] = {};
    for (int k4 = 0; k4 < DIN; k4 += 4) {
        f32x4 xv[8];
        #pragma unroll
        for (int ii = 0; ii < 8; ii++) xv[ii] = *(const f32x4*)&xs[ti * 8 + ii][k4];
        #pragma unroll
        for (int kk = 0; kk < 4; kk++) {
            f32x4 w0 = *(const f32x4*)&w1s[k4 + kk][tf * 8];
            f32x4 w1v = *(const f32x4*)&w1s[k4 + kk][tf * 8 + 4];
            #pragma unroll
            for (int ii = 0; ii < 8; ii++) {
                float s = xv[ii][kk];
                t0[ii] += s * w0;
                t1[ii] += s * w1v;
            }
        }
    }
    float dvv[8];
    #pragma unroll
    for (int ii = 0; ii < 8; ii++) dvv[ii] = dinv[i0 + ti * 8 + ii];
    #pragma unroll
    for (int ff = 0; ff < 8; ff++) {
        s16x8 pk;
        #pragma unroll
        for (int ii = 0; ii < 8; ii++) {
            float v = (ff < 4 ? t0[ii][ff] : t1[ii][ff - 4]) * dvv[ii];
            pk[ii] = (short)f2bf(v);
        }
        *(s16x8*)(YT + ((size_t)(b * DH + tf * 8 + ff)) * NN + i0 + ti * 8) = pk;
    }
}

// ======== gemm1: 256x256 tile, BK=64, FOUR waves of 128x128 (1 wave/SIMD) ========
// LDS reads per K-tile per CU: 4 waves x 32 b128 = 128 (vs 192 with 8x(128x64)).
// 2 phases/K-tile: A: read ks1 frags + MFMA ks0 (carried); lgkmcnt(0)+BAR(i);
//                  B: stage t+2->P + vmcnt(16) [= tile t+1 landed] + BAR(ii);
//                     read-ahead t+1 ks0 frags from P^1; MFMA ks1.
__global__ __launch_bounds__(256, 1) void gemm4w(
    const unsigned short* __restrict__ A, const unsigned short* __restrict__ Bt,
    unsigned short* __restrict__ H, const float* __restrict__ dinv,
    const float* __restrict__ bias)
{
    constexpr int K = NN;          // 4096
    constexpr int NT = K / 64;     // 64 K-tiles
    __shared__ __align__(16) unsigned short As[2][256 * 64];   // 64 KB
    __shared__ __align__(16) unsigned short Bs[2][256 * 64];   // 64 KB

    const int tid = threadIdx.x;
    const int lane = tid & 63;
    const int w = tid >> 6;                 // wave 0..3
    const int wm = w >> 1, wn = w & 1;      // 2 x 2 wave grid, tile 128x128
    const int fr = lane & 15, kg = lane >> 4;

    const int bid = blockIdx.x;             // 256 blocks -> XCD swizzle
    const int swz = (bid & 7) * 32 + (bid >> 3);
    const int bx = swz & 15, by = swz >> 4;
    const int c0 = bx * 256, j0 = by * 256;

    // staging: 2048 chunks of 16B per operand tile; 8 gload16/thread each
    int srcOff[8];
    #pragma unroll
    for (int q = 0; q < 8; q++) {
        int cid = q * 256 + tid;
        int row = cid >> 3, kc = cid & 7;
        srcOff[q] = row * K + ((kc ^ (row & 7)) << 3);   // ushort units
    }
    const unsigned short* Aj = A + (size_t)j0 * K;
    const unsigned short* Bc = Bt + (size_t)c0 * K;

#define STAGE(buf, kt) do { \
    _Pragma("unroll") \
    for (int q = 0; q < 8; q++) \
        gload16(Aj + (kt) + srcOff[q], &As[buf][(q * 256 + tid) * 8]); \
    _Pragma("unroll") \
    for (int q = 0; q < 8; q++) \
        gload16(Bc + (kt) + srcOff[q], &Bs[buf][(q * 256 + tid) * 8]); } while (0)

    // prologue: tile0 (16 loads) + tile1 (16 loads); drain tile0
    STAGE(0, 0);
    STAGE(1, 64);
    asm volatile("s_waitcnt vmcnt(16)" ::: "memory");
    bar();

    const int x0 = ((kg) ^ (fr & 7)) << 4;        // ks0 chunk, bytes
    const int x1 = ((4 + kg) ^ (fr & 7)) << 4;    // ks1 chunk, bytes
    int aOff[8], bOff[8];
    #pragma unroll
    for (int m = 0; m < 8; m++) aOff[m] = (wm * 128 + m * 16 + fr) * 128;
    #pragma unroll
    for (int n = 0; n < 8; n++) bOff[n] = (wn * 128 + n * 16 + fr) * 128;

    s16x8 af0[8], bf0[8], af1[8], bf1[8];
    #pragma unroll
    for (int m = 0; m < 8; m++) af0[m] = *(const s16x8*)((const char*)As[0] + aOff[m] + x0);
    #pragma unroll
    for (int n = 0; n < 8; n++) bf0[n] = *(const s16x8*)((const char*)Bs[0] + bOff[n] + x0);

    f32x4 acc[8][8] = {};   // 256 VGPR

    for (int t = 0; t < NT; t++) {
        const int P = t & 1;
        const char* Ap = (const char*)As[P];
        const char* Bp = (const char*)Bs[P];
        const char* Aq = (const char*)As[P ^ 1];
        const char* Bq = (const char*)Bs[P ^ 1];
        const bool s1 = (t + 1) < NT, s2 = (t + 2) < NT;

        // ---- phase A: read ks1 frags (16); MFMA ks0 on carried frags (64)
        #pragma unroll
        for (int m = 0; m < 8; m++) af1[m] = *(const s16x8*)(Ap + aOff[m] + x1);
        #pragma unroll
        for (int n = 0; n < 8; n++) bf1[n] = *(const s16x8*)(Bp + bOff[n] + x1);
        #pragma unroll
        for (int m = 0; m < 8; m++)
            #pragma unroll
            for (int n = 0; n < 8; n++)
                acc[m][n] = __builtin_amdgcn_mfma_f32_16x16x32_bf16(af0[m], bf0[n], acc[m][n], 0, 0, 0);
        asm volatile("s_waitcnt lgkmcnt(0)" ::: "memory");
        bar();                                   // BAR(i): all P-reads serviced

        // ---- phase B: stage t+2 -> P; counted vmcnt; BAR(ii); read-ahead; MFMA ks1
        if (s2) {
            STAGE(P, (t + 2) * 64);
            asm volatile("s_waitcnt vmcnt(16)" ::: "memory");   // tile t+1 fully landed
        } else {
            asm volatile("s_waitcnt vmcnt(0)" ::: "memory");
        }
        bar();                                   // BAR(ii): cross-wave visibility
        if (s1) {
            #pragma unroll
            for (int m = 0; m < 8; m++) af0[m] = *(const s16x8*)(Aq + aOff[m] + x0);
            #pragma unroll
            for (int n = 0; n < 8; n++) bf0[n] = *(const s16x8*)(Bq + bOff[n] + x0);
        }
        #pragma unroll
        for (int m = 0; m < 8; m++)
            #pragma unroll
            for (int n = 0; n < 8; n++)
                acc[m][n] = __builtin_amdgcn_mfma_f32_16x16x32_bf16(af1[m], bf1[n], acc[m][n], 0, 0, 0);
    }
#undef STAGE

    // epilogue: row = (lane>>4)*4 + r, col = lane&15 per 16x16 frag
    #pragma unroll
    for (int m = 0; m < 8; m++) {
        int rbase = j0 + wm * 128 + m * 16 + kg * 4;
        float dv[4];
        #pragma unroll
        for (int r = 0; r < 4; r++) dv[r] = dinv[rbase + r];
        #pragma unroll
        for (int n = 0; n < 8; n++) {
            int gcol = c0 + wn * 128 + n * 16 + fr;
            float bb = bias[gcol & (DH - 1)];
            #pragma unroll
            for (int r = 0; r < 4; r++) {
                float v = acc[m][n][r] * dv[r] + bb;
                v = v > 0.f ? v : 0.f;
                H[(size_t)(rbase + r) * NN + gcol] = f2bf(v);
            }
        }
    }
}

// ---------- k_z2: MFMA-based ZT = dinv_j * (H_b @ W2), per block: 128 j x one batch ----------
__global__ __launch_bounds__(256) void k_z2(
    const unsigned short* __restrict__ H, const float* __restrict__ W2,
    const float* __restrict__ dinv, unsigned short* __restrict__ ZT)
{
    __shared__ __align__(16) unsigned short Hs[128 * DH];     // 32 KB, [j][f] linear
    __shared__ __align__(16) unsigned short W2Ts[DOUT * DH];  // 8 KB, [g][f]
    const int tid = threadIdx.x;
    const int j0 = blockIdx.x * 128, b = blockIdx.y;
    const unsigned short* Hb = H + (size_t)j0 * NN + b * DH;

    #pragma unroll
    for (int q = 0; q < 8; q++) {
        int cid = q * 256 + tid;
        int row = cid >> 4, kc = cid & 15;
        gload16(Hb + (size_t)row * NN + kc * 8, &Hs[cid * 8]);
    }
    #pragma unroll
    for (int q = 0; q < 16; q++) {
        int idx = q * 256 + tid;
        int f = idx >> 5, g = idx & 31;
        W2Ts[g * DH + f] = f2bf(W2[f * DOUT + g]);
    }
    __syncthreads();

    const int lane = tid & 63, w = tid >> 6;
    const int fr = lane & 15, kg = lane >> 4;
    f32x4 acc[2][2] = {};
    #pragma unroll
    for (int ks = 0; ks < 4; ks++) {
        s16x8 af[2], bf[2];
        #pragma unroll
        for (int mt = 0; mt < 2; mt++) {
            int row = w * 32 + mt * 16 + fr;
            af[mt] = *(const s16x8*)&Hs[row * DH + ks * 32 + kg * 8];
        }
        #pragma unroll
        for (int nt = 0; nt < 2; nt++) {
            int g = nt * 16 + fr;
            bf[nt] = *(const s16x8*)&W2Ts[g * DH + ks * 32 + kg * 8];
        }
        #pragma unroll
        for (int mt = 0; mt < 2; mt++)
            #pragma unroll
            for (int nt = 0; nt < 2; nt++)
                acc[mt][nt] = __builtin_amdgcn_mfma_f32_16x16x32_bf16(af[mt], bf[nt], acc[mt][nt], 0, 0, 0);
    }
    #pragma unroll
    for (int mt = 0; mt < 2; mt++) {
        int jbase = j0 + w * 32 + mt * 16 + kg * 4;
        float dv[4];
        #pragma unroll
        for (int r = 0; r < 4; r++) dv[r] = dinv[jbase + r];
        #pragma unroll
        for (int nt = 0; nt < 2; nt++) {
            int g = nt * 16 + fr;
            s16x4 pk;
            #pragma unroll
            for (int r = 0; r < 4; r++)
                pk[r] = (short)f2bf(acc[mt][nt][r] * dv[r]);
            *(s16x4*)(ZT + (size_t)(b * DOUT + g) * NN + jbase) = pk;
        }
    }
}

// ---------- gemm2: 64x128 tile (2 blocks/CU) with FUSED softmax epilogue ----------
__global__ __launch_bounds__(256) void gemm_sm(
    const unsigned short* __restrict__ A, const unsigned short* __restrict__ Bt,
    float* __restrict__ out, const float* __restrict__ dinv,
    const float* __restrict__ bias, int K)
{
    constexpr int BK = 64;
    __shared__ __align__(16) unsigned short Asm[64 * BK];    // 8 KB
    __shared__ __align__(16) unsigned short Bsm[128 * BK];   // 16 KB
    const int tid = threadIdx.x;
    const int lane = tid & 63;
    const int w = tid >> 6;
    const int wm = w >> 1, wn = w & 1;     // 2 x 2 wave grid; per-wave 32 x 64
    const int c0 = blockIdx.x * 128;
    const int j0 = blockIdx.y * 64;

    int srcA[2], srcB[4];
    #pragma unroll
    for (int q = 0; q < 2; q++) {
        int cid = q * 256 + tid;           // 0..511
        int row = cid >> 3, kc = cid & 7;
        srcA[q] = row * K + ((kc ^ (row & 7)) << 3);
    }
    #pragma unroll
    for (int q = 0; q < 4; q++) {
        int cid = q * 256 + tid;           // 0..1023
        int row = cid >> 3, kc = cid & 7;
        srcB[q] = row * K + ((kc ^ (row & 7)) << 3);
    }
    const int fr = lane & 15;
    const int kg = lane >> 4;

    f32x4 acc[2][4] = {};
    const unsigned short* Abase = A + (size_t)j0 * K;
    const unsigned short* Bbase = Bt + (size_t)c0 * K;

    for (int kt = 0; kt < K; kt += BK) {
        __syncthreads();
        const unsigned short* Ag = Abase + kt;
        const unsigned short* Bg = Bbase + kt;
        #pragma unroll
        for (int q = 0; q < 2; q++)
            gload16(Ag + srcA[q], &Asm[(q * 256 + tid) * 8]);
        #pragma unroll
        for (int q = 0; q < 4; q++)
            gload16(Bg + srcB[q], &Bsm[(q * 256 + tid) * 8]);
        __syncthreads();

        s16x8 af[2][2], bf[2][4];
        #pragma unroll
        for (int ks = 0; ks < 2; ks++) {
            int kc = ks * 4 + kg;
            #pragma unroll
            for (int m = 0; m < 2; m++) {
                int row = wm * 32 + m * 16 + fr;
                af[ks][m] = *(const s16x8*)((const char*)Asm + row * 128 + ((kc ^ (row & 7)) << 4));
            }
            #pragma unroll
            for (int n = 0; n < 4; n++) {
                int row = wn * 64 + n * 16 + fr;
                bf[ks][n] = *(const s16x8*)((const char*)Bsm + row * 128 + ((kc ^ (row & 7)) << 4));
            }
        }
        #pragma unroll
        for (int ks = 0; ks < 2; ks++)
            #pragma unroll
            for (int m = 0; m < 2; m++)
                #pragma unroll
                for (int n = 0; n < 4; n++)
                    acc[m][n] = __builtin_amdgcn_mfma_f32_16x16x32_bf16(
                        af[ks][m], bf[ks][n], acc[m][n], 0, 0, 0);
    }

    const float b_lo = bias[fr], b_hi = bias[fr + 16];
    #pragma unroll
    for (int m = 0; m < 2; m++) {
        int rbase = j0 + wm * 32 + m * 16 + kg * 4;
        float dv[4];
        #pragma unroll
        for (int r = 0; r < 4; r++) dv[r] = dinv[rbase + r];
        #pragma unroll
        for (int np = 0; np < 2; np++) {
            int bg = (c0 >> 5) + wn * 2 + np;       // batch index 0..31
            #pragma unroll
            for (int r = 0; r < 4; r++) {
                int row = rbase + r;                 // node j
                float v0 = acc[m][np * 2][r]     * dv[r] + b_lo;   // g = fr
                float v1 = acc[m][np * 2 + 1][r] * dv[r] + b_hi;   // g = fr+16
                float mx = fmaxf(v0, v1);
                #pragma unroll
                for (int d = 8; d; d >>= 1) mx = fmaxf(mx, __shfl_xor(mx, d));
                float e0 = expf(v0 - mx), e1 = expf(v1 - mx);
                float s = e0 + e1;
                #pragma unroll
                for (int d = 8; d; d >>= 1) s += __shfl_xor(s, d);
                float inv = 1.0f / s;
                size_t ob = ((size_t)bg * NN + row) * DOUT;
                out[ob + fr]      = e0 * inv;
                out[ob + fr + 16] = e1 * inv;
            }
        }
    }
}

extern "C" void kernel_launch(void* const* d_in, const int* in_sizes, int n_in,
                              void* d_out, int out_size, void* d_ws, size_t ws_size,
                              hipStream_t stream)
{
    (void)in_sizes; (void)n_in; (void)out_size; (void)ws_size;
    const float* x    = (const float*)d_in[0];
    const float* emb1 = (const float*)d_in[1];
    const float* emb2 = (const float*)d_in[2];
    const float* l1w  = (const float*)d_in[3];
    const float* l1b  = (const float*)d_in[4];
    const float* l2w  = (const float*)d_in[5];
    const float* l2b  = (const float*)d_in[6];
    const float* g1w  = (const float*)d_in[7];
    const float* g1b  = (const float*)d_in[8];
    const float* g2w  = (const float*)d_in[9];
    const float* g2b  = (const float*)d_in[10];
    float* out = (float*)d_out;

    char* w = (char*)d_ws;
    float* n1 = (float*)w;                    w += NN * DIM * 4;
    float* n2 = (float*)w;                    w += NN * DIM * 4;
    int* deg = (int*)w;                       w += NN * 4;
    float* dinv = (float*)w;                  w += NN * 4;
    unsigned short* MT = (unsigned short*)w;  w += (size_t)NN * NN * 2;
    unsigned short* YT = (unsigned short*)w;  w += (size_t)NN * NN * 2;
    unsigned short* H  = (unsigned short*)w;  w += (size_t)NN * NN * 2;
    unsigned short* ZT = (unsigned short*)w;  w += (size_t)(NB * DOUT) * NN * 2;
    // Ux/Vx live in YT's region (dead until k_y1, which runs after gemm_adj)
    unsigned short* Ux = YT;
    unsigned short* Vx = YT + (size_t)NN * KADJ;

    hipMemsetAsync(deg, 0, NN * sizeof(int), stream);
    k_embed<<<1280, 256, 0, stream>>>(emb1, emb2, l1w, l1b, l2w, l2b, n1, n2);
    k_build_uv<<<256, 256, 0, stream>>>(n1, n2, Ux, Vx);
    gemm_adj<<<dim3(32, 32), 256, 0, stream>>>(Vx, Ux, MT, deg);
    k_dinv<<<16, 256, 0, stream>>>(deg, dinv);
    k_y1<<<dim3(32, 32), 256, 0, stream>>>(x, g1w, dinv, YT);
    gemm4w<<<256, 256, 0, stream>>>(MT, YT, H, dinv, g1b);
    k_z2<<<dim3(32, 32), 256, 0, stream>>>(H, g2w, dinv, ZT);
    gemm_sm<<<dim3(8, 64), 256, 0, stream>>>(MT, ZT, out, dinv, g2b, NN);
}

// Round 10
// 274.562 us; speedup vs baseline: 1.1717x; 1.1717x over previous
//
#include <hip/hip_runtime.h>

typedef float f32x4 __attribute__((ext_vector_type(4)));
typedef short s16x8 __attribute__((ext_vector_type(8)));
typedef short s16x4 __attribute__((ext_vector_type(4)));

#define NN 4096
#define NB 32
#define DIN 64
#define DH 128
#define DOUT 32
#define DIM 40
#define KADJ 512   // 6 split-blocks x 80, zero-padded to 512

__device__ __forceinline__ unsigned short f2bf(float f) {
    unsigned int u = __float_as_uint(f);
    unsigned int r = (u + 0x7FFFu + ((u >> 16) & 1u)) >> 16;
    return (unsigned short)r;
}
__device__ __forceinline__ float bf2f(unsigned short h) {
    return __uint_as_float(((unsigned int)h) << 16);
}
__device__ __forceinline__ void gload16(const void* g, void* l) {
    __builtin_amdgcn_global_load_lds(
        (const __attribute__((address_space(1))) unsigned int*)g,
        (__attribute__((address_space(3))) unsigned int*)l, 16, 0, 0);
}
__device__ __forceinline__ void bar() {
    asm volatile("" ::: "memory");
    __builtin_amdgcn_s_barrier();
    asm volatile("" ::: "memory");
}

// ---------------- stage 1: n1/n2 = tanh(3*(emb @ W + b)) ----------------
__global__ __launch_bounds__(256) void k_embed(
    const float* __restrict__ emb1, const float* __restrict__ emb2,
    const float* __restrict__ l1w, const float* __restrict__ l1b,
    const float* __restrict__ l2w, const float* __restrict__ l2b,
    float* __restrict__ n1, float* __restrict__ n2)
{
    __shared__ float w1s[DIM * DIM], w2s[DIM * DIM], b1s[DIM], b2s[DIM];
    int tid = threadIdx.x;
    for (int i = tid; i < DIM * DIM; i += 256) { w1s[i] = l1w[i]; w2s[i] = l2w[i]; }
    if (tid < DIM) { b1s[tid] = l1b[tid]; b2s[tid] = l2b[tid]; }
    __syncthreads();
    int t = blockIdx.x * 256 + tid;          // < 2*4096*40 = 327680
    int half = t >= NN * DIM;
    int r = t - half * (NN * DIM);
    int i = r / DIM, c = r - i * DIM;
    const float* emb = half ? emb2 : emb1;
    const float* ws  = half ? w2s : w1s;
    float acc = half ? b2s[c] : b1s[c];
    for (int k = 0; k < DIM; k++) acc += emb[i * DIM + k] * ws[k * DIM + c];
    (half ? n2 : n1)[r] = tanhf(3.0f * acc);
}

// ---------------- stage 2a: build split operands for the adjacency GEMM ----------------
__global__ __launch_bounds__(256) void k_build_uv(
    const float* __restrict__ n1, const float* __restrict__ n2,
    unsigned short* __restrict__ Ux, unsigned short* __restrict__ Vx)
{
    __shared__ unsigned short Ul[16][KADJ], Vl[16][KADJ];
    const int tid = threadIdx.x;
    const int r = tid >> 4;                 // local node 0..15
    const int node = blockIdx.x * 16 + r;
    const int k0 = (tid & 15) * 5;          // 5 k's per thread (80 total)
    const int PMAP[6] = {0, 0, 1, 1, 0, 2};
    const int QMAP[6] = {0, 1, 0, 1, 2, 0};
    #pragma unroll
    for (int e = 0; e < 5; e++) {
        int k = k0 + e;
        float a = (k < DIM) ? n1[node * DIM + k] : -n2[node * DIM + k - DIM];
        float b = (k < DIM) ? n2[node * DIM + k] : n1[node * DIM + k - DIM];
        unsigned short u0 = f2bf(a); float ra = a - bf2f(u0);
        unsigned short u1 = f2bf(ra); ra -= bf2f(u1);
        unsigned short u2 = f2bf(ra);
        unsigned short v0 = f2bf(b); float rb = b - bf2f(v0);
        unsigned short v1 = f2bf(rb); rb -= bf2f(v1);
        unsigned short v2 = f2bf(rb);
        unsigned short uu[3] = {u0, u1, u2}, vv[3] = {v0, v1, v2};
        #pragma unroll
        for (int bq = 0; bq < 6; bq++) {
            Ul[r][80 * bq + k] = uu[PMAP[bq]];
            Vl[r][80 * bq + k] = vv[QMAP[bq]];
        }
    }
    {   // zero-pad 480..511
        int c = tid & 15;
        Ul[r][480 + c * 2]     = 0; Vl[r][480 + c * 2]     = 0;
        Ul[r][480 + c * 2 + 1] = 0; Vl[r][480 + c * 2 + 1] = 0;
    }
    __syncthreads();
    #pragma unroll
    for (int q = 0; q < 4; q++) {           // 16*512/8 = 1024 chunks
        int idx = q * 256 + tid;
        int rr = idx >> 6, c8 = idx & 63;
        size_t off = ((size_t)(blockIdx.x * 16 + rr)) * KADJ + c8 * 8;
        *(s16x8*)(Ux + off) = *(s16x8*)&Ul[rr][c8 * 8];
        *(s16x8*)(Vx + off) = *(s16x8*)&Vl[rr][c8 * 8];
    }
}

// ---------------- stage 2b: adjacency GEMM, 256x256 gemm8-structure, K=512 ----------------
// C[j][i] = Vx[j]·Ux[i]; MT[j][i] = (C>0 || i==j); deg[j] += row popcount.
__global__ __launch_bounds__(512, 2) void gemm_adj8(
    const unsigned short* __restrict__ A, const unsigned short* __restrict__ Bt,
    unsigned short* __restrict__ MT, int* __restrict__ deg)
{
    constexpr int K = KADJ;        // 512
    constexpr int NT = K / 64;     // 8 K-tiles
    __shared__ __align__(16) unsigned short As[2][256 * 64];
    __shared__ __align__(16) unsigned short Bs[2][256 * 64];

    const int tid = threadIdx.x;
    const int lane = tid & 63;
    const int w = tid >> 6;
    const int wm = w >> 2, wn = w & 3;
    const int fr = lane & 15, kg = lane >> 4;

    const int bid = blockIdx.x;             // 256 blocks -> XCD swizzle
    const int swz = (bid & 7) * 32 + (bid >> 3);
    const int bx = swz & 15, by = swz >> 4;
    const int c0 = bx * 256, j0 = by * 256;

    const int cid0 = w * 128 + lane, cid1 = cid0 + 64;
    const int r0 = cid0 >> 3, k0c = cid0 & 7;
    const int r1 = cid1 >> 3, k1c = cid1 & 7;
    const int so0 = r0 * K + ((k0c ^ (r0 & 7)) << 3);
    const int so1 = r1 * K + ((k1c ^ (r1 & 7)) << 3);
    const int lb0 = (w * 2 + 0) * 512;
    const int lb1 = (w * 2 + 1) * 512;

    const unsigned short* Aj = A + (size_t)j0 * K;
    const unsigned short* Bc = Bt + (size_t)c0 * K;

#define STAGE_A(buf, half, kt) do { \
    const unsigned short* g_ = Aj + (size_t)((half) * 128) * K + (kt); \
    gload16(g_ + so0, &As[buf][(half) * 8192 + lb0]); \
    gload16(g_ + so1, &As[buf][(half) * 8192 + lb1]); } while (0)
#define STAGE_B(buf, half, kt) do { \
    const unsigned short* g_ = Bc + (size_t)((half) * 128) * K + (kt); \
    gload16(g_ + so0, &Bs[buf][(half) * 8192 + lb0]); \
    gload16(g_ + so1, &Bs[buf][(half) * 8192 + lb1]); } while (0)

    STAGE_A(0, 0, 0);  STAGE_A(0, 1, 0);
    STAGE_B(0, 0, 0);  STAGE_B(0, 1, 0);
    STAGE_A(1, 0, 64); STAGE_A(1, 1, 64);
    STAGE_B(1, 0, 64);
    asm volatile("s_waitcnt vmcnt(6)" ::: "memory");
    bar();

    const int x0 = ((kg) ^ (fr & 7)) << 4;
    const int x1 = ((4 + kg) ^ (fr & 7)) << 4;
    int aOff[8], bOff[4];
    #pragma unroll
    for (int m = 0; m < 8; m++) aOff[m] = (wm * 128 + m * 16 + fr) * 128;
    #pragma unroll
    for (int n = 0; n < 4; n++) bOff[n] = (wn * 64 + n * 16 + fr) * 128;

    s16x8 af0c[4], bf0c[4];
    #pragma unroll
    for (int m = 0; m < 4; m++) af0c[m] = *(const s16x8*)((const char*)As[0] + aOff[m] + x0);
    #pragma unroll
    for (int n = 0; n < 4; n++) bf0c[n] = *(const s16x8*)((const char*)Bs[0] + bOff[n] + x0);

    f32x4 acc[8][4] = {};

    for (int t = 0; t < NT; t++) {
        const int P = t & 1;
        const char* Ap = (const char*)As[P];
        const char* Bp = (const char*)Bs[P];
        const char* Aq = (const char*)As[P ^ 1];
        const char* Bq = (const char*)Bs[P ^ 1];
        const int kt1 = (t + 1) * 64, kt2 = (t + 2) * 64;
        const bool s1 = (t + 1) < NT, s2 = (t + 2) < NT;
        s16x8 af0h[4], af1l[4], af1h[4], bf1[4], af0n[4], bf0n[4];

        #pragma unroll
        for (int m = 0; m < 4; m++) af0h[m] = *(const s16x8*)(Ap + aOff[m + 4] + x0);
        #pragma unroll
        for (int m = 0; m < 4; m++) af1l[m] = *(const s16x8*)(Ap + aOff[m] + x1);
        if (s1) STAGE_B(P ^ 1, 1, kt1);
        __builtin_amdgcn_s_setprio(1);
        #pragma unroll
        for (int m = 0; m < 4; m++)
            #pragma unroll
            for (int n = 0; n < 4; n++)
                acc[m][n] = __builtin_amdgcn_mfma_f32_16x16x32_bf16(af0c[m], bf0c[n], acc[m][n], 0, 0, 0);
        __builtin_amdgcn_s_setprio(0);

        #pragma unroll
        for (int m = 0; m < 4; m++) af1h[m] = *(const s16x8*)(Ap + aOff[m + 4] + x1);
        #pragma unroll
        for (int n = 0; n < 4; n++) bf1[n] = *(const s16x8*)(Bp + bOff[n] + x1);
        __builtin_amdgcn_s_setprio(1);
        #pragma unroll
        for (int m = 4; m < 8; m++)
            #pragma unroll
            for (int n = 0; n < 4; n++)
                acc[m][n] = __builtin_amdgcn_mfma_f32_16x16x32_bf16(af0h[m - 4], bf0c[n], acc[m][n], 0, 0, 0);
        __builtin_amdgcn_s_setprio(0);
        asm volatile("s_waitcnt lgkmcnt(0)" ::: "memory");
        bar();

        __builtin_amdgcn_s_setprio(1);
        #pragma unroll
        for (int m = 0; m < 4; m++)
            #pragma unroll
            for (int n = 0; n < 4; n++)
                acc[m][n] = __builtin_amdgcn_mfma_f32_16x16x32_bf16(af1l[m], bf1[n], acc[m][n], 0, 0, 0);
        __builtin_amdgcn_s_setprio(0);
        if (s2) {
            STAGE_A(P, 0, kt2);
            STAGE_A(P, 1, kt2);
            STAGE_B(P, 0, kt2);
            asm volatile("s_waitcnt vmcnt(6)" ::: "memory");
        } else {
            asm volatile("s_waitcnt vmcnt(0)" ::: "memory");
        }
        bar();

        if (s1) {
            #pragma unroll
            for (int m = 0; m < 4; m++) af0n[m] = *(const s16x8*)(Aq + aOff[m] + x0);
            #pragma unroll
            for (int n = 0; n < 4; n++) bf0n[n] = *(const s16x8*)(Bq + bOff[n] + x0);
        }
        __builtin_amdgcn_s_setprio(1);
        #pragma unroll
        for (int m = 4; m < 8; m++)
            #pragma unroll
            for (int n = 0; n < 4; n++)
                acc[m][n] = __builtin_amdgcn_mfma_f32_16x16x32_bf16(af1h[m - 4], bf1[n], acc[m][n], 0, 0, 0);
        __builtin_amdgcn_s_setprio(0);
        if (s1) {
            #pragma unroll
            for (int m = 0; m < 4; m++) af0c[m] = af0n[m];
            #pragma unroll
            for (int n = 0; n < 4; n++) bf0c[n] = bf0n[n];
        }
    }
#undef STAGE_A
#undef STAGE_B

    // epilogue: bits + degree
    #pragma unroll
    for (int m = 0; m < 8; m++) {
        int rbase = j0 + wm * 128 + m * 16 + kg * 4;
        #pragma unroll
        for (int r = 0; r < 4; r++) {
            int row = rbase + r;
            int cnt = 0;
            #pragma unroll
            for (int n = 0; n < 4; n++) {
                int col = c0 + wn * 64 + n * 16 + fr;
                bool bit = (acc[m][n][r] > 0.f) || (row == col);
                MT[(size_t)row * NN + col] = bit ? (unsigned short)0x3F80 : (unsigned short)0;
                cnt += bit ? 1 : 0;
            }
            cnt += __shfl_xor(cnt, 1);
            cnt += __shfl_xor(cnt, 2);
            cnt += __shfl_xor(cnt, 4);
            cnt += __shfl_xor(cnt, 8);
            if (fr == 0) atomicAdd(&deg[row], cnt);
        }
    }
}

__global__ void k_dinv(const int* __restrict__ deg, float* __restrict__ dinv) {
    int i = blockIdx.x * 256 + threadIdx.x;
    if (i < NN) dinv[i] = 1.0f / sqrtf((float)deg[i]);
}

// ---------------- YT[c=b*128+f][i] = bf16( dinv_i * (x[b,i,:] @ W1[:,f]) ) ----------------
__global__ __launch_bounds__(256) void k_y1(
    const float* __restrict__ x, const float* __restrict__ W1,
    const float* __restrict__ dinv, unsigned short* __restrict__ YT)
{
    __shared__ __align__(16) float xs[128][DIN];
    __shared__ __align__(16) float w1s[DIN][DH];
    int i0 = blockIdx.x * 128, b = blockIdx.y;
    int tid = threadIdx.x;
    const f32x4* xg = (const f32x4*)(x + ((size_t)(b * NN + i0)) * DIN);
    #pragma unroll
    for (int q = 0; q < 8; q++) {
        int idx = q * 256 + tid;
        int row = idx >> 4, c4 = idx & 15;
        *(f32x4*)&xs[row][c4 * 4] = xg[(size_t)row * 16 + c4];
    }
    #pragma unroll
    for (int q = 0; q < 8; q++) {
        int idx = q * 256 + tid;
        int row = idx >> 5, c4 = idx & 31;
        *(f32x4*)&w1s[row][c4 * 4] = ((const f32x4*)W1)[idx];
    }
    __syncthreads();
    int tf = tid & 15, ti = tid >> 4;
    f32x4 t0[8] = {}, t1[8] = {};
    for (int k4 = 0; k4 < DIN; k4 += 4) {
        f32x4 xv[8];
        #pragma unroll
        for (int ii = 0; ii < 8; ii++) xv[ii] = *(const f32x4*)&xs[ti * 8 + ii][k4];
        #pragma unroll
        for (int kk = 0; kk < 4; kk++) {
            f32x4 w0 = *(const f32x4*)&w1s[k4 + kk][tf * 8];
            f32x4 w1v = *(const f32x4*)&w1s[k4 + kk][tf * 8 + 4];
            #pragma unroll
            for (int ii = 0; ii < 8; ii++) {
                float s = xv[ii][kk];
                t0[ii] += s * w0;
                t1[ii] += s * w1v;
            }
        }
    }
    float dvv[8];
    #pragma unroll
    for (int ii = 0; ii < 8; ii++) dvv[ii] = dinv[i0 + ti * 8 + ii];
    #pragma unroll
    for (int ff = 0; ff < 8; ff++) {
        s16x8 pk;
        #pragma unroll
        for (int ii = 0; ii < 8; ii++) {
            float v = (ff < 4 ? t0[ii][ff] : t1[ii][ff - 4]) * dvv[ii];
            pk[ii] = (short)f2bf(v);
        }
        *(s16x8*)(YT + ((size_t)(b * DH + tf * 8 + ff)) * NN + i0 + ti * 8) = pk;
    }
}

// ======== gemm1: 256x256, BK=64, 8 waves; 2 barriers/K-tile + phase read-ahead (R8 proven) ========
__global__ __launch_bounds__(512, 2) void gemm8(
    const unsigned short* __restrict__ A, const unsigned short* __restrict__ Bt,
    unsigned short* __restrict__ H, const float* __restrict__ dinv,
    const float* __restrict__ bias)
{
    constexpr int K = NN;          // 4096
    constexpr int NT = K / 64;     // 64 K-tiles
    __shared__ __align__(16) unsigned short As[2][256 * 64];   // 64 KB
    __shared__ __align__(16) unsigned short Bs[2][256 * 64];   // 64 KB

    const int tid = threadIdx.x;
    const int lane = tid & 63;
    const int w = tid >> 6;                 // wave 0..7
    const int wm = w >> 2, wn = w & 3;      // 2 x 4 wave grid
    const int fr = lane & 15, kg = lane >> 4;

    const int bid = blockIdx.x;             // 256 blocks -> XCD swizzle
    const int swz = (bid & 7) * 32 + (bid >> 3);
    const int bx = swz & 15, by = swz >> 4;
    const int c0 = bx * 256, j0 = by * 256;

    const int cid0 = w * 128 + lane, cid1 = cid0 + 64;
    const int r0 = cid0 >> 3, k0c = cid0 & 7;
    const int r1 = cid1 >> 3, k1c = cid1 & 7;
    const int so0 = r0 * K + ((k0c ^ (r0 & 7)) << 3);   // ushort units
    const int so1 = r1 * K + ((k1c ^ (r1 & 7)) << 3);
    const int lb0 = (w * 2 + 0) * 512;                  // ushort units
    const int lb1 = (w * 2 + 1) * 512;

    const unsigned short* Aj = A + (size_t)j0 * K;
    const unsigned short* Bc = Bt + (size_t)c0 * K;

#define STAGE_A(buf, half, kt) do { \
    const unsigned short* g_ = Aj + (size_t)((half) * 128) * K + (kt); \
    gload16(g_ + so0, &As[buf][(half) * 8192 + lb0]); \
    gload16(g_ + so1, &As[buf][(half) * 8192 + lb1]); } while (0)
#define STAGE_B(buf, half, kt) do { \
    const unsigned short* g_ = Bc + (size_t)((half) * 128) * K + (kt); \
    gload16(g_ + so0, &Bs[buf][(half) * 8192 + lb0]); \
    gload16(g_ + so1, &Bs[buf][(half) * 8192 + lb1]); } while (0)

    STAGE_A(0, 0, 0);  STAGE_A(0, 1, 0);
    STAGE_B(0, 0, 0);  STAGE_B(0, 1, 0);
    STAGE_A(1, 0, 64); STAGE_A(1, 1, 64);
    STAGE_B(1, 0, 64);
    asm volatile("s_waitcnt vmcnt(6)" ::: "memory");
    bar();

    const int x0 = ((kg) ^ (fr & 7)) << 4;
    const int x1 = ((4 + kg) ^ (fr & 7)) << 4;
    int aOff[8], bOff[4];
    #pragma unroll
    for (int m = 0; m < 8; m++) aOff[m] = (wm * 128 + m * 16 + fr) * 128;
    #pragma unroll
    for (int n = 0; n < 4; n++) bOff[n] = (wn * 64 + n * 16 + fr) * 128;

    s16x8 af0c[4], bf0c[4];
    #pragma unroll
    for (int m = 0; m < 4; m++) af0c[m] = *(const s16x8*)((const char*)As[0] + aOff[m] + x0);
    #pragma unroll
    for (int n = 0; n < 4; n++) bf0c[n] = *(const s16x8*)((const char*)Bs[0] + bOff[n] + x0);

    f32x4 acc[8][4] = {};

    for (int t = 0; t < NT; t++) {
        const int P = t & 1;
        const char* Ap = (const char*)As[P];
        const char* Bp = (const char*)Bs[P];
        const char* Aq = (const char*)As[P ^ 1];
        const char* Bq = (const char*)Bs[P ^ 1];
        const int kt1 = (t + 1) * 64, kt2 = (t + 2) * 64;
        const bool s1 = (t + 1) < NT, s2 = (t + 2) < NT;
        s16x8 af0h[4], af1l[4], af1h[4], bf1[4], af0n[4], bf0n[4];

        // ---- phase A
        #pragma unroll
        for (int m = 0; m < 4; m++) af0h[m] = *(const s16x8*)(Ap + aOff[m + 4] + x0);
        #pragma unroll
        for (int m = 0; m < 4; m++) af1l[m] = *(const s16x8*)(Ap + aOff[m] + x1);
        if (s1) STAGE_B(P ^ 1, 1, kt1);
        __builtin_amdgcn_s_setprio(1);
        #pragma unroll
        for (int m = 0; m < 4; m++)
            #pragma unroll
            for (int n = 0; n < 4; n++)
                acc[m][n] = __builtin_amdgcn_mfma_f32_16x16x32_bf16(af0c[m], bf0c[n], acc[m][n], 0, 0, 0);
        __builtin_amdgcn_s_setprio(0);

        // ---- phase B
        #pragma unroll
        for (int m = 0; m < 4; m++) af1h[m] = *(const s16x8*)(Ap + aOff[m + 4] + x1);
        #pragma unroll
        for (int n = 0; n < 4; n++) bf1[n] = *(const s16x8*)(Bp + bOff[n] + x1);
        __builtin_amdgcn_s_setprio(1);
        #pragma unroll
        for (int m = 4; m < 8; m++)
            #pragma unroll
            for (int n = 0; n < 4; n++)
                acc[m][n] = __builtin_amdgcn_mfma_f32_16x16x32_bf16(af0h[m - 4], bf0c[n], acc[m][n], 0, 0, 0);
        __builtin_amdgcn_s_setprio(0);
        asm volatile("s_waitcnt lgkmcnt(0)" ::: "memory");
        bar();                                   // BAR(i)

        // ---- phase C
        __builtin_amdgcn_s_setprio(1);
        #pragma unroll
        for (int m = 0; m < 4; m++)
            #pragma unroll
            for (int n = 0; n < 4; n++)
                acc[m][n] = __builtin_amdgcn_mfma_f32_16x16x32_bf16(af1l[m], bf1[n], acc[m][n], 0, 0, 0);
        __builtin_amdgcn_s_setprio(0);
        if (s2) {
            STAGE_A(P, 0, kt2);
            STAGE_A(P, 1, kt2);
            STAGE_B(P, 0, kt2);
            asm volatile("s_waitcnt vmcnt(6)" ::: "memory");
        } else {
            asm volatile("s_waitcnt vmcnt(0)" ::: "memory");
        }
        bar();                                   // BAR(ii)

        // ---- phase D
        if (s1) {
            #pragma unroll
            for (int m = 0; m < 4; m++) af0n[m] = *(const s16x8*)(Aq + aOff[m] + x0);
            #pragma unroll
            for (int n = 0; n < 4; n++) bf0n[n] = *(const s16x8*)(Bq + bOff[n] + x0);
        }
        __builtin_amdgcn_s_setprio(1);
        #pragma unroll
        for (int m = 4; m < 8; m++)
            #pragma unroll
            for (int n = 0; n < 4; n++)
                acc[m][n] = __builtin_amdgcn_mfma_f32_16x16x32_bf16(af1h[m - 4], bf1[n], acc[m][n], 0, 0, 0);
        __builtin_amdgcn_s_setprio(0);
        if (s1) {
            #pragma unroll
            for (int m = 0; m < 4; m++) af0c[m] = af0n[m];
            #pragma unroll
            for (int n = 0; n < 4; n++) bf0c[n] = bf0n[n];
        }
    }
#undef STAGE_A
#undef STAGE_B

    // epilogue
    #pragma unroll
    for (int m = 0; m < 8; m++) {
        int rbase = j0 + wm * 128 + m * 16 + kg * 4;
        float dv[4];
        #pragma unroll
        for (int r = 0; r < 4; r++) dv[r] = dinv[rbase + r];
        #pragma unroll
        for (int n = 0; n < 4; n++) {
            int gcol = c0 + wn * 64 + n * 16 + fr;
            float bb = bias[gcol & (DH - 1)];
            #pragma unroll
            for (int r = 0; r < 4; r++) {
                float v = acc[m][n][r] * dv[r] + bb;
                v = v > 0.f ? v : 0.f;
                H[(size_t)(rbase + r) * NN + gcol] = f2bf(v);
            }
        }
    }
}

// ---------- k_z2: MFMA-based ZT = dinv_j * (H_b @ W2) ----------
__global__ __launch_bounds__(256) void k_z2(
    const unsigned short* __restrict__ H, const float* __restrict__ W2,
    const float* __restrict__ dinv, unsigned short* __restrict__ ZT)
{
    __shared__ __align__(16) unsigned short Hs[128 * DH];     // 32 KB
    __shared__ __align__(16) unsigned short W2Ts[DOUT * DH];  // 8 KB
    const int tid = threadIdx.x;
    const int j0 = blockIdx.x * 128, b = blockIdx.y;
    const unsigned short* Hb = H + (size_t)j0 * NN + b * DH;

    #pragma unroll
    for (int q = 0; q < 8; q++) {
        int cid = q * 256 + tid;
        int row = cid >> 4, kc = cid & 15;
        gload16(Hb + (size_t)row * NN + kc * 8, &Hs[cid * 8]);
    }
    #pragma unroll
    for (int q = 0; q < 16; q++) {
        int idx = q * 256 + tid;
        int f = idx >> 5, g = idx & 31;
        W2Ts[g * DH + f] = f2bf(W2[f * DOUT + g]);
    }
    __syncthreads();

    const int lane = tid & 63, w = tid >> 6;
    const int fr = lane & 15, kg = lane >> 4;
    f32x4 acc[2][2] = {};
    #pragma unroll
    for (int ks = 0; ks < 4; ks++) {
        s16x8 af[2], bf[2];
        #pragma unroll
        for (int mt = 0; mt < 2; mt++) {
            int row = w * 32 + mt * 16 + fr;
            af[mt] = *(const s16x8*)&Hs[row * DH + ks * 32 + kg * 8];
        }
        #pragma unroll
        for (int nt = 0; nt < 2; nt++) {
            int g = nt * 16 + fr;
            bf[nt] = *(const s16x8*)&W2Ts[g * DH + ks * 32 + kg * 8];
        }
        #pragma unroll
        for (int mt = 0; mt < 2; mt++)
            #pragma unroll
            for (int nt = 0; nt < 2; nt++)
                acc[mt][nt] = __builtin_amdgcn_mfma_f32_16x16x32_bf16(af[mt], bf[nt], acc[mt][nt], 0, 0, 0);
    }
    #pragma unroll
    for (int mt = 0; mt < 2; mt++) {
        int jbase = j0 + w * 32 + mt * 16 + kg * 4;
        float dv[4];
        #pragma unroll
        for (int r = 0; r < 4; r++) dv[r] = dinv[jbase + r];
        #pragma unroll
        for (int nt = 0; nt < 2; nt++) {
            int g = nt * 16 + fr;
            s16x4 pk;
            #pragma unroll
            for (int r = 0; r < 4; r++)
                pk[r] = (short)f2bf(acc[mt][nt][r] * dv[r]);
            *(s16x4*)(ZT + (size_t)(b * DOUT + g) * NN + jbase) = pk;
        }
    }
}

// ---------- gemm2: 64x128 tile (2 blocks/CU) with FUSED softmax epilogue ----------
__global__ __launch_bounds__(256) void gemm_sm(
    const unsigned short* __restrict__ A, const unsigned short* __restrict__ Bt,
    float* __restrict__ out, const float* __restrict__ dinv,
    const float* __restrict__ bias, int K)
{
    constexpr int BK = 64;
    __shared__ __align__(16) unsigned short Asm[64 * BK];    // 8 KB
    __shared__ __align__(16) unsigned short Bsm[128 * BK];   // 16 KB
    const int tid = threadIdx.x;
    const int lane = tid & 63;
    const int w = tid >> 6;
    const int wm = w >> 1, wn = w & 1;     // 2 x 2 wave grid; per-wave 32 x 64
    const int c0 = blockIdx.x * 128;
    const int j0 = blockIdx.y * 64;

    int srcA[2], srcB[4];
    #pragma unroll
    for (int q = 0; q < 2; q++) {
        int cid = q * 256 + tid;
        int row = cid >> 3, kc = cid & 7;
        srcA[q] = row * K + ((kc ^ (row & 7)) << 3);
    }
    #pragma unroll
    for (int q = 0; q < 4; q++) {
        int cid = q * 256 + tid;
        int row = cid >> 3, kc = cid & 7;
        srcB[q] = row * K + ((kc ^ (row & 7)) << 3);
    }
    const int fr = lane & 15;
    const int kg = lane >> 4;

    f32x4 acc[2][4] = {};
    const unsigned short* Abase = A + (size_t)j0 * K;
    const unsigned short* Bbase = Bt + (size_t)c0 * K;

    for (int kt = 0; kt < K; kt += BK) {
        __syncthreads();
        const unsigned short* Ag = Abase + kt;
        const unsigned short* Bg = Bbase + kt;
        #pragma unroll
        for (int q = 0; q < 2; q++)
            gload16(Ag + srcA[q], &Asm[(q * 256 + tid) * 8]);
        #pragma unroll
        for (int q = 0; q < 4; q++)
            gload16(Bg + srcB[q], &Bsm[(q * 256 + tid) * 8]);
        __syncthreads();

        s16x8 af[2][2], bf[2][4];
        #pragma unroll
        for (int ks = 0; ks < 2; ks++) {
            int kc = ks * 4 + kg;
            #pragma unroll
            for (int m = 0; m < 2; m++) {
                int row = wm * 32 + m * 16 + fr;
                af[ks][m] = *(const s16x8*)((const char*)Asm + row * 128 + ((kc ^ (row & 7)) << 4));
            }
            #pragma unroll
            for (int n = 0; n < 4; n++) {
                int row = wn * 64 + n * 16 + fr;
                bf[ks][n] = *(const s16x8*)((const char*)Bsm + row * 128 + ((kc ^ (row & 7)) << 4));
            }
        }
        #pragma unroll
        for (int ks = 0; ks < 2; ks++)
            #pragma unroll
            for (int m = 0; m < 2; m++)
                #pragma unroll
                for (int n = 0; n < 4; n++)
                    acc[m][n] = __builtin_amdgcn_mfma_f32_16x16x32_bf16(
                        af[ks][m], bf[ks][n], acc[m][n], 0, 0, 0);
    }

    const float b_lo = bias[fr], b_hi = bias[fr + 16];
    #pragma unroll
    for (int m = 0; m < 2; m++) {
        int rbase = j0 + wm * 32 + m * 16 + kg * 4;
        float dv[4];
        #pragma unroll
        for (int r = 0; r < 4; r++) dv[r] = dinv[rbase + r];
        #pragma unroll
        for (int np = 0; np < 2; np++) {
            int bg = (c0 >> 5) + wn * 2 + np;       // batch index 0..31
            #pragma unroll
            for (int r = 0; r < 4; r++) {
                int row = rbase + r;                 // node j
                float v0 = acc[m][np * 2][r]     * dv[r] + b_lo;   // g = fr
                float v1 = acc[m][np * 2 + 1][r] * dv[r] + b_hi;   // g = fr+16
                float mx = fmaxf(v0, v1);
                #pragma unroll
                for (int d = 8; d; d >>= 1) mx = fmaxf(mx, __shfl_xor(mx, d));
                float e0 = expf(v0 - mx), e1 = expf(v1 - mx);
                float s = e0 + e1;
                #pragma unroll
                for (int d = 8; d; d >>= 1) s += __shfl_xor(s, d);
                float inv = 1.0f / s;
                size_t ob = ((size_t)bg * NN + row) * DOUT;
                out[ob + fr]      = e0 * inv;
                out[ob + fr + 16] = e1 * inv;
            }
        }
    }
}

extern "C" void kernel_launch(void* const* d_in, const int* in_sizes, int n_in,
                              void* d_out, int out_size, void* d_ws, size_t ws_size,
                              hipStream_t stream)
{
    (void)in_sizes; (void)n_in; (void)out_size; (void)ws_size;
    const float* x    = (const float*)d_in[0];
    const float* emb1 = (const float*)d_in[1];
    const float* emb2 = (const float*)d_in[2];
    const float* l1w  = (const float*)d_in[3];
    const float* l1b  = (const float*)d_in[4];
    const float* l2w  = (const float*)d_in[5];
    const float* l2b  = (const float*)d_in[6];
    const float* g1w  = (const float*)d_in[7];
    const float* g1b  = (const float*)d_in[8];
    const float* g2w  = (const float*)d_in[9];
    const float* g2b  = (const float*)d_in[10];
    float* out = (float*)d_out;

    char* w = (char*)d_ws;
    float* n1 = (float*)w;                    w += NN * DIM * 4;
    float* n2 = (float*)w;                    w += NN * DIM * 4;
    int* deg = (int*)w;                       w += NN * 4;
    float* dinv = (float*)w;                  w += NN * 4;
    unsigned short* MT = (unsigned short*)w;  w += (size_t)NN * NN * 2;
    unsigned short* YT = (unsigned short*)w;  w += (size_t)NN * NN * 2;
    unsigned short* H  = (unsigned short*)w;  w += (size_t)NN * NN * 2;
    unsigned short* ZT = (unsigned short*)w;  w += (size_t)(NB * DOUT) * NN * 2;
    // Ux/Vx live in YT's region (dead until k_y1, which runs after gemm_adj8)
    unsigned short* Ux = YT;
    unsigned short* Vx = YT + (size_t)NN * KADJ;

    hipMemsetAsync(deg, 0, NN * sizeof(int), stream);
    k_embed<<<1280, 256, 0, stream>>>(emb1, emb2, l1w, l1b, l2w, l2b, n1, n2);
    k_build_uv<<<256, 256, 0, stream>>>(n1, n2, Ux, Vx);
    gemm_adj8<<<256, 512, 0, stream>>>(Vx, Ux, MT, deg);
    k_dinv<<<16, 256, 0, stream>>>(deg, dinv);
    k_y1<<<dim3(32, 32), 256, 0, stream>>>(x, g1w, dinv, YT);
    gemm8<<<256, 512, 0, stream>>>(MT, YT, H, dinv, g1b);
    k_z2<<<dim3(32, 32), 256, 0, stream>>>(H, g2w, dinv, ZT);
    gemm_sm<<<dim3(8, 64), 256, 0, stream>>>(MT, ZT, out, dinv, g2b, NN);
}

// Round 11
// 273.319 us; speedup vs baseline: 1.1770x; 1.0045x over previous
//
#include <hip/hip_runtime.h>

typedef float f32x4 __attribute__((ext_vector_type(4)));
typedef short s16x8 __attribute__((ext_vector_type(8)));
typedef short s16x4 __attribute__((ext_vector_type(4)));

#define NN 4096
#define NB 32
#define DIN 64
#define DH 128
#define DOUT 32
#define DIM 40
#define KADJ 512   // 6 split-blocks x 80, zero-padded to 512

__device__ __forceinline__ unsigned short f2bf(float f) {
    unsigned int u = __float_as_uint(f);
    unsigned int r = (u + 0x7FFFu + ((u >> 16) & 1u)) >> 16;
    return (unsigned short)r;
}
__device__ __forceinline__ float bf2f(unsigned short h) {
    return __uint_as_float(((unsigned int)h) << 16);
}
__device__ __forceinline__ void gload16(const void* g, void* l) {
    __builtin_amdgcn_global_load_lds(
        (const __attribute__((address_space(1))) unsigned int*)g,
        (__attribute__((address_space(3))) unsigned int*)l, 16, 0, 0);
}
__device__ __forceinline__ void bar() {
    asm volatile("" ::: "memory");
    __builtin_amdgcn_s_barrier();
    asm volatile("" ::: "memory");
}

// ---------------- fused: n1/n2 = tanh(3*(emb @ W + b)) -> 3-way bf16 split operands ----------------
__global__ __launch_bounds__(256) void k_embuv(
    const float* __restrict__ emb1, const float* __restrict__ emb2,
    const float* __restrict__ l1w, const float* __restrict__ l1b,
    const float* __restrict__ l2w, const float* __restrict__ l2b,
    unsigned short* __restrict__ Ux, unsigned short* __restrict__ Vx)
{
    __shared__ float e1s[16 * DIM], e2s[16 * DIM];
    __shared__ float w1s[DIM * DIM], w2s[DIM * DIM], b1s[DIM], b2s[DIM];
    __shared__ unsigned short Ul[16][KADJ], Vl[16][KADJ];
    const int tid = threadIdx.x;
    const int node0 = blockIdx.x * 16;
    for (int i = tid; i < 16 * DIM; i += 256) {
        e1s[i] = emb1[node0 * DIM + i];
        e2s[i] = emb2[node0 * DIM + i];
    }
    for (int i = tid; i < DIM * DIM; i += 256) { w1s[i] = l1w[i]; w2s[i] = l2w[i]; }
    if (tid < DIM) { b1s[tid] = l1b[tid]; b2s[tid] = l2b[tid]; }
    __syncthreads();
    const int r = tid >> 4;                 // local node 0..15
    const int k0 = (tid & 15) * 5;          // 5 k's per thread (80 total)
    const int PMAP[6] = {0, 0, 1, 1, 0, 2};
    const int QMAP[6] = {0, 1, 0, 1, 2, 0};
    #pragma unroll
    for (int e = 0; e < 5; e++) {
        int k = k0 + e;
        int kp = (k < DIM) ? k : k - DIM;
        float acc1 = b1s[kp], acc2 = b2s[kp];
        for (int kk = 0; kk < DIM; kk++) {
            acc1 += e1s[r * DIM + kk] * w1s[kk * DIM + kp];
            acc2 += e2s[r * DIM + kk] * w2s[kk * DIM + kp];
        }
        float n1v = tanhf(3.0f * acc1), n2v = tanhf(3.0f * acc2);
        float a = (k < DIM) ? n1v : -n2v;
        float b = (k < DIM) ? n2v : n1v;
        unsigned short u0 = f2bf(a); float ra = a - bf2f(u0);
        unsigned short u1 = f2bf(ra); ra -= bf2f(u1);
        unsigned short u2 = f2bf(ra);
        unsigned short v0 = f2bf(b); float rb = b - bf2f(v0);
        unsigned short v1 = f2bf(rb); rb -= bf2f(v1);
        unsigned short v2 = f2bf(rb);
        unsigned short uu[3] = {u0, u1, u2}, vv[3] = {v0, v1, v2};
        #pragma unroll
        for (int bq = 0; bq < 6; bq++) {
            Ul[r][80 * bq + k] = uu[PMAP[bq]];
            Vl[r][80 * bq + k] = vv[QMAP[bq]];
        }
    }
    {   // zero-pad 480..511
        int c = tid & 15;
        Ul[r][480 + c * 2]     = 0; Vl[r][480 + c * 2]     = 0;
        Ul[r][480 + c * 2 + 1] = 0; Vl[r][480 + c * 2 + 1] = 0;
    }
    __syncthreads();
    #pragma unroll
    for (int q = 0; q < 4; q++) {           // 16*512/8 = 1024 chunks
        int idx = q * 256 + tid;
        int rr = idx >> 6, c8 = idx & 63;
        size_t off = ((size_t)(node0 + rr)) * KADJ + c8 * 8;
        *(s16x8*)(Ux + off) = *(s16x8*)&Ul[rr][c8 * 8];
        *(s16x8*)(Vx + off) = *(s16x8*)&Vl[rr][c8 * 8];
    }
}

// ---------------- adjacency GEMM, 256x256 gemm8-structure, K=512 (R10 proven) ----------------
__global__ __launch_bounds__(512, 2) void gemm_adj8(
    const unsigned short* __restrict__ A, const unsigned short* __restrict__ Bt,
    unsigned short* __restrict__ MT, int* __restrict__ deg)
{
    constexpr int K = KADJ;        // 512
    constexpr int NT = K / 64;     // 8 K-tiles
    __shared__ __align__(16) unsigned short As[2][256 * 64];
    __shared__ __align__(16) unsigned short Bs[2][256 * 64];

    const int tid = threadIdx.x;
    const int lane = tid & 63;
    const int w = tid >> 6;
    const int wm = w >> 2, wn = w & 3;
    const int fr = lane & 15, kg = lane >> 4;

    const int bid = blockIdx.x;
    const int swz = (bid & 7) * 32 + (bid >> 3);
    const int bx = swz & 15, by = swz >> 4;
    const int c0 = bx * 256, j0 = by * 256;

    const int cid0 = w * 128 + lane, cid1 = cid0 + 64;
    const int r0 = cid0 >> 3, k0c = cid0 & 7;
    const int r1 = cid1 >> 3, k1c = cid1 & 7;
    const int so0 = r0 * K + ((k0c ^ (r0 & 7)) << 3);
    const int so1 = r1 * K + ((k1c ^ (r1 & 7)) << 3);
    const int lb0 = (w * 2 + 0) * 512;
    const int lb1 = (w * 2 + 1) * 512;

    const unsigned short* Aj = A + (size_t)j0 * K;
    const unsigned short* Bc = Bt + (size_t)c0 * K;

#define STAGE_A(buf, half, kt) do { \
    const unsigned short* g_ = Aj + (size_t)((half) * 128) * K + (kt); \
    gload16(g_ + so0, &As[buf][(half) * 8192 + lb0]); \
    gload16(g_ + so1, &As[buf][(half) * 8192 + lb1]); } while (0)
#define STAGE_B(buf, half, kt) do { \
    const unsigned short* g_ = Bc + (size_t)((half) * 128) * K + (kt); \
    gload16(g_ + so0, &Bs[buf][(half) * 8192 + lb0]); \
    gload16(g_ + so1, &Bs[buf][(half) * 8192 + lb1]); } while (0)

    STAGE_A(0, 0, 0);  STAGE_A(0, 1, 0);
    STAGE_B(0, 0, 0);  STAGE_B(0, 1, 0);
    STAGE_A(1, 0, 64); STAGE_A(1, 1, 64);
    STAGE_B(1, 0, 64);
    asm volatile("s_waitcnt vmcnt(6)" ::: "memory");
    bar();

    const int x0 = ((kg) ^ (fr & 7)) << 4;
    const int x1 = ((4 + kg) ^ (fr & 7)) << 4;
    int aOff[8], bOff[4];
    #pragma unroll
    for (int m = 0; m < 8; m++) aOff[m] = (wm * 128 + m * 16 + fr) * 128;
    #pragma unroll
    for (int n = 0; n < 4; n++) bOff[n] = (wn * 64 + n * 16 + fr) * 128;

    s16x8 af0c[4], bf0c[4];
    #pragma unroll
    for (int m = 0; m < 4; m++) af0c[m] = *(const s16x8*)((const char*)As[0] + aOff[m] + x0);
    #pragma unroll
    for (int n = 0; n < 4; n++) bf0c[n] = *(const s16x8*)((const char*)Bs[0] + bOff[n] + x0);

    f32x4 acc[8][4] = {};

    for (int t = 0; t < NT; t++) {
        const int P = t & 1;
        const char* Ap = (const char*)As[P];
        const char* Bp = (const char*)Bs[P];
        const char* Aq = (const char*)As[P ^ 1];
        const char* Bq = (const char*)Bs[P ^ 1];
        const int kt1 = (t + 1) * 64, kt2 = (t + 2) * 64;
        const bool s1 = (t + 1) < NT, s2 = (t + 2) < NT;
        s16x8 af0h[4], af1l[4], af1h[4], bf1[4], af0n[4], bf0n[4];

        #pragma unroll
        for (int m = 0; m < 4; m++) af0h[m] = *(const s16x8*)(Ap + aOff[m + 4] + x0);
        #pragma unroll
        for (int m = 0; m < 4; m++) af1l[m] = *(const s16x8*)(Ap + aOff[m] + x1);
        if (s1) STAGE_B(P ^ 1, 1, kt1);
        __builtin_amdgcn_s_setprio(1);
        #pragma unroll
        for (int m = 0; m < 4; m++)
            #pragma unroll
            for (int n = 0; n < 4; n++)
                acc[m][n] = __builtin_amdgcn_mfma_f32_16x16x32_bf16(af0c[m], bf0c[n], acc[m][n], 0, 0, 0);
        __builtin_amdgcn_s_setprio(0);

        #pragma unroll
        for (int m = 0; m < 4; m++) af1h[m] = *(const s16x8*)(Ap + aOff[m + 4] + x1);
        #pragma unroll
        for (int n = 0; n < 4; n++) bf1[n] = *(const s16x8*)(Bp + bOff[n] + x1);
        __builtin_amdgcn_s_setprio(1);
        #pragma unroll
        for (int m = 4; m < 8; m++)
            #pragma unroll
            for (int n = 0; n < 4; n++)
                acc[m][n] = __builtin_amdgcn_mfma_f32_16x16x32_bf16(af0h[m - 4], bf0c[n], acc[m][n], 0, 0, 0);
        __builtin_amdgcn_s_setprio(0);
        asm volatile("s_waitcnt lgkmcnt(0)" ::: "memory");
        bar();

        __builtin_amdgcn_s_setprio(1);
        #pragma unroll
        for (int m = 0; m < 4; m++)
            #pragma unroll
            for (int n = 0; n < 4; n++)
                acc[m][n] = __builtin_amdgcn_mfma_f32_16x16x32_bf16(af1l[m], bf1[n], acc[m][n], 0, 0, 0);
        __builtin_amdgcn_s_setprio(0);
        if (s2) {
            STAGE_A(P, 0, kt2);
            STAGE_A(P, 1, kt2);
            STAGE_B(P, 0, kt2);
            asm volatile("s_waitcnt vmcnt(6)" ::: "memory");
        } else {
            asm volatile("s_waitcnt vmcnt(0)" ::: "memory");
        }
        bar();

        if (s1) {
            #pragma unroll
            for (int m = 0; m < 4; m++) af0n[m] = *(const s16x8*)(Aq + aOff[m] + x0);
            #pragma unroll
            for (int n = 0; n < 4; n++) bf0n[n] = *(const s16x8*)(Bq + bOff[n] + x0);
        }
        __builtin_amdgcn_s_setprio(1);
        #pragma unroll
        for (int m = 4; m < 8; m++)
            #pragma unroll
            for (int n = 0; n < 4; n++)
                acc[m][n] = __builtin_amdgcn_mfma_f32_16x16x32_bf16(af1h[m - 4], bf1[n], acc[m][n], 0, 0, 0);
        __builtin_amdgcn_s_setprio(0);
        if (s1) {
            #pragma unroll
            for (int m = 0; m < 4; m++) af0c[m] = af0n[m];
            #pragma unroll
            for (int n = 0; n < 4; n++) bf0c[n] = bf0n[n];
        }
    }
#undef STAGE_A
#undef STAGE_B

    #pragma unroll
    for (int m = 0; m < 8; m++) {
        int rbase = j0 + wm * 128 + m * 16 + kg * 4;
        #pragma unroll
        for (int r = 0; r < 4; r++) {
            int row = rbase + r;
            int cnt = 0;
            #pragma unroll
            for (int n = 0; n < 4; n++) {
                int col = c0 + wn * 64 + n * 16 + fr;
                bool bit = (acc[m][n][r] > 0.f) || (row == col);
                MT[(size_t)row * NN + col] = bit ? (unsigned short)0x3F80 : (unsigned short)0;
                cnt += bit ? 1 : 0;
            }
            cnt += __shfl_xor(cnt, 1);
            cnt += __shfl_xor(cnt, 2);
            cnt += __shfl_xor(cnt, 4);
            cnt += __shfl_xor(cnt, 8);
            if (fr == 0) atomicAdd(&deg[row], cnt);
        }
    }
}

__global__ void k_dinv(const int* __restrict__ deg, float* __restrict__ dinv) {
    int i = blockIdx.x * 256 + threadIdx.x;
    if (i < NN) dinv[i] = 1.0f / sqrtf((float)deg[i]);
}

// ---------------- YT[c=b*128+f][i] = bf16( dinv_i * (x[b,i,:] @ W1[:,f]) ) ----------------
__global__ __launch_bounds__(256) void k_y1(
    const float* __restrict__ x, const float* __restrict__ W1,
    const float* __restrict__ dinv, unsigned short* __restrict__ YT)
{
    __shared__ __align__(16) float xs[128][DIN];
    __shared__ __align__(16) float w1s[DIN][DH];
    int i0 = blockIdx.x * 128, b = blockIdx.y;
    int tid = threadIdx.x;
    const f32x4* xg = (const f32x4*)(x + ((size_t)(b * NN + i0)) * DIN);
    #pragma unroll
    for (int q = 0; q < 8; q++) {
        int idx = q * 256 + tid;
        int row = idx >> 4, c4 = idx & 15;
        *(f32x4*)&xs[row][c4 * 4] = xg[(size_t)row * 16 + c4];
    }
    #pragma unroll
    for (int q = 0; q < 8; q++) {
        int idx = q * 256 + tid;
        int row = idx >> 5, c4 = idx & 31;
        *(f32x4*)&w1s[row][c4 * 4] = ((const f32x4*)W1)[idx];
    }
    __syncthreads();
    int tf = tid & 15, ti = tid >> 4;
    f32x4 t0[8] = {}, t1[8] = {};
    for (int k4 = 0; k4 < DIN; k4 += 4) {
        f32x4 xv[8];
        #pragma unroll
        for (int ii = 0; ii < 8; ii++) xv[ii] = *(const f32x4*)&xs[ti * 8 + ii][k4];
        #pragma unroll
        for (int kk = 0; kk < 4; kk++) {
            f32x4 w0 = *(const f32x4*)&w1s[k4 + kk][tf * 8];
            f32x4 w1v = *(const f32x4*)&w1s[k4 + kk][tf * 8 + 4];
            #pragma unroll
            for (int ii = 0; ii < 8; ii++) {
                float s = xv[ii][kk];
                t0[ii] += s * w0;
                t1[ii] += s * w1v;
            }
        }
    }
    float dvv[8];
    #pragma unroll
    for (int ii = 0; ii < 8; ii++) dvv[ii] = dinv[i0 + ti * 8 + ii];
    #pragma unroll
    for (int ff = 0; ff < 8; ff++) {
        s16x8 pk;
        #pragma unroll
        for (int ii = 0; ii < 8; ii++) {
            float v = (ff < 4 ? t0[ii][ff] : t1[ii][ff - 4]) * dvv[ii];
            pk[ii] = (short)f2bf(v);
        }
        *(s16x8*)(YT + ((size_t)(b * DH + tf * 8 + ff)) * NN + i0 + ti * 8) = pk;
    }
}

// ======== gemm1: 256x256, BK=64, 8 waves; m201-style 8-phase quadrant schedule ========
// Tiles: T(even)->buf0, T+1->buf1 always. Per phase: {reads(<=12); stage 1 Q-unit;
// [vmcnt]; barrier; setprio; 16 MFMA; setprio; barrier}.
// Q-units match consumption: A-Q(q) = rows q*64+[0,64) U q*64+128+[0,64) (every wave's mh_q);
// B-Q(nh) = rows b*64+nh*32+[0,32), b=0..3 (every wn's nh).
// Slots: ph1:AQ0(T+1)->b1, ph2:AQ1(T+1)->b1, ph3:BQ0(T+2)->b0, ph4:BQ1(T+2)+vmcnt(4),
//        ph5:AQ0(T+2)->b0, ph6:AQ1(T+2)->b0, ph7:BQ0(T+3)->b1, ph8:BQ1(T+3)+vmcnt(4).
// Overwrite audit: each unit staged >=1 barrier after its last reader phase.
// Landing audit: vmcnt(4)@ph4 lands {BQ0,BQ1,AQ0,AQ1}(T+1) before ph5; vmcnt(4)@ph8
// lands all of T+2 before next ph1. Prologue: T0 all + BQ(1); vmcnt(4).
__global__ __launch_bounds__(512, 2) void gemm8q(
    const unsigned short* __restrict__ A, const unsigned short* __restrict__ Bt,
    unsigned short* __restrict__ H, const float* __restrict__ dinv,
    const float* __restrict__ bias)
{
    constexpr int K = NN;          // 4096
    constexpr int NT = K / 64;     // 64 K-tiles
    __shared__ __align__(16) unsigned short As[2][256 * 64];   // 64 KB
    __shared__ __align__(16) unsigned short Bs[2][256 * 64];   // 64 KB

    const int tid = threadIdx.x;
    const int lane = tid & 63;
    const int w = tid >> 6;
    const int wm = w >> 2, wn = w & 3;      // 2 x 4 wave grid, wave tile 128x64
    const int fr = lane & 15, kg = lane >> 4;

    const int bid = blockIdx.x;
    const int swz = (bid & 7) * 32 + (bid >> 3);
    const int bx = swz & 15, by = swz >> 4;
    const int c0 = bx * 256, j0 = by * 256;

    const unsigned short* Aj = A + (size_t)j0 * K;
    const unsigned short* Bc = Bt + (size_t)c0 * K;

    const int lr = tid >> 3, kcs = tid & 7;   // stage coords (tid < 512)

#define STAGE_AQ(buf, q, kt) do { \
    int ra_ = (q) * 64 + lr; \
    int rb_ = ra_ + 128; \
    gload16(Aj + (size_t)ra_ * K + (kt) + ((kcs ^ (ra_ & 7)) << 3), \
            &As[buf][(q) * 4096 + tid * 8]); \
    gload16(Aj + (size_t)rb_ * K + (kt) + ((kcs ^ (rb_ & 7)) << 3), \
            &As[buf][(q) * 4096 + 8192 + tid * 8]); \
} while (0)
#define STAGE_BQ(buf, nh, kt) do { \
    int ca_ = tid, cb_ = tid + 512; \
    int r0_ = (ca_ >> 8) * 64 + (nh) * 32 + ((ca_ >> 3) & 31); \
    int r1_ = (cb_ >> 8) * 64 + (nh) * 32 + ((cb_ >> 3) & 31); \
    gload16(Bc + (size_t)r0_ * K + (kt) + (((ca_ & 7) ^ (r0_ & 7)) << 3), \
            &Bs[buf][(ca_ >> 8) * 4096 + (nh) * 2048 + (ca_ & 255) * 8]); \
    gload16(Bc + (size_t)r1_ * K + (kt) + (((cb_ & 7) ^ (r1_ & 7)) << 3), \
            &Bs[buf][(cb_ >> 8) * 4096 + (nh) * 2048 + (cb_ & 255) * 8]); \
} while (0)

    // prologue: T0 all 4 units + BQ0(1), BQ1(1); land T0, leave BQ(1) in flight.
    STAGE_AQ(0, 0, 0); STAGE_AQ(0, 1, 0);
    STAGE_BQ(0, 0, 0); STAGE_BQ(0, 1, 0);
    STAGE_BQ(1, 0, 64); STAGE_BQ(1, 1, 64);
    asm volatile("s_waitcnt vmcnt(4)" ::: "memory");
    bar();

    const int x0 = ((kg) ^ (fr & 7)) << 4;
    const int x1 = ((4 + kg) ^ (fr & 7)) << 4;
    int aOff[8], bOff[4];
    #pragma unroll
    for (int m = 0; m < 8; m++) aOff[m] = (wm * 128 + m * 16 + fr) * 128;
    #pragma unroll
    for (int n = 0; n < 4; n++) bOff[n] = (wn * 64 + n * 16 + fr) * 128;

    f32x4 acc[8][4] = {};
    const char* A0p = (const char*)As[0];
    const char* B0p = (const char*)Bs[0];
    const char* A1p = (const char*)As[1];
    const char* B1p = (const char*)Bs[1];

#define MFMA_Q(MB, NB_, AF0, AF1, BK0, BK1) do { \
    __builtin_amdgcn_s_setprio(1); \
    _Pragma("unroll") \
    for (int m = 0; m < 4; m++) { \
        _Pragma("unroll") \
        for (int n = 0; n < 2; n++) { \
            acc[(MB) + m][(NB_) + n] = __builtin_amdgcn_mfma_f32_16x16x32_bf16( \
                AF0[m], BK0[n], acc[(MB) + m][(NB_) + n], 0, 0, 0); \
            acc[(MB) + m][(NB_) + n] = __builtin_amdgcn_mfma_f32_16x16x32_bf16( \
                AF1[m], BK1[n], acc[(MB) + m][(NB_) + n], 0, 0, 0); \
        } \
    } \
    __builtin_amdgcn_s_setprio(0); \
} while (0)

    s16x8 af0[4], af1[4], b0k0[2], b0k1[2], b1k0[2], b1k1[2];

    for (int T = 0; T < NT; T += 2) {
        const bool s2 = (T + 2) < NT, s3 = (T + 3) < NT;
        const int kt1 = (T + 1) * 64, kt2 = (T + 2) * 64, kt3 = (T + 3) * 64;

        // ---- ph1: A-mh0 + B-nh0 (buf0); stage AQ0(T+1); MFMA m0-3 x n0-1
        #pragma unroll
        for (int m = 0; m < 4; m++) { af0[m] = *(const s16x8*)(A0p + aOff[m] + x0);
                                      af1[m] = *(const s16x8*)(A0p + aOff[m] + x1); }
        #pragma unroll
        for (int n = 0; n < 2; n++) { b0k0[n] = *(const s16x8*)(B0p + bOff[n] + x0);
                                      b0k1[n] = *(const s16x8*)(B0p + bOff[n] + x1); }
        STAGE_AQ(1, 0, kt1);
        bar();
        MFMA_Q(0, 0, af0, af1, b0k0, b0k1);
        bar();

        // ---- ph2: B-nh1; stage AQ1(T+1); MFMA m0-3 x n2-3
        #pragma unroll
        for (int n = 0; n < 2; n++) { b1k0[n] = *(const s16x8*)(B0p + bOff[n + 2] + x0);
                                      b1k1[n] = *(const s16x8*)(B0p + bOff[n + 2] + x1); }
        STAGE_AQ(1, 1, kt1);
        bar();
        MFMA_Q(0, 2, af0, af1, b1k0, b1k1);
        bar();

        // ---- ph3: A-mh1; stage BQ0(T+2); MFMA m4-7 x n0-1
        #pragma unroll
        for (int m = 0; m < 4; m++) { af0[m] = *(const s16x8*)(A0p + aOff[m + 4] + x0);
                                      af1[m] = *(const s16x8*)(A0p + aOff[m + 4] + x1); }
        if (s2) STAGE_BQ(0, 0, kt2);
        bar();
        MFMA_Q(4, 0, af0, af1, b0k0, b0k1);
        bar();

        // ---- ph4: stage BQ1(T+2); vmcnt -> T+1 fully landed; MFMA m4-7 x n2-3
        if (s2) { STAGE_BQ(0, 1, kt2);
                  asm volatile("s_waitcnt vmcnt(4)" ::: "memory"); }
        else    { asm volatile("s_waitcnt vmcnt(0)" ::: "memory"); }
        bar();
        MFMA_Q(4, 2, af0, af1, b1k0, b1k1);
        bar();

        // ---- ph5: tile T+1 (buf1): A-mh0 + B-nh0; stage AQ0(T+2); MFMA m0-3 x n0-1
        #pragma unroll
        for (int m = 0; m < 4; m++) { af0[m] = *(const s16x8*)(A1p + aOff[m] + x0);
                                      af1[m] = *(const s16x8*)(A1p + aOff[m] + x1); }
        #pragma unroll
        for (int n = 0; n < 2; n++) { b0k0[n] = *(const s16x8*)(B1p + bOff[n] + x0);
                                      b0k1[n] = *(const s16x8*)(B1p + bOff[n] + x1); }
        if (s2) STAGE_AQ(0, 0, kt2);
        bar();
        MFMA_Q(0, 0, af0, af1, b0k0, b0k1);
        bar();

        // ---- ph6: B-nh1; stage AQ1(T+2); MFMA m0-3 x n2-3
        #pragma unroll
        for (int n = 0; n < 2; n++) { b1k0[n] = *(const s16x8*)(B1p + bOff[n + 2] + x0);
                                      b1k1[n] = *(const s16x8*)(B1p + bOff[n + 2] + x1); }
        if (s2) STAGE_AQ(0, 1, kt2);
        bar();
        MFMA_Q(0, 2, af0, af1, b1k0, b1k1);
        bar();

        // ---- ph7: A-mh1; stage BQ0(T+3); MFMA m4-7 x n0-1
        #pragma unroll
        for (int m = 0; m < 4; m++) { af0[m] = *(const s16x8*)(A1p + aOff[m + 4] + x0);
                                      af1[m] = *(const s16x8*)(A1p + aOff[m + 4] + x1); }
        if (s3) STAGE_BQ(1, 0, kt3);
        bar();
        MFMA_Q(4, 0, af0, af1, b0k0, b0k1);
        bar();

        // ---- ph8: stage BQ1(T+3); vmcnt -> T+2 fully landed; MFMA m4-7 x n2-3
        if (s3) { STAGE_BQ(1, 1, kt3);
                  asm volatile("s_waitcnt vmcnt(4)" ::: "memory"); }
        else    { asm volatile("s_waitcnt vmcnt(0)" ::: "memory"); }
        bar();
        MFMA_Q(4, 2, af0, af1, b1k0, b1k1);
        bar();
    }
#undef MFMA_Q
#undef STAGE_AQ
#undef STAGE_BQ

    // epilogue: row = (lane>>4)*4 + r, col = lane&15 per 16x16 frag
    #pragma unroll
    for (int m = 0; m < 8; m++) {
        int rbase = j0 + wm * 128 + m * 16 + kg * 4;
        float dv[4];
        #pragma unroll
        for (int r = 0; r < 4; r++) dv[r] = dinv[rbase + r];
        #pragma unroll
        for (int n = 0; n < 4; n++) {
            int gcol = c0 + wn * 64 + n * 16 + fr;
            float bb = bias[gcol & (DH - 1)];
            #pragma unroll
            for (int r = 0; r < 4; r++) {
                float v = acc[m][n][r] * dv[r] + bb;
                v = v > 0.f ? v : 0.f;
                H[(size_t)(rbase + r) * NN + gcol] = f2bf(v);
            }
        }
    }
}

// ---------- k_z2: MFMA-based ZT = dinv_j * (H_b @ W2) ----------
__global__ __launch_bounds__(256) void k_z2(
    const unsigned short* __restrict__ H, const float* __restrict__ W2,
    const float* __restrict__ dinv, unsigned short* __restrict__ ZT)
{
    __shared__ __align__(16) unsigned short Hs[128 * DH];     // 32 KB
    __shared__ __align__(16) unsigned short W2Ts[DOUT * DH];  // 8 KB
    const int tid = threadIdx.x;
    const int j0 = blockIdx.x * 128, b = blockIdx.y;
    const unsigned short* Hb = H + (size_t)j0 * NN + b * DH;

    #pragma unroll
    for (int q = 0; q < 8; q++) {
        int cid = q * 256 + tid;
        int row = cid >> 4, kc = cid & 15;
        gload16(Hb + (size_t)row * NN + kc * 8, &Hs[cid * 8]);
    }
    #pragma unroll
    for (int q = 0; q < 16; q++) {
        int idx = q * 256 + tid;
        int f = idx >> 5, g = idx & 31;
        W2Ts[g * DH + f] = f2bf(W2[f * DOUT + g]);
    }
    __syncthreads();

    const int lane = tid & 63, w = tid >> 6;
    const int fr = lane & 15, kg = lane >> 4;
    f32x4 acc[2][2] = {};
    #pragma unroll
    for (int ks = 0; ks < 4; ks++) {
        s16x8 af[2], bf[2];
        #pragma unroll
        for (int mt = 0; mt < 2; mt++) {
            int row = w * 32 + mt * 16 + fr;
            af[mt] = *(const s16x8*)&Hs[row * DH + ks * 32 + kg * 8];
        }
        #pragma unroll
        for (int nt = 0; nt < 2; nt++) {
            int g = nt * 16 + fr;
            bf[nt] = *(const s16x8*)&W2Ts[g * DH + ks * 32 + kg * 8];
        }
        #pragma unroll
        for (int mt = 0; mt < 2; mt++)
            #pragma unroll
            for (int nt = 0; nt < 2; nt++)
                acc[mt][nt] = __builtin_amdgcn_mfma_f32_16x16x32_bf16(af[mt], bf[nt], acc[mt][nt], 0, 0, 0);
    }
    #pragma unroll
    for (int mt = 0; mt < 2; mt++) {
        int jbase = j0 + w * 32 + mt * 16 + kg * 4;
        float dv[4];
        #pragma unroll
        for (int r = 0; r < 4; r++) dv[r] = dinv[jbase + r];
        #pragma unroll
        for (int nt = 0; nt < 2; nt++) {
            int g = nt * 16 + fr;
            s16x4 pk;
            #pragma unroll
            for (int r = 0; r < 4; r++)
                pk[r] = (short)f2bf(acc[mt][nt][r] * dv[r]);
            *(s16x4*)(ZT + (size_t)(b * DOUT + g) * NN + jbase) = pk;
        }
    }
}

// ---------- gemm2: 64x128 tile (2 blocks/CU) with FUSED softmax epilogue ----------
__global__ __launch_bounds__(256) void gemm_sm(
    const unsigned short* __restrict__ A, const unsigned short* __restrict__ Bt,
    float* __restrict__ out, const float* __restrict__ dinv,
    const float* __restrict__ bias, int K)
{
    constexpr int BK = 64;
    __shared__ __align__(16) unsigned short Asm[64 * BK];    // 8 KB
    __shared__ __align__(16) unsigned short Bsm[128 * BK];   // 16 KB
    const int tid = threadIdx.x;
    const int lane = tid & 63;
    const int w = tid >> 6;
    const int wm = w >> 1, wn = w & 1;     // 2 x 2 wave grid; per-wave 32 x 64
    const int c0 = blockIdx.x * 128;
    const int j0 = blockIdx.y * 64;

    int srcA[2], srcB[4];
    #pragma unroll
    for (int q = 0; q < 2; q++) {
        int cid = q * 256 + tid;
        int row = cid >> 3, kc = cid & 7;
        srcA[q] = row * K + ((kc ^ (row & 7)) << 3);
    }
    #pragma unroll
    for (int q = 0; q < 4; q++) {
        int cid = q * 256 + tid;
        int row = cid >> 3, kc = cid & 7;
        srcB[q] = row * K + ((kc ^ (row & 7)) << 3);
    }
    const int fr = lane & 15;
    const int kg = lane >> 4;

    f32x4 acc[2][4] = {};
    const unsigned short* Abase = A + (size_t)j0 * K;
    const unsigned short* Bbase = Bt + (size_t)c0 * K;

    for (int kt = 0; kt < K; kt += BK) {
        __syncthreads();
        const unsigned short* Ag = Abase + kt;
        const unsigned short* Bg = Bbase + kt;
        #pragma unroll
        for (int q = 0; q < 2; q++)
            gload16(Ag + srcA[q], &Asm[(q * 256 + tid) * 8]);
        #pragma unroll
        for (int q = 0; q < 4; q++)
            gload16(Bg + srcB[q], &Bsm[(q * 256 + tid) * 8]);
        __syncthreads();

        s16x8 af[2][2], bf[2][4];
        #pragma unroll
        for (int ks = 0; ks < 2; ks++) {
            int kc = ks * 4 + kg;
            #pragma unroll
            for (int m = 0; m < 2; m++) {
                int row = wm * 32 + m * 16 + fr;
                af[ks][m] = *(const s16x8*)((const char*)Asm + row * 128 + ((kc ^ (row & 7)) << 4));
            }
            #pragma unroll
            for (int n = 0; n < 4; n++) {
                int row = wn * 64 + n * 16 + fr;
                bf[ks][n] = *(const s16x8*)((const char*)Bsm + row * 128 + ((kc ^ (row & 7)) << 4));
            }
        }
        #pragma unroll
        for (int ks = 0; ks < 2; ks++)
            #pragma unroll
            for (int m = 0; m < 2; m++)
                #pragma unroll
                for (int n = 0; n < 4; n++)
                    acc[m][n] = __builtin_amdgcn_mfma_f32_16x16x32_bf16(
                        af[ks][m], bf[ks][n], acc[m][n], 0, 0, 0);
    }

    const float b_lo = bias[fr], b_hi = bias[fr + 16];
    #pragma unroll
    for (int m = 0; m < 2; m++) {
        int rbase = j0 + wm * 32 + m * 16 + kg * 4;
        float dv[4];
        #pragma unroll
        for (int r = 0; r < 4; r++) dv[r] = dinv[rbase + r];
        #pragma unroll
        for (int np = 0; np < 2; np++) {
            int bg = (c0 >> 5) + wn * 2 + np;       // batch index 0..31
            #pragma unroll
            for (int r = 0; r < 4; r++) {
                int row = rbase + r;                 // node j
                float v0 = acc[m][np * 2][r]     * dv[r] + b_lo;   // g = fr
                float v1 = acc[m][np * 2 + 1][r] * dv[r] + b_hi;   // g = fr+16
                float mx = fmaxf(v0, v1);
                #pragma unroll
                for (int d = 8; d; d >>= 1) mx = fmaxf(mx, __shfl_xor(mx, d));
                float e0 = expf(v0 - mx), e1 = expf(v1 - mx);
                float s = e0 + e1;
                #pragma unroll
                for (int d = 8; d; d >>= 1) s += __shfl_xor(s, d);
                float inv = 1.0f / s;
                size_t ob = ((size_t)bg * NN + row) * DOUT;
                out[ob + fr]      = e0 * inv;
                out[ob + fr + 16] = e1 * inv;
            }
        }
    }
}

extern "C" void kernel_launch(void* const* d_in, const int* in_sizes, int n_in,
                              void* d_out, int out_size, void* d_ws, size_t ws_size,
                              hipStream_t stream)
{
    (void)in_sizes; (void)n_in; (void)out_size; (void)ws_size;
    const float* x    = (const float*)d_in[0];
    const float* emb1 = (const float*)d_in[1];
    const float* emb2 = (const float*)d_in[2];
    const float* l1w  = (const float*)d_in[3];
    const float* l1b  = (const float*)d_in[4];
    const float* l2w  = (const float*)d_in[5];
    const float* l2b  = (const float*)d_in[6];
    const float* g1w  = (const float*)d_in[7];
    const float* g1b  = (const float*)d_in[8];
    const float* g2w  = (const float*)d_in[9];
    const float* g2b  = (const float*)d_in[10];
    float* out = (float*)d_out;

    char* w = (char*)d_ws;
    int* deg = (int*)w;                       w += NN * 4;
    float* dinv = (float*)w;                  w += NN * 4;
    unsigned short* MT = (unsigned short*)w;  w += (size_t)NN * NN * 2;
    unsigned short* YT = (unsigned short*)w;  w += (size_t)NN * NN * 2;
    unsigned short* H  = (unsigned short*)w;  w += (size_t)NN * NN * 2;
    unsigned short* ZT = (unsigned short*)w;  w += (size_t)(NB * DOUT) * NN * 2;
    // Ux/Vx live in YT's region (dead until k_y1, which runs after gemm_adj8)
    unsigned short* Ux = YT;
    unsigned short* Vx = YT + (size_t)NN * KADJ;

    hipMemsetAsync(deg, 0, NN * sizeof(int), stream);
    k_embuv<<<256, 256, 0, stream>>>(emb1, emb2, l1w, l1b, l2w, l2b, Ux, Vx);
    gemm_adj8<<<256, 512, 0, stream>>>(Vx, Ux, MT, deg);
    k_dinv<<<16, 256, 0, stream>>>(deg, dinv);
    k_y1<<<dim3(32, 32), 256, 0, stream>>>(x, g1w, dinv, YT);
    gemm8q<<<256, 512, 0, stream>>>(MT, YT, H, dinv, g1b);
    k_z2<<<dim3(32, 32), 256, 0, stream>>>(H, g2w, dinv, ZT);
    gemm_sm<<<dim3(8, 64), 256, 0, stream>>>(MT, ZT, out, dinv, g2b, NN);
}

// Round 12
// 260.816 us; speedup vs baseline: 1.2334x; 1.0479x over previous
//
#include <hip/hip_runtime.h>

typedef float f32x4 __attribute__((ext_vector_type(4)));
typedef short s16x8 __attribute__((ext_vector_type(8)));
typedef short s16x4 __attribute__((ext_vector_type(4)));

#define NN 4096
#define NB 32
#define DIN 64
#define DH 128
#define DOUT 32
#define DIM 40
#define KADJ 512   // 6 split-blocks x 80, zero-padded to 512

__device__ __forceinline__ unsigned short f2bf(float f) {
    unsigned int u = __float_as_uint(f);
    unsigned int r = (u + 0x7FFFu + ((u >> 16) & 1u)) >> 16;
    return (unsigned short)r;
}
__device__ __forceinline__ float bf2f(unsigned short h) {
    return __uint_as_float(((unsigned int)h) << 16);
}
__device__ __forceinline__ void gload16(const void* g, void* l) {
    __builtin_amdgcn_global_load_lds(
        (const __attribute__((address_space(1))) unsigned int*)g,
        (__attribute__((address_space(3))) unsigned int*)l, 16, 0, 0);
}
__device__ __forceinline__ void bar() {
    asm volatile("" ::: "memory");
    __builtin_amdgcn_s_barrier();
    asm volatile("" ::: "memory");
}

// ---------------- fused: n1/n2 = tanh(3*(emb @ W + b)) -> 3-way bf16 split operands ----------------
// Also zeroes deg[] (runs before gemm_adj8 in stream order).
__global__ __launch_bounds__(256) void k_embuv(
    const float* __restrict__ emb1, const float* __restrict__ emb2,
    const float* __restrict__ l1w, const float* __restrict__ l1b,
    const float* __restrict__ l2w, const float* __restrict__ l2b,
    unsigned short* __restrict__ Ux, unsigned short* __restrict__ Vx,
    int* __restrict__ deg)
{
    __shared__ float e1s[16 * DIM], e2s[16 * DIM];
    __shared__ float w1s[DIM * DIM], w2s[DIM * DIM], b1s[DIM], b2s[DIM];
    __shared__ unsigned short Ul[16][KADJ], Vl[16][KADJ];
    const int tid = threadIdx.x;
    const int node0 = blockIdx.x * 16;
    if (tid < 16) deg[node0 + tid] = 0;
    for (int i = tid; i < 16 * DIM; i += 256) {
        e1s[i] = emb1[node0 * DIM + i];
        e2s[i] = emb2[node0 * DIM + i];
    }
    for (int i = tid; i < DIM * DIM; i += 256) { w1s[i] = l1w[i]; w2s[i] = l2w[i]; }
    if (tid < DIM) { b1s[tid] = l1b[tid]; b2s[tid] = l2b[tid]; }
    __syncthreads();
    const int r = tid >> 4;                 // local node 0..15
    const int k0 = (tid & 15) * 5;          // 5 k's per thread (80 total)
    const int PMAP[6] = {0, 0, 1, 1, 0, 2};
    const int QMAP[6] = {0, 1, 0, 1, 2, 0};
    #pragma unroll
    for (int e = 0; e < 5; e++) {
        int k = k0 + e;
        int kp = (k < DIM) ? k : k - DIM;
        float acc1 = b1s[kp], acc2 = b2s[kp];
        for (int kk = 0; kk < DIM; kk++) {
            acc1 += e1s[r * DIM + kk] * w1s[kk * DIM + kp];
            acc2 += e2s[r * DIM + kk] * w2s[kk * DIM + kp];
        }
        float n1v = tanhf(3.0f * acc1), n2v = tanhf(3.0f * acc2);
        float a = (k < DIM) ? n1v : -n2v;
        float b = (k < DIM) ? n2v : n1v;
        unsigned short u0 = f2bf(a); float ra = a - bf2f(u0);
        unsigned short u1 = f2bf(ra); ra -= bf2f(u1);
        unsigned short u2 = f2bf(ra);
        unsigned short v0 = f2bf(b); float rb = b - bf2f(v0);
        unsigned short v1 = f2bf(rb); rb -= bf2f(v1);
        unsigned short v2 = f2bf(rb);
        unsigned short uu[3] = {u0, u1, u2}, vv[3] = {v0, v1, v2};
        #pragma unroll
        for (int bq = 0; bq < 6; bq++) {
            Ul[r][80 * bq + k] = uu[PMAP[bq]];
            Vl[r][80 * bq + k] = vv[QMAP[bq]];
        }
    }
    {   // zero-pad 480..511
        int c = tid & 15;
        Ul[r][480 + c * 2]     = 0; Vl[r][480 + c * 2]     = 0;
        Ul[r][480 + c * 2 + 1] = 0; Vl[r][480 + c * 2 + 1] = 0;
    }
    __syncthreads();
    #pragma unroll
    for (int q = 0; q < 4; q++) {           // 16*512/8 = 1024 chunks
        int idx = q * 256 + tid;
        int rr = idx >> 6, c8 = idx & 63;
        size_t off = ((size_t)(node0 + rr)) * KADJ + c8 * 8;
        *(s16x8*)(Ux + off) = *(s16x8*)&Ul[rr][c8 * 8];
        *(s16x8*)(Vx + off) = *(s16x8*)&Vl[rr][c8 * 8];
    }
}

// ---------------- adjacency GEMM, 256x256 gemm8-structure, K=512 (R10 proven) ----------------
__global__ __launch_bounds__(512, 2) void gemm_adj8(
    const unsigned short* __restrict__ A, const unsigned short* __restrict__ Bt,
    unsigned short* __restrict__ MT, int* __restrict__ deg)
{
    constexpr int K = KADJ;        // 512
    constexpr int NT = K / 64;     // 8 K-tiles
    __shared__ __align__(16) unsigned short As[2][256 * 64];
    __shared__ __align__(16) unsigned short Bs[2][256 * 64];

    const int tid = threadIdx.x;
    const int lane = tid & 63;
    const int w = tid >> 6;
    const int wm = w >> 2, wn = w & 3;
    const int fr = lane & 15, kg = lane >> 4;

    const int bid = blockIdx.x;
    const int swz = (bid & 7) * 32 + (bid >> 3);
    const int bx = swz & 15, by = swz >> 4;
    const int c0 = bx * 256, j0 = by * 256;

    const int cid0 = w * 128 + lane, cid1 = cid0 + 64;
    const int r0 = cid0 >> 3, k0c = cid0 & 7;
    const int r1 = cid1 >> 3, k1c = cid1 & 7;
    const int so0 = r0 * K + ((k0c ^ (r0 & 7)) << 3);
    const int so1 = r1 * K + ((k1c ^ (r1 & 7)) << 3);
    const int lb0 = (w * 2 + 0) * 512;
    const int lb1 = (w * 2 + 1) * 512;

    const unsigned short* Aj = A + (size_t)j0 * K;
    const unsigned short* Bc = Bt + (size_t)c0 * K;

#define STAGE_A(buf, half, kt) do { \
    const unsigned short* g_ = Aj + (size_t)((half) * 128) * K + (kt); \
    gload16(g_ + so0, &As[buf][(half) * 8192 + lb0]); \
    gload16(g_ + so1, &As[buf][(half) * 8192 + lb1]); } while (0)
#define STAGE_B(buf, half, kt) do { \
    const unsigned short* g_ = Bc + (size_t)((half) * 128) * K + (kt); \
    gload16(g_ + so0, &Bs[buf][(half) * 8192 + lb0]); \
    gload16(g_ + so1, &Bs[buf][(half) * 8192 + lb1]); } while (0)

    STAGE_A(0, 0, 0);  STAGE_A(0, 1, 0);
    STAGE_B(0, 0, 0);  STAGE_B(0, 1, 0);
    STAGE_A(1, 0, 64); STAGE_A(1, 1, 64);
    STAGE_B(1, 0, 64);
    asm volatile("s_waitcnt vmcnt(6)" ::: "memory");
    bar();

    const int x0 = ((kg) ^ (fr & 7)) << 4;
    const int x1 = ((4 + kg) ^ (fr & 7)) << 4;
    int aOff[8], bOff[4];
    #pragma unroll
    for (int m = 0; m < 8; m++) aOff[m] = (wm * 128 + m * 16 + fr) * 128;
    #pragma unroll
    for (int n = 0; n < 4; n++) bOff[n] = (wn * 64 + n * 16 + fr) * 128;

    s16x8 af0c[4], bf0c[4];
    #pragma unroll
    for (int m = 0; m < 4; m++) af0c[m] = *(const s16x8*)((const char*)As[0] + aOff[m] + x0);
    #pragma unroll
    for (int n = 0; n < 4; n++) bf0c[n] = *(const s16x8*)((const char*)Bs[0] + bOff[n] + x0);

    f32x4 acc[8][4] = {};

    for (int t = 0; t < NT; t++) {
        const int P = t & 1;
        const char* Ap = (const char*)As[P];
        const char* Bp = (const char*)Bs[P];
        const char* Aq = (const char*)As[P ^ 1];
        const char* Bq = (const char*)Bs[P ^ 1];
        const int kt1 = (t + 1) * 64, kt2 = (t + 2) * 64;
        const bool s1 = (t + 1) < NT, s2 = (t + 2) < NT;
        s16x8 af0h[4], af1l[4], af1h[4], bf1[4], af0n[4], bf0n[4];

        #pragma unroll
        for (int m = 0; m < 4; m++) af0h[m] = *(const s16x8*)(Ap + aOff[m + 4] + x0);
        #pragma unroll
        for (int m = 0; m < 4; m++) af1l[m] = *(const s16x8*)(Ap + aOff[m] + x1);
        if (s1) STAGE_B(P ^ 1, 1, kt1);
        __builtin_amdgcn_s_setprio(1);
        #pragma unroll
        for (int m = 0; m < 4; m++)
            #pragma unroll
            for (int n = 0; n < 4; n++)
                acc[m][n] = __builtin_amdgcn_mfma_f32_16x16x32_bf16(af0c[m], bf0c[n], acc[m][n], 0, 0, 0);
        __builtin_amdgcn_s_setprio(0);

        #pragma unroll
        for (int m = 0; m < 4; m++) af1h[m] = *(const s16x8*)(Ap + aOff[m + 4] + x1);
        #pragma unroll
        for (int n = 0; n < 4; n++) bf1[n] = *(const s16x8*)(Bp + bOff[n] + x1);
        __builtin_amdgcn_s_setprio(1);
        #pragma unroll
        for (int m = 4; m < 8; m++)
            #pragma unroll
            for (int n = 0; n < 4; n++)
                acc[m][n] = __builtin_amdgcn_mfma_f32_16x16x32_bf16(af0h[m - 4], bf0c[n], acc[m][n], 0, 0, 0);
        __builtin_amdgcn_s_setprio(0);
        asm volatile("s_waitcnt lgkmcnt(0)" ::: "memory");
        bar();

        __builtin_amdgcn_s_setprio(1);
        #pragma unroll
        for (int m = 0; m < 4; m++)
            #pragma unroll
            for (int n = 0; n < 4; n++)
                acc[m][n] = __builtin_amdgcn_mfma_f32_16x16x32_bf16(af1l[m], bf1[n], acc[m][n], 0, 0, 0);
        __builtin_amdgcn_s_setprio(0);
        if (s2) {
            STAGE_A(P, 0, kt2);
            STAGE_A(P, 1, kt2);
            STAGE_B(P, 0, kt2);
            asm volatile("s_waitcnt vmcnt(6)" ::: "memory");
        } else {
            asm volatile("s_waitcnt vmcnt(0)" ::: "memory");
        }
        bar();

        if (s1) {
            #pragma unroll
            for (int m = 0; m < 4; m++) af0n[m] = *(const s16x8*)(Aq + aOff[m] + x0);
            #pragma unroll
            for (int n = 0; n < 4; n++) bf0n[n] = *(const s16x8*)(Bq + bOff[n] + x0);
        }
        __builtin_amdgcn_s_setprio(1);
        #pragma unroll
        for (int m = 4; m < 8; m++)
            #pragma unroll
            for (int n = 0; n < 4; n++)
                acc[m][n] = __builtin_amdgcn_mfma_f32_16x16x32_bf16(af1h[m - 4], bf1[n], acc[m][n], 0, 0, 0);
        __builtin_amdgcn_s_setprio(0);
        if (s1) {
            #pragma unroll
            for (int m = 0; m < 4; m++) af0c[m] = af0n[m];
            #pragma unroll
            for (int n = 0; n < 4; n++) bf0c[n] = bf0n[n];
        }
    }
#undef STAGE_A
#undef STAGE_B

    #pragma unroll
    for (int m = 0; m < 8; m++) {
        int rbase = j0 + wm * 128 + m * 16 + kg * 4;
        #pragma unroll
        for (int r = 0; r < 4; r++) {
            int row = rbase + r;
            int cnt = 0;
            #pragma unroll
            for (int n = 0; n < 4; n++) {
                int col = c0 + wn * 64 + n * 16 + fr;
                bool bit = (acc[m][n][r] > 0.f) || (row == col);
                MT[(size_t)row * NN + col] = bit ? (unsigned short)0x3F80 : (unsigned short)0;
                cnt += bit ? 1 : 0;
            }
            cnt += __shfl_xor(cnt, 1);
            cnt += __shfl_xor(cnt, 2);
            cnt += __shfl_xor(cnt, 4);
            cnt += __shfl_xor(cnt, 8);
            if (fr == 0) atomicAdd(&deg[row], cnt);
        }
    }
}

__global__ void k_dinv(const int* __restrict__ deg, float* __restrict__ dinv) {
    int i = blockIdx.x * 256 + threadIdx.x;
    if (i < NN) dinv[i] = 1.0f / sqrtf((float)deg[i]);
}

// ---------------- YT[c=b*128+f][i] = bf16( dinv_i * (x[b,i,:] @ W1[:,f]) ) ----------------
__global__ __launch_bounds__(256) void k_y1(
    const float* __restrict__ x, const float* __restrict__ W1,
    const float* __restrict__ dinv, unsigned short* __restrict__ YT)
{
    __shared__ __align__(16) float xs[128][DIN];
    __shared__ __align__(16) float w1s[DIN][DH];
    int i0 = blockIdx.x * 128, b = blockIdx.y;
    int tid = threadIdx.x;
    const f32x4* xg = (const f32x4*)(x + ((size_t)(b * NN + i0)) * DIN);
    #pragma unroll
    for (int q = 0; q < 8; q++) {
        int idx = q * 256 + tid;
        int row = idx >> 4, c4 = idx & 15;
        *(f32x4*)&xs[row][c4 * 4] = xg[(size_t)row * 16 + c4];
    }
    #pragma unroll
    for (int q = 0; q < 8; q++) {
        int idx = q * 256 + tid;
        int row = idx >> 5, c4 = idx & 31;
        *(f32x4*)&w1s[row][c4 * 4] = ((const f32x4*)W1)[idx];
    }
    __syncthreads();
    int tf = tid & 15, ti = tid >> 4;
    f32x4 t0[8] = {}, t1[8] = {};
    for (int k4 = 0; k4 < DIN; k4 += 4) {
        f32x4 xv[8];
        #pragma unroll
        for (int ii = 0; ii < 8; ii++) xv[ii] = *(const f32x4*)&xs[ti * 8 + ii][k4];
        #pragma unroll
        for (int kk = 0; kk < 4; kk++) {
            f32x4 w0 = *(const f32x4*)&w1s[k4 + kk][tf * 8];
            f32x4 w1v = *(const f32x4*)&w1s[k4 + kk][tf * 8 + 4];
            #pragma unroll
            for (int ii = 0; ii < 8; ii++) {
                float s = xv[ii][kk];
                t0[ii] += s * w0;
                t1[ii] += s * w1v;
            }
        }
    }
    float dvv[8];
    #pragma unroll
    for (int ii = 0; ii < 8; ii++) dvv[ii] = dinv[i0 + ti * 8 + ii];
    #pragma unroll
    for (int ff = 0; ff < 8; ff++) {
        s16x8 pk;
        #pragma unroll
        for (int ii = 0; ii < 8; ii++) {
            float v = (ff < 4 ? t0[ii][ff] : t1[ii][ff - 4]) * dvv[ii];
            pk[ii] = (short)f2bf(v);
        }
        *(s16x8*)(YT + ((size_t)(b * DH + tf * 8 + ff)) * NN + i0 + ti * 8) = pk;
    }
}

// ======== gemm1: 256x256, BK=64, 8 waves; m201-style 8-phase quadrant schedule (R11) ========
__global__ __launch_bounds__(512, 2) void gemm8q(
    const unsigned short* __restrict__ A, const unsigned short* __restrict__ Bt,
    unsigned short* __restrict__ H, const float* __restrict__ dinv,
    const float* __restrict__ bias)
{
    constexpr int K = NN;          // 4096
    constexpr int NT = K / 64;     // 64 K-tiles
    __shared__ __align__(16) unsigned short As[2][256 * 64];   // 64 KB
    __shared__ __align__(16) unsigned short Bs[2][256 * 64];   // 64 KB

    const int tid = threadIdx.x;
    const int lane = tid & 63;
    const int w = tid >> 6;
    const int wm = w >> 2, wn = w & 3;      // 2 x 4 wave grid, wave tile 128x64
    const int fr = lane & 15, kg = lane >> 4;

    const int bid = blockIdx.x;
    const int swz = (bid & 7) * 32 + (bid >> 3);
    const int bx = swz & 15, by = swz >> 4;
    const int c0 = bx * 256, j0 = by * 256;

    const unsigned short* Aj = A + (size_t)j0 * K;
    const unsigned short* Bc = Bt + (size_t)c0 * K;

    const int lr = tid >> 3, kcs = tid & 7;   // stage coords (tid < 512)

#define STAGE_AQ(buf, q, kt) do { \
    int ra_ = (q) * 64 + lr; \
    int rb_ = ra_ + 128; \
    gload16(Aj + (size_t)ra_ * K + (kt) + ((kcs ^ (ra_ & 7)) << 3), \
            &As[buf][(q) * 4096 + tid * 8]); \
    gload16(Aj + (size_t)rb_ * K + (kt) + ((kcs ^ (rb_ & 7)) << 3), \
            &As[buf][(q) * 4096 + 8192 + tid * 8]); \
} while (0)
#define STAGE_BQ(buf, nh, kt) do { \
    int ca_ = tid, cb_ = tid + 512; \
    int r0_ = (ca_ >> 8) * 64 + (nh) * 32 + ((ca_ >> 3) & 31); \
    int r1_ = (cb_ >> 8) * 64 + (nh) * 32 + ((cb_ >> 3) & 31); \
    gload16(Bc + (size_t)r0_ * K + (kt) + (((ca_ & 7) ^ (r0_ & 7)) << 3), \
            &Bs[buf][(ca_ >> 8) * 4096 + (nh) * 2048 + (ca_ & 255) * 8]); \
    gload16(Bc + (size_t)r1_ * K + (kt) + (((cb_ & 7) ^ (r1_ & 7)) << 3), \
            &Bs[buf][(cb_ >> 8) * 4096 + (nh) * 2048 + (cb_ & 255) * 8]); \
} while (0)

    STAGE_AQ(0, 0, 0); STAGE_AQ(0, 1, 0);
    STAGE_BQ(0, 0, 0); STAGE_BQ(0, 1, 0);
    STAGE_BQ(1, 0, 64); STAGE_BQ(1, 1, 64);
    asm volatile("s_waitcnt vmcnt(4)" ::: "memory");
    bar();

    const int x0 = ((kg) ^ (fr & 7)) << 4;
    const int x1 = ((4 + kg) ^ (fr & 7)) << 4;
    int aOff[8], bOff[4];
    #pragma unroll
    for (int m = 0; m < 8; m++) aOff[m] = (wm * 128 + m * 16 + fr) * 128;
    #pragma unroll
    for (int n = 0; n < 4; n++) bOff[n] = (wn * 64 + n * 16 + fr) * 128;

    f32x4 acc[8][4] = {};
    const char* A0p = (const char*)As[0];
    const char* B0p = (const char*)Bs[0];
    const char* A1p = (const char*)As[1];
    const char* B1p = (const char*)Bs[1];

#define MFMA_Q(MB, NB_, AF0, AF1, BK0, BK1) do { \
    __builtin_amdgcn_s_setprio(1); \
    _Pragma("unroll") \
    for (int m = 0; m < 4; m++) { \
        _Pragma("unroll") \
        for (int n = 0; n < 2; n++) { \
            acc[(MB) + m][(NB_) + n] = __builtin_amdgcn_mfma_f32_16x16x32_bf16( \
                AF0[m], BK0[n], acc[(MB) + m][(NB_) + n], 0, 0, 0); \
            acc[(MB) + m][(NB_) + n] = __builtin_amdgcn_mfma_f32_16x16x32_bf16( \
                AF1[m], BK1[n], acc[(MB) + m][(NB_) + n], 0, 0, 0); \
        } \
    } \
    __builtin_amdgcn_s_setprio(0); \
} while (0)

    s16x8 af0[4], af1[4], b0k0[2], b0k1[2], b1k0[2], b1k1[2];

    for (int T = 0; T < NT; T += 2) {
        const bool s2 = (T + 2) < NT, s3 = (T + 3) < NT;
        const int kt1 = (T + 1) * 64, kt2 = (T + 2) * 64, kt3 = (T + 3) * 64;

        #pragma unroll
        for (int m = 0; m < 4; m++) { af0[m] = *(const s16x8*)(A0p + aOff[m] + x0);
                                      af1[m] = *(const s16x8*)(A0p + aOff[m] + x1); }
        #pragma unroll
        for (int n = 0; n < 2; n++) { b0k0[n] = *(const s16x8*)(B0p + bOff[n] + x0);
                                      b0k1[n] = *(const s16x8*)(B0p + bOff[n] + x1); }
        STAGE_AQ(1, 0, kt1);
        bar();
        MFMA_Q(0, 0, af0, af1, b0k0, b0k1);
        bar();

        #pragma unroll
        for (int n = 0; n < 2; n++) { b1k0[n] = *(const s16x8*)(B0p + bOff[n + 2] + x0);
                                      b1k1[n] = *(const s16x8*)(B0p + bOff[n + 2] + x1); }
        STAGE_AQ(1, 1, kt1);
        bar();
        MFMA_Q(0, 2, af0, af1, b1k0, b1k1);
        bar();

        #pragma unroll
        for (int m = 0; m < 4; m++) { af0[m] = *(const s16x8*)(A0p + aOff[m + 4] + x0);
                                      af1[m] = *(const s16x8*)(A0p + aOff[m + 4] + x1); }
        if (s2) STAGE_BQ(0, 0, kt2);
        bar();
        MFMA_Q(4, 0, af0, af1, b0k0, b0k1);
        bar();

        if (s2) { STAGE_BQ(0, 1, kt2);
                  asm volatile("s_waitcnt vmcnt(4)" ::: "memory"); }
        else    { asm volatile("s_waitcnt vmcnt(0)" ::: "memory"); }
        bar();
        MFMA_Q(4, 2, af0, af1, b1k0, b1k1);
        bar();

        #pragma unroll
        for (int m = 0; m < 4; m++) { af0[m] = *(const s16x8*)(A1p + aOff[m] + x0);
                                      af1[m] = *(const s16x8*)(A1p + aOff[m] + x1); }
        #pragma unroll
        for (int n = 0; n < 2; n++) { b0k0[n] = *(const s16x8*)(B1p + bOff[n] + x0);
                                      b0k1[n] = *(const s16x8*)(B1p + bOff[n] + x1); }
        if (s2) STAGE_AQ(0, 0, kt2);
        bar();
        MFMA_Q(0, 0, af0, af1, b0k0, b0k1);
        bar();

        #pragma unroll
        for (int n = 0; n < 2; n++) { b1k0[n] = *(const s16x8*)(B1p + bOff[n + 2] + x0);
                                      b1k1[n] = *(const s16x8*)(B1p + bOff[n + 2] + x1); }
        if (s2) STAGE_AQ(0, 1, kt2);
        bar();
        MFMA_Q(0, 2, af0, af1, b1k0, b1k1);
        bar();

        #pragma unroll
        for (int m = 0; m < 4; m++) { af0[m] = *(const s16x8*)(A1p + aOff[m + 4] + x0);
                                      af1[m] = *(const s16x8*)(A1p + aOff[m + 4] + x1); }
        if (s3) STAGE_BQ(1, 0, kt3);
        bar();
        MFMA_Q(4, 0, af0, af1, b0k0, b0k1);
        bar();

        if (s3) { STAGE_BQ(1, 1, kt3);
                  asm volatile("s_waitcnt vmcnt(4)" ::: "memory"); }
        else    { asm volatile("s_waitcnt vmcnt(0)" ::: "memory"); }
        bar();
        MFMA_Q(4, 2, af0, af1, b1k0, b1k1);
        bar();
    }
#undef MFMA_Q
#undef STAGE_AQ
#undef STAGE_BQ

    #pragma unroll
    for (int m = 0; m < 8; m++) {
        int rbase = j0 + wm * 128 + m * 16 + kg * 4;
        float dv[4];
        #pragma unroll
        for (int r = 0; r < 4; r++) dv[r] = dinv[rbase + r];
        #pragma unroll
        for (int n = 0; n < 4; n++) {
            int gcol = c0 + wn * 64 + n * 16 + fr;
            float bb = bias[gcol & (DH - 1)];
            #pragma unroll
            for (int r = 0; r < 4; r++) {
                float v = acc[m][n][r] * dv[r] + bb;
                v = v > 0.f ? v : 0.f;
                H[(size_t)(rbase + r) * NN + gcol] = f2bf(v);
            }
        }
    }
}

// ---------- k_z2: MFMA-based ZT = dinv_j * (H_b @ W2) ----------
__global__ __launch_bounds__(256) void k_z2(
    const unsigned short* __restrict__ H, const float* __restrict__ W2,
    const float* __restrict__ dinv, unsigned short* __restrict__ ZT)
{
    __shared__ __align__(16) unsigned short Hs[128 * DH];     // 32 KB
    __shared__ __align__(16) unsigned short W2Ts[DOUT * DH];  // 8 KB
    const int tid = threadIdx.x;
    const int j0 = blockIdx.x * 128, b = blockIdx.y;
    const unsigned short* Hb = H + (size_t)j0 * NN + b * DH;

    #pragma unroll
    for (int q = 0; q < 8; q++) {
        int cid = q * 256 + tid;
        int row = cid >> 4, kc = cid & 15;
        gload16(Hb + (size_t)row * NN + kc * 8, &Hs[cid * 8]);
    }
    #pragma unroll
    for (int q = 0; q < 16; q++) {
        int idx = q * 256 + tid;
        int f = idx >> 5, g = idx & 31;
        W2Ts[g * DH + f] = f2bf(W2[f * DOUT + g]);
    }
    __syncthreads();

    const int lane = tid & 63, w = tid >> 6;
    const int fr = lane & 15, kg = lane >> 4;
    f32x4 acc[2][2] = {};
    #pragma unroll
    for (int ks = 0; ks < 4; ks++) {
        s16x8 af[2], bf[2];
        #pragma unroll
        for (int mt = 0; mt < 2; mt++) {
            int row = w * 32 + mt * 16 + fr;
            af[mt] = *(const s16x8*)&Hs[row * DH + ks * 32 + kg * 8];
        }
        #pragma unroll
        for (int nt = 0; nt < 2; nt++) {
            int g = nt * 16 + fr;
            bf[nt] = *(const s16x8*)&W2Ts[g * DH + ks * 32 + kg * 8];
        }
        #pragma unroll
        for (int mt = 0; mt < 2; mt++)
            #pragma unroll
            for (int nt = 0; nt < 2; nt++)
                acc[mt][nt] = __builtin_amdgcn_mfma_f32_16x16x32_bf16(af[mt], bf[nt], acc[mt][nt], 0, 0, 0);
    }
    #pragma unroll
    for (int mt = 0; mt < 2; mt++) {
        int jbase = j0 + w * 32 + mt * 16 + kg * 4;
        float dv[4];
        #pragma unroll
        for (int r = 0; r < 4; r++) dv[r] = dinv[jbase + r];
        #pragma unroll
        for (int nt = 0; nt < 2; nt++) {
            int g = nt * 16 + fr;
            s16x4 pk;
            #pragma unroll
            for (int r = 0; r < 4; r++)
                pk[r] = (short)f2bf(acc[mt][nt][r] * dv[r]);
            *(s16x4*)(ZT + (size_t)(b * DOUT + g) * NN + jbase) = pk;
        }
    }
}

// ---------- gsm2: gemm2 64x128 tile, deep-pipelined (R8 pattern) + fused softmax ----------
// Per tile t (buf P=t&1): phA: stage t+2->P [safe: all P-reads drained at prev lgkm+bar];
//   MFMA ks0 (carried); vmcnt(6) [=t+1 landed]; bar.  phB: read t+1 frags from P^1;
//   MFMA ks1 (carried); lgkmcnt(0); bar; swap carried.
__global__ __launch_bounds__(256) void gsm2(
    const unsigned short* __restrict__ A, const unsigned short* __restrict__ Bt,
    float* __restrict__ out, const float* __restrict__ dinv,
    const float* __restrict__ bias)
{
    constexpr int K = NN;
    constexpr int NT = K / 64;     // 64
    __shared__ __align__(16) unsigned short Asm[2][64 * 64];    // 2 x 8 KB
    __shared__ __align__(16) unsigned short Bsm[2][128 * 64];   // 2 x 16 KB
    const int tid = threadIdx.x;
    const int lane = tid & 63;
    const int w = tid >> 6;
    const int wm = w >> 1, wn = w & 1;     // 2 x 2 wave grid; per-wave 32 x 64
    const int c0 = blockIdx.x * 128;
    const int j0 = blockIdx.y * 64;
    const int fr = lane & 15, kg = lane >> 4;

    int srcA[2], srcB[4];
    #pragma unroll
    for (int q = 0; q < 2; q++) {
        int cid = q * 256 + tid;
        int row = cid >> 3, kc = cid & 7;
        srcA[q] = row * K + ((kc ^ (row & 7)) << 3);
    }
    #pragma unroll
    for (int q = 0; q < 4; q++) {
        int cid = q * 256 + tid;
        int row = cid >> 3, kc = cid & 7;
        srcB[q] = row * K + ((kc ^ (row & 7)) << 3);
    }
    const unsigned short* Abase = A + (size_t)j0 * K;
    const unsigned short* Bbase = Bt + (size_t)c0 * K;

#define STAGE_T(buf, kt) do { \
    _Pragma("unroll") \
    for (int q = 0; q < 2; q++) \
        gload16(Abase + (kt) + srcA[q], &Asm[buf][(q * 256 + tid) * 8]); \
    _Pragma("unroll") \
    for (int q = 0; q < 4; q++) \
        gload16(Bbase + (kt) + srcB[q], &Bsm[buf][(q * 256 + tid) * 8]); } while (0)

    // prologue: stage T0, T1; land T0; read T0 frags; drain before first overwrite of buf0
    STAGE_T(0, 0);
    STAGE_T(1, 64);
    asm volatile("s_waitcnt vmcnt(6)" ::: "memory");
    bar();

    const int x0 = (kg ^ (fr & 7)) << 4;
    const int x1 = ((4 + kg) ^ (fr & 7)) << 4;
    int aOff[2], bOff[4];
    #pragma unroll
    for (int m = 0; m < 2; m++) aOff[m] = (wm * 32 + m * 16 + fr) * 128;
    #pragma unroll
    for (int n = 0; n < 4; n++) bOff[n] = (wn * 64 + n * 16 + fr) * 128;

    s16x8 afc[2][2], bfc[2][4];
    #pragma unroll
    for (int ks = 0; ks < 2; ks++) {
        int xk = ks ? x1 : x0;
        #pragma unroll
        for (int m = 0; m < 2; m++) afc[ks][m] = *(const s16x8*)((const char*)Asm[0] + aOff[m] + xk);
        #pragma unroll
        for (int n = 0; n < 4; n++) bfc[ks][n] = *(const s16x8*)((const char*)Bsm[0] + bOff[n] + xk);
    }
    asm volatile("s_waitcnt lgkmcnt(0)" ::: "memory");
    bar();   // prologue reads of buf0 drained before t=0 phA stages into buf0

    f32x4 acc[2][4] = {};

    for (int t = 0; t < NT; t++) {
        const int P = t & 1;
        const bool s1 = (t + 1) < NT, s2 = (t + 2) < NT;

        // ---- phA: stage t+2 -> P; MFMA ks0 on carried; counted vmcnt; bar
        if (s2) STAGE_T(P, (t + 2) * 64);
        __builtin_amdgcn_s_setprio(1);
        #pragma unroll
        for (int m = 0; m < 2; m++)
            #pragma unroll
            for (int n = 0; n < 4; n++)
                acc[m][n] = __builtin_amdgcn_mfma_f32_16x16x32_bf16(afc[0][m], bfc[0][n], acc[m][n], 0, 0, 0);
        __builtin_amdgcn_s_setprio(0);
        if (s2) asm volatile("s_waitcnt vmcnt(6)" ::: "memory");
        else    asm volatile("s_waitcnt vmcnt(0)" ::: "memory");
        bar();

        // ---- phB: read t+1 frags from P^1; MFMA ks1 on carried; lgkm drain; bar
        s16x8 afn[2][2], bfn[2][4];
        if (s1) {
            const char* Aq = (const char*)Asm[P ^ 1];
            const char* Bq = (const char*)Bsm[P ^ 1];
            #pragma unroll
            for (int ks = 0; ks < 2; ks++) {
                int xk = ks ? x1 : x0;
                #pragma unroll
                for (int m = 0; m < 2; m++) afn[ks][m] = *(const s16x8*)(Aq + aOff[m] + xk);
                #pragma unroll
                for (int n = 0; n < 4; n++) bfn[ks][n] = *(const s16x8*)(Bq + bOff[n] + xk);
            }
        }
        __builtin_amdgcn_s_setprio(1);
        #pragma unroll
        for (int m = 0; m < 2; m++)
            #pragma unroll
            for (int n = 0; n < 4; n++)
                acc[m][n] = __builtin_amdgcn_mfma_f32_16x16x32_bf16(afc[1][m], bfc[1][n], acc[m][n], 0, 0, 0);
        __builtin_amdgcn_s_setprio(0);
        asm volatile("s_waitcnt lgkmcnt(0)" ::: "memory");
        bar();
        if (s1) {
            #pragma unroll
            for (int ks = 0; ks < 2; ks++) {
                #pragma unroll
                for (int m = 0; m < 2; m++) afc[ks][m] = afn[ks][m];
                #pragma unroll
                for (int n = 0; n < 4; n++) bfc[ks][n] = bfn[ks][n];
            }
        }
    }
#undef STAGE_T

    // fused epilogue: g = fr (n even) / fr+16 (n odd); batch = (c0>>5) + wn*2 + (n>>1)
    const float b_lo = bias[fr], b_hi = bias[fr + 16];
    #pragma unroll
    for (int m = 0; m < 2; m++) {
        int rbase = j0 + wm * 32 + m * 16 + kg * 4;
        float dv[4];
        #pragma unroll
        for (int r = 0; r < 4; r++) dv[r] = dinv[rbase + r];
        #pragma unroll
        for (int np = 0; np < 2; np++) {
            int bg = (c0 >> 5) + wn * 2 + np;       // batch index 0..31
            #pragma unroll
            for (int r = 0; r < 4; r++) {
                int row = rbase + r;                 // node j
                float v0 = acc[m][np * 2][r]     * dv[r] + b_lo;   // g = fr
                float v1 = acc[m][np * 2 + 1][r] * dv[r] + b_hi;   // g = fr+16
                float mx = fmaxf(v0, v1);
                #pragma unroll
                for (int d = 8; d; d >>= 1) mx = fmaxf(mx, __shfl_xor(mx, d));
                float e0 = expf(v0 - mx), e1 = expf(v1 - mx);
                float s = e0 + e1;
                #pragma unroll
                for (int d = 8; d; d >>= 1) s += __shfl_xor(s, d);
                float inv = 1.0f / s;
                size_t ob = ((size_t)bg * NN + row) * DOUT;
                out[ob + fr]      = e0 * inv;
                out[ob + fr + 16] = e1 * inv;
            }
        }
    }
}

extern "C" void kernel_launch(void* const* d_in, const int* in_sizes, int n_in,
                              void* d_out, int out_size, void* d_ws, size_t ws_size,
                              hipStream_t stream)
{
    (void)in_sizes; (void)n_in; (void)out_size; (void)ws_size;
    const float* x    = (const float*)d_in[0];
    const float* emb1 = (const float*)d_in[1];
    const float* emb2 = (const float*)d_in[2];
    const float* l1w  = (const float*)d_in[3];
    const float* l1b  = (const float*)d_in[4];
    const float* l2w  = (const float*)d_in[5];
    const float* l2b  = (const float*)d_in[6];
    const float* g1w  = (const float*)d_in[7];
    const float* g1b  = (const float*)d_in[8];
    const float* g2w  = (const float*)d_in[9];
    const float* g2b  = (const float*)d_in[10];
    float* out = (float*)d_out;

    char* w = (char*)d_ws;
    int* deg = (int*)w;                       w += NN * 4;
    float* dinv = (float*)w;                  w += NN * 4;
    unsigned short* MT = (unsigned short*)w;  w += (size_t)NN * NN * 2;
    unsigned short* YT = (unsigned short*)w;  w += (size_t)NN * NN * 2;
    unsigned short* H  = (unsigned short*)w;  w += (size_t)NN * NN * 2;
    unsigned short* ZT = (unsigned short*)w;  w += (size_t)(NB * DOUT) * NN * 2;
    // Ux/Vx live in YT's region (dead until k_y1, which runs after gemm_adj8)
    unsigned short* Ux = YT;
    unsigned short* Vx = YT + (size_t)NN * KADJ;

    k_embuv<<<256, 256, 0, stream>>>(emb1, emb2, l1w, l1b, l2w, l2b, Ux, Vx, deg);
    gemm_adj8<<<256, 512, 0, stream>>>(Vx, Ux, MT, deg);
    k_dinv<<<16, 256, 0, stream>>>(deg, dinv);
    k_y1<<<dim3(32, 32), 256, 0, stream>>>(x, g1w, dinv, YT);
    gemm8q<<<256, 512, 0, stream>>>(MT, YT, H, dinv, g1b);
    k_z2<<<dim3(32, 32), 256, 0, stream>>>(H, g2w, dinv, ZT);
    gsm2<<<dim3(8, 64), 256, 0, stream>>>(MT, ZT, out, dinv, g2b);
}

// Round 13
// 253.941 us; speedup vs baseline: 1.2668x; 1.0271x over previous
//
#include <hip/hip_runtime.h>

typedef float f32x4 __attribute__((ext_vector_type(4)));
typedef short s16x8 __attribute__((ext_vector_type(8)));
typedef short s16x4 __attribute__((ext_vector_type(4)));

#define NN 4096
#define NB 32
#define DIN 64
#define DH 128
#define DOUT 32
#define DIM 40
#define KADJ 512   // 6 split-blocks x 80, zero-padded to 512

__device__ __forceinline__ unsigned short f2bf(float f) {
    unsigned int u = __float_as_uint(f);
    unsigned int r = (u + 0x7FFFu + ((u >> 16) & 1u)) >> 16;
    return (unsigned short)r;
}
__device__ __forceinline__ float bf2f(unsigned short h) {
    return __uint_as_float(((unsigned int)h) << 16);
}
__device__ __forceinline__ void gload16(const void* g, void* l) {
    __builtin_amdgcn_global_load_lds(
        (const __attribute__((address_space(1))) unsigned int*)g,
        (__attribute__((address_space(3))) unsigned int*)l, 16, 0, 0);
}
__device__ __forceinline__ void bar() {
    asm volatile("" ::: "memory");
    __builtin_amdgcn_s_barrier();
    asm volatile("" ::: "memory");
}

// ---------------- fused: n1/n2 = tanh(3*(emb @ W + b)) -> 3-way bf16 split operands ----------------
// Also zeroes deg[] (runs before gemm_adj8 in stream order).
__global__ __launch_bounds__(256) void k_embuv(
    const float* __restrict__ emb1, const float* __restrict__ emb2,
    const float* __restrict__ l1w, const float* __restrict__ l1b,
    const float* __restrict__ l2w, const float* __restrict__ l2b,
    unsigned short* __restrict__ Ux, unsigned short* __restrict__ Vx,
    int* __restrict__ deg)
{
    __shared__ float e1s[16 * DIM], e2s[16 * DIM];
    __shared__ float w1s[DIM * DIM], w2s[DIM * DIM], b1s[DIM], b2s[DIM];
    __shared__ unsigned short Ul[16][KADJ], Vl[16][KADJ];
    const int tid = threadIdx.x;
    const int node0 = blockIdx.x * 16;
    if (tid < 16) deg[node0 + tid] = 0;
    for (int i = tid; i < 16 * DIM; i += 256) {
        e1s[i] = emb1[node0 * DIM + i];
        e2s[i] = emb2[node0 * DIM + i];
    }
    for (int i = tid; i < DIM * DIM; i += 256) { w1s[i] = l1w[i]; w2s[i] = l2w[i]; }
    if (tid < DIM) { b1s[tid] = l1b[tid]; b2s[tid] = l2b[tid]; }
    __syncthreads();
    const int r = tid >> 4;                 // local node 0..15
    const int k0 = (tid & 15) * 5;          // 5 k's per thread (80 total)
    const int PMAP[6] = {0, 0, 1, 1, 0, 2};
    const int QMAP[6] = {0, 1, 0, 1, 2, 0};
    #pragma unroll
    for (int e = 0; e < 5; e++) {
        int k = k0 + e;
        int kp = (k < DIM) ? k : k - DIM;
        float acc1 = b1s[kp], acc2 = b2s[kp];
        for (int kk = 0; kk < DIM; kk++) {
            acc1 += e1s[r * DIM + kk] * w1s[kk * DIM + kp];
            acc2 += e2s[r * DIM + kk] * w2s[kk * DIM + kp];
        }
        float n1v = tanhf(3.0f * acc1), n2v = tanhf(3.0f * acc2);
        float a = (k < DIM) ? n1v : -n2v;
        float b = (k < DIM) ? n2v : n1v;
        unsigned short u0 = f2bf(a); float ra = a - bf2f(u0);
        unsigned short u1 = f2bf(ra); ra -= bf2f(u1);
        unsigned short u2 = f2bf(ra);
        unsigned short v0 = f2bf(b); float rb = b - bf2f(v0);
        unsigned short v1 = f2bf(rb); rb -= bf2f(v1);
        unsigned short v2 = f2bf(rb);
        unsigned short uu[3] = {u0, u1, u2}, vv[3] = {v0, v1, v2};
        #pragma unroll
        for (int bq = 0; bq < 6; bq++) {
            Ul[r][80 * bq + k] = uu[PMAP[bq]];
            Vl[r][80 * bq + k] = vv[QMAP[bq]];
        }
    }
    {   // zero-pad 480..511
        int c = tid & 15;
        Ul[r][480 + c * 2]     = 0; Vl[r][480 + c * 2]     = 0;
        Ul[r][480 + c * 2 + 1] = 0; Vl[r][480 + c * 2 + 1] = 0;
    }
    __syncthreads();
    #pragma unroll
    for (int q = 0; q < 4; q++) {           // 16*512/8 = 1024 chunks
        int idx = q * 256 + tid;
        int rr = idx >> 6, c8 = idx & 63;
        size_t off = ((size_t)(node0 + rr)) * KADJ + c8 * 8;
        *(s16x8*)(Ux + off) = *(s16x8*)&Ul[rr][c8 * 8];
        *(s16x8*)(Vx + off) = *(s16x8*)&Vl[rr][c8 * 8];
    }
}

// ---------------- adjacency GEMM, 256x256 gemm8-structure, K=512 (R10 proven) ----------------
__global__ __launch_bounds__(512, 2) void gemm_adj8(
    const unsigned short* __restrict__ A, const unsigned short* __restrict__ Bt,
    unsigned short* __restrict__ MT, int* __restrict__ deg)
{
    constexpr int K = KADJ;        // 512
    constexpr int NT = K / 64;     // 8 K-tiles
    __shared__ __align__(16) unsigned short As[2][256 * 64];
    __shared__ __align__(16) unsigned short Bs[2][256 * 64];

    const int tid = threadIdx.x;
    const int lane = tid & 63;
    const int w = tid >> 6;
    const int wm = w >> 2, wn = w & 3;
    const int fr = lane & 15, kg = lane >> 4;

    const int bid = blockIdx.x;
    const int swz = (bid & 7) * 32 + (bid >> 3);
    const int bx = swz & 15, by = swz >> 4;
    const int c0 = bx * 256, j0 = by * 256;

    const int cid0 = w * 128 + lane, cid1 = cid0 + 64;
    const int r0 = cid0 >> 3, k0c = cid0 & 7;
    const int r1 = cid1 >> 3, k1c = cid1 & 7;
    const int so0 = r0 * K + ((k0c ^ (r0 & 7)) << 3);
    const int so1 = r1 * K + ((k1c ^ (r1 & 7)) << 3);
    const int lb0 = (w * 2 + 0) * 512;
    const int lb1 = (w * 2 + 1) * 512;

    const unsigned short* Aj = A + (size_t)j0 * K;
    const unsigned short* Bc = Bt + (size_t)c0 * K;

#define STAGE_A(buf, half, kt) do { \
    const unsigned short* g_ = Aj + (size_t)((half) * 128) * K + (kt); \
    gload16(g_ + so0, &As[buf][(half) * 8192 + lb0]); \
    gload16(g_ + so1, &As[buf][(half) * 8192 + lb1]); } while (0)
#define STAGE_B(buf, half, kt) do { \
    const unsigned short* g_ = Bc + (size_t)((half) * 128) * K + (kt); \
    gload16(g_ + so0, &Bs[buf][(half) * 8192 + lb0]); \
    gload16(g_ + so1, &Bs[buf][(half) * 8192 + lb1]); } while (0)

    STAGE_A(0, 0, 0);  STAGE_A(0, 1, 0);
    STAGE_B(0, 0, 0);  STAGE_B(0, 1, 0);
    STAGE_A(1, 0, 64); STAGE_A(1, 1, 64);
    STAGE_B(1, 0, 64);
    asm volatile("s_waitcnt vmcnt(6)" ::: "memory");
    bar();

    const int x0 = ((kg) ^ (fr & 7)) << 4;
    const int x1 = ((4 + kg) ^ (fr & 7)) << 4;
    int aOff[8], bOff[4];
    #pragma unroll
    for (int m = 0; m < 8; m++) aOff[m] = (wm * 128 + m * 16 + fr) * 128;
    #pragma unroll
    for (int n = 0; n < 4; n++) bOff[n] = (wn * 64 + n * 16 + fr) * 128;

    s16x8 af0c[4], bf0c[4];
    #pragma unroll
    for (int m = 0; m < 4; m++) af0c[m] = *(const s16x8*)((const char*)As[0] + aOff[m] + x0);
    #pragma unroll
    for (int n = 0; n < 4; n++) bf0c[n] = *(const s16x8*)((const char*)Bs[0] + bOff[n] + x0);

    f32x4 acc[8][4] = {};

    for (int t = 0; t < NT; t++) {
        const int P = t & 1;
        const char* Ap = (const char*)As[P];
        const char* Bp = (const char*)Bs[P];
        const char* Aq = (const char*)As[P ^ 1];
        const char* Bq = (const char*)Bs[P ^ 1];
        const int kt1 = (t + 1) * 64, kt2 = (t + 2) * 64;
        const bool s1 = (t + 1) < NT, s2 = (t + 2) < NT;
        s16x8 af0h[4], af1l[4], af1h[4], bf1[4], af0n[4], bf0n[4];

        #pragma unroll
        for (int m = 0; m < 4; m++) af0h[m] = *(const s16x8*)(Ap + aOff[m + 4] + x0);
        #pragma unroll
        for (int m = 0; m < 4; m++) af1l[m] = *(const s16x8*)(Ap + aOff[m] + x1);
        if (s1) STAGE_B(P ^ 1, 1, kt1);
        __builtin_amdgcn_s_setprio(1);
        #pragma unroll
        for (int m = 0; m < 4; m++)
            #pragma unroll
            for (int n = 0; n < 4; n++)
                acc[m][n] = __builtin_amdgcn_mfma_f32_16x16x32_bf16(af0c[m], bf0c[n], acc[m][n], 0, 0, 0);
        __builtin_amdgcn_s_setprio(0);

        #pragma unroll
        for (int m = 0; m < 4; m++) af1h[m] = *(const s16x8*)(Ap + aOff[m + 4] + x1);
        #pragma unroll
        for (int n = 0; n < 4; n++) bf1[n] = *(const s16x8*)(Bp + bOff[n] + x1);
        __builtin_amdgcn_s_setprio(1);
        #pragma unroll
        for (int m = 4; m < 8; m++)
            #pragma unroll
            for (int n = 0; n < 4; n++)
                acc[m][n] = __builtin_amdgcn_mfma_f32_16x16x32_bf16(af0h[m - 4], bf0c[n], acc[m][n], 0, 0, 0);
        __builtin_amdgcn_s_setprio(0);
        asm volatile("s_waitcnt lgkmcnt(0)" ::: "memory");
        bar();

        __builtin_amdgcn_s_setprio(1);
        #pragma unroll
        for (int m = 0; m < 4; m++)
            #pragma unroll
            for (int n = 0; n < 4; n++)
                acc[m][n] = __builtin_amdgcn_mfma_f32_16x16x32_bf16(af1l[m], bf1[n], acc[m][n], 0, 0, 0);
        __builtin_amdgcn_s_setprio(0);
        if (s2) {
            STAGE_A(P, 0, kt2);
            STAGE_A(P, 1, kt2);
            STAGE_B(P, 0, kt2);
            asm volatile("s_waitcnt vmcnt(6)" ::: "memory");
        } else {
            asm volatile("s_waitcnt vmcnt(0)" ::: "memory");
        }
        bar();

        if (s1) {
            #pragma unroll
            for (int m = 0; m < 4; m++) af0n[m] = *(const s16x8*)(Aq + aOff[m] + x0);
            #pragma unroll
            for (int n = 0; n < 4; n++) bf0n[n] = *(const s16x8*)(Bq + bOff[n] + x0);
        }
        __builtin_amdgcn_s_setprio(1);
        #pragma unroll
        for (int m = 4; m < 8; m++)
            #pragma unroll
            for (int n = 0; n < 4; n++)
                acc[m][n] = __builtin_amdgcn_mfma_f32_16x16x32_bf16(af1h[m - 4], bf1[n], acc[m][n], 0, 0, 0);
        __builtin_amdgcn_s_setprio(0);
        if (s1) {
            #pragma unroll
            for (int m = 0; m < 4; m++) af0c[m] = af0n[m];
            #pragma unroll
            for (int n = 0; n < 4; n++) bf0c[n] = bf0n[n];
        }
    }
#undef STAGE_A
#undef STAGE_B

    #pragma unroll
    for (int m = 0; m < 8; m++) {
        int rbase = j0 + wm * 128 + m * 16 + kg * 4;
        #pragma unroll
        for (int r = 0; r < 4; r++) {
            int row = rbase + r;
            int cnt = 0;
            #pragma unroll
            for (int n = 0; n < 4; n++) {
                int col = c0 + wn * 64 + n * 16 + fr;
                bool bit = (acc[m][n][r] > 0.f) || (row == col);
                MT[(size_t)row * NN + col] = bit ? (unsigned short)0x3F80 : (unsigned short)0;
                cnt += bit ? 1 : 0;
            }
            cnt += __shfl_xor(cnt, 1);
            cnt += __shfl_xor(cnt, 2);
            cnt += __shfl_xor(cnt, 4);
            cnt += __shfl_xor(cnt, 8);
            if (fr == 0) atomicAdd(&deg[row], cnt);
        }
    }
}

__global__ void k_dinv(const int* __restrict__ deg, float* __restrict__ dinv) {
    int i = blockIdx.x * 256 + threadIdx.x;
    if (i < NN) dinv[i] = 1.0f / sqrtf((float)deg[i]);
}

// ---------------- k_y1m: MFMA YT[c=b*128+f][i] = bf16( dinv_i * (x[b,i,:] @ W1[:,f]) ) ----------------
// x and W1 rounded to bf16 (single); C[i][f] via mfma(A=x rows, B=W1^T rows), K=64.
__global__ __launch_bounds__(256) void k_y1m(
    const float* __restrict__ x, const float* __restrict__ W1,
    const float* __restrict__ dinv, unsigned short* __restrict__ YT)
{
    __shared__ __align__(16) unsigned short Xs[128 * 64];   // 16KB, row=128B, chunk-XOR swizzle
    __shared__ __align__(16) unsigned short Ws[128 * 64];   // 16KB, W1T[f][k] swizzled
    const int tid = threadIdx.x;
    const int i0 = blockIdx.x * 128, b = blockIdx.y;

    // stage x tile: 128 rows x 64 f32 -> bf16, swizzled
    const float* xg = x + ((size_t)(b * NN + i0)) * DIN;
    #pragma unroll
    for (int q = 0; q < 8; q++) {
        int idx = q * 256 + tid;             // 2048 f32x4 chunks
        int row = idx >> 4, c4 = idx & 15;   // k base = c4*4
        f32x4 v = *(const f32x4*)(xg + (size_t)row * DIN + c4 * 4);
        s16x4 pk;
        #pragma unroll
        for (int e = 0; e < 4; e++) pk[e] = (short)f2bf(v[e]);
        int chunk = (c4 >> 1) ^ (row & 7);
        *(s16x4*)((char*)Xs + row * 128 + (chunk << 4) + (c4 & 1) * 8) = pk;
    }
    // stage W1^T: W1[k][f] f32 -> Ws[f][k] bf16, swizzled
    #pragma unroll
    for (int q = 0; q < 8; q++) {
        int idx = q * 256 + tid;             // 2048 f32x4 (64x128 elems)
        int k = idx >> 5, f4 = (idx & 31) * 4;
        f32x4 v = ((const f32x4*)W1)[idx];
        #pragma unroll
        for (int e = 0; e < 4; e++) {
            int f = f4 + e;
            int chunk = (k >> 3) ^ (f & 7);
            *(unsigned short*)((char*)Ws + f * 128 + (chunk << 4) + (k & 7) * 2) = f2bf(v[e]);
        }
    }
    __syncthreads();

    const int lane = tid & 63, w = tid >> 6;
    const int wm = w >> 1, wn = w & 1;       // 2x2 wave grid: 64 i x 64 f per wave
    const int fr = lane & 15, kg = lane >> 4;
    f32x4 acc[4][4] = {};
    #pragma unroll
    for (int ks = 0; ks < 2; ks++) {
        int kc = ks * 4 + kg;
        s16x8 af[4], bf[4];
        #pragma unroll
        for (int mt = 0; mt < 4; mt++) {
            int row = wm * 64 + mt * 16 + fr;
            af[mt] = *(const s16x8*)((const char*)Xs + row * 128 + ((kc ^ (row & 7)) << 4));
        }
        #pragma unroll
        for (int nt = 0; nt < 4; nt++) {
            int f = wn * 64 + nt * 16 + fr;
            bf[nt] = *(const s16x8*)((const char*)Ws + f * 128 + ((kc ^ (f & 7)) << 4));
        }
        #pragma unroll
        for (int mt = 0; mt < 4; mt++)
            #pragma unroll
            for (int nt = 0; nt < 4; nt++)
                acc[mt][nt] = __builtin_amdgcn_mfma_f32_16x16x32_bf16(af[mt], bf[nt], acc[mt][nt], 0, 0, 0);
    }
    // epilogue: frag row = i (4 consecutive per lane), col = f; pack s16x4 along i
    #pragma unroll
    for (int mt = 0; mt < 4; mt++) {
        int ibase = i0 + wm * 64 + mt * 16 + kg * 4;
        float dv[4];
        #pragma unroll
        for (int r = 0; r < 4; r++) dv[r] = dinv[ibase + r];
        #pragma unroll
        for (int nt = 0; nt < 4; nt++) {
            int f = wn * 64 + nt * 16 + fr;
            s16x4 pk;
            #pragma unroll
            for (int r = 0; r < 4; r++) pk[r] = (short)f2bf(acc[mt][nt][r] * dv[r]);
            *(s16x4*)(YT + (size_t)(b * DH + f) * NN + ibase) = pk;
        }
    }
}

// ======== gemm1: 256x256, BK=64, 8 waves; m201-style 8-phase quadrant schedule (R11) ========
__global__ __launch_bounds__(512, 2) void gemm8q(
    const unsigned short* __restrict__ A, const unsigned short* __restrict__ Bt,
    unsigned short* __restrict__ H, const float* __restrict__ dinv,
    const float* __restrict__ bias)
{
    constexpr int K = NN;          // 4096
    constexpr int NT = K / 64;     // 64 K-tiles
    __shared__ __align__(16) unsigned short As[2][256 * 64];   // 64 KB
    __shared__ __align__(16) unsigned short Bs[2][256 * 64];   // 64 KB

    const int tid = threadIdx.x;
    const int lane = tid & 63;
    const int w = tid >> 6;
    const int wm = w >> 2, wn = w & 3;      // 2 x 4 wave grid, wave tile 128x64
    const int fr = lane & 15, kg = lane >> 4;

    const int bid = blockIdx.x;
    const int swz = (bid & 7) * 32 + (bid >> 3);
    const int bx = swz & 15, by = swz >> 4;
    const int c0 = bx * 256, j0 = by * 256;

    const unsigned short* Aj = A + (size_t)j0 * K;
    const unsigned short* Bc = Bt + (size_t)c0 * K;

    const int lr = tid >> 3, kcs = tid & 7;   // stage coords (tid < 512)

#define STAGE_AQ(buf, q, kt) do { \
    int ra_ = (q) * 64 + lr; \
    int rb_ = ra_ + 128; \
    gload16(Aj + (size_t)ra_ * K + (kt) + ((kcs ^ (ra_ & 7)) << 3), \
            &As[buf][(q) * 4096 + tid * 8]); \
    gload16(Aj + (size_t)rb_ * K + (kt) + ((kcs ^ (rb_ & 7)) << 3), \
            &As[buf][(q) * 4096 + 8192 + tid * 8]); \
} while (0)
#define STAGE_BQ(buf, nh, kt) do { \
    int ca_ = tid, cb_ = tid + 512; \
    int r0_ = (ca_ >> 8) * 64 + (nh) * 32 + ((ca_ >> 3) & 31); \
    int r1_ = (cb_ >> 8) * 64 + (nh) * 32 + ((cb_ >> 3) & 31); \
    gload16(Bc + (size_t)r0_ * K + (kt) + (((ca_ & 7) ^ (r0_ & 7)) << 3), \
            &Bs[buf][(ca_ >> 8) * 4096 + (nh) * 2048 + (ca_ & 255) * 8]); \
    gload16(Bc + (size_t)r1_ * K + (kt) + (((cb_ & 7) ^ (r1_ & 7)) << 3), \
            &Bs[buf][(cb_ >> 8) * 4096 + (nh) * 2048 + (cb_ & 255) * 8]); \
} while (0)

    STAGE_AQ(0, 0, 0); STAGE_AQ(0, 1, 0);
    STAGE_BQ(0, 0, 0); STAGE_BQ(0, 1, 0);
    STAGE_BQ(1, 0, 64); STAGE_BQ(1, 1, 64);
    asm volatile("s_waitcnt vmcnt(4)" ::: "memory");
    bar();

    const int x0 = ((kg) ^ (fr & 7)) << 4;
    const int x1 = ((4 + kg) ^ (fr & 7)) << 4;
    int aOff[8], bOff[4];
    #pragma unroll
    for (int m = 0; m < 8; m++) aOff[m] = (wm * 128 + m * 16 + fr) * 128;
    #pragma unroll
    for (int n = 0; n < 4; n++) bOff[n] = (wn * 64 + n * 16 + fr) * 128;

    f32x4 acc[8][4] = {};
    const char* A0p = (const char*)As[0];
    const char* B0p = (const char*)Bs[0];
    const char* A1p = (const char*)As[1];
    const char* B1p = (const char*)Bs[1];

#define MFMA_Q(MB, NB_, AF0, AF1, BK0, BK1) do { \
    __builtin_amdgcn_s_setprio(1); \
    _Pragma("unroll") \
    for (int m = 0; m < 4; m++) { \
        _Pragma("unroll") \
        for (int n = 0; n < 2; n++) { \
            acc[(MB) + m][(NB_) + n] = __builtin_amdgcn_mfma_f32_16x16x32_bf16( \
                AF0[m], BK0[n], acc[(MB) + m][(NB_) + n], 0, 0, 0); \
            acc[(MB) + m][(NB_) + n] = __builtin_amdgcn_mfma_f32_16x16x32_bf16( \
                AF1[m], BK1[n], acc[(MB) + m][(NB_) + n], 0, 0, 0); \
        } \
    } \
    __builtin_amdgcn_s_setprio(0); \
} while (0)

    s16x8 af0[4], af1[4], b0k0[2], b0k1[2], b1k0[2], b1k1[2];

    for (int T = 0; T < NT; T += 2) {
        const bool s2 = (T + 2) < NT, s3 = (T + 3) < NT;
        const int kt1 = (T + 1) * 64, kt2 = (T + 2) * 64, kt3 = (T + 3) * 64;

        #pragma unroll
        for (int m = 0; m < 4; m++) { af0[m] = *(const s16x8*)(A0p + aOff[m] + x0);
                                      af1[m] = *(const s16x8*)(A0p + aOff[m] + x1); }
        #pragma unroll
        for (int n = 0; n < 2; n++) { b0k0[n] = *(const s16x8*)(B0p + bOff[n] + x0);
                                      b0k1[n] = *(const s16x8*)(B0p + bOff[n] + x1); }
        STAGE_AQ(1, 0, kt1);
        bar();
        MFMA_Q(0, 0, af0, af1, b0k0, b0k1);
        bar();

        #pragma unroll
        for (int n = 0; n < 2; n++) { b1k0[n] = *(const s16x8*)(B0p + bOff[n + 2] + x0);
                                      b1k1[n] = *(const s16x8*)(B0p + bOff[n + 2] + x1); }
        STAGE_AQ(1, 1, kt1);
        bar();
        MFMA_Q(0, 2, af0, af1, b1k0, b1k1);
        bar();

        #pragma unroll
        for (int m = 0; m < 4; m++) { af0[m] = *(const s16x8*)(A0p + aOff[m + 4] + x0);
                                      af1[m] = *(const s16x8*)(A0p + aOff[m + 4] + x1); }
        if (s2) STAGE_BQ(0, 0, kt2);
        bar();
        MFMA_Q(4, 0, af0, af1, b0k0, b0k1);
        bar();

        if (s2) { STAGE_BQ(0, 1, kt2);
                  asm volatile("s_waitcnt vmcnt(4)" ::: "memory"); }
        else    { asm volatile("s_waitcnt vmcnt(0)" ::: "memory"); }
        bar();
        MFMA_Q(4, 2, af0, af1, b1k0, b1k1);
        bar();

        #pragma unroll
        for (int m = 0; m < 4; m++) { af0[m] = *(const s16x8*)(A1p + aOff[m] + x0);
                                      af1[m] = *(const s16x8*)(A1p + aOff[m] + x1); }
        #pragma unroll
        for (int n = 0; n < 2; n++) { b0k0[n] = *(const s16x8*)(B1p + bOff[n] + x0);
                                      b0k1[n] = *(const s16x8*)(B1p + bOff[n] + x1); }
        if (s2) STAGE_AQ(0, 0, kt2);
        bar();
        MFMA_Q(0, 0, af0, af1, b0k0, b0k1);
        bar();

        #pragma unroll
        for (int n = 0; n < 2; n++) { b1k0[n] = *(const s16x8*)(B1p + bOff[n + 2] + x0);
                                      b1k1[n] = *(const s16x8*)(B1p + bOff[n + 2] + x1); }
        if (s2) STAGE_AQ(0, 1, kt2);
        bar();
        MFMA_Q(0, 2, af0, af1, b1k0, b1k1);
        bar();

        #pragma unroll
        for (int m = 0; m < 4; m++) { af0[m] = *(const s16x8*)(A1p + aOff[m + 4] + x0);
                                      af1[m] = *(const s16x8*)(A1p + aOff[m + 4] + x1); }
        if (s3) STAGE_BQ(1, 0, kt3);
        bar();
        MFMA_Q(4, 0, af0, af1, b0k0, b0k1);
        bar();

        if (s3) { STAGE_BQ(1, 1, kt3);
                  asm volatile("s_waitcnt vmcnt(4)" ::: "memory"); }
        else    { asm volatile("s_waitcnt vmcnt(0)" ::: "memory"); }
        bar();
        MFMA_Q(4, 2, af0, af1, b1k0, b1k1);
        bar();
    }
#undef MFMA_Q
#undef STAGE_AQ
#undef STAGE_BQ

    #pragma unroll
    for (int m = 0; m < 8; m++) {
        int rbase = j0 + wm * 128 + m * 16 + kg * 4;
        float dv[4];
        #pragma unroll
        for (int r = 0; r < 4; r++) dv[r] = dinv[rbase + r];
        #pragma unroll
        for (int n = 0; n < 4; n++) {
            int gcol = c0 + wn * 64 + n * 16 + fr;
            float bb = bias[gcol & (DH - 1)];
            #pragma unroll
            for (int r = 0; r < 4; r++) {
                float v = acc[m][n][r] * dv[r] + bb;
                v = v > 0.f ? v : 0.f;
                H[(size_t)(rbase + r) * NN + gcol] = f2bf(v);
            }
        }
    }
}

// ---------- k_z2: MFMA-based ZT = dinv_j * (H_b @ W2) ----------
__global__ __launch_bounds__(256) void k_z2(
    const unsigned short* __restrict__ H, const float* __restrict__ W2,
    const float* __restrict__ dinv, unsigned short* __restrict__ ZT)
{
    __shared__ __align__(16) unsigned short Hs[128 * DH];     // 32 KB
    __shared__ __align__(16) unsigned short W2Ts[DOUT * DH];  // 8 KB
    const int tid = threadIdx.x;
    const int j0 = blockIdx.x * 128, b = blockIdx.y;
    const unsigned short* Hb = H + (size_t)j0 * NN + b * DH;

    #pragma unroll
    for (int q = 0; q < 8; q++) {
        int cid = q * 256 + tid;
        int row = cid >> 4, kc = cid & 15;
        gload16(Hb + (size_t)row * NN + kc * 8, &Hs[cid * 8]);
    }
    #pragma unroll
    for (int q = 0; q < 16; q++) {
        int idx = q * 256 + tid;
        int f = idx >> 5, g = idx & 31;
        W2Ts[g * DH + f] = f2bf(W2[f * DOUT + g]);
    }
    __syncthreads();

    const int lane = tid & 63, w = tid >> 6;
    const int fr = lane & 15, kg = lane >> 4;
    f32x4 acc[2][2] = {};
    #pragma unroll
    for (int ks = 0; ks < 4; ks++) {
        s16x8 af[2], bf[2];
        #pragma unroll
        for (int mt = 0; mt < 2; mt++) {
            int row = w * 32 + mt * 16 + fr;
            af[mt] = *(const s16x8*)&Hs[row * DH + ks * 32 + kg * 8];
        }
        #pragma unroll
        for (int nt = 0; nt < 2; nt++) {
            int g = nt * 16 + fr;
            bf[nt] = *(const s16x8*)&W2Ts[g * DH + ks * 32 + kg * 8];
        }
        #pragma unroll
        for (int mt = 0; mt < 2; mt++)
            #pragma unroll
            for (int nt = 0; nt < 2; nt++)
                acc[mt][nt] = __builtin_amdgcn_mfma_f32_16x16x32_bf16(af[mt], bf[nt], acc[mt][nt], 0, 0, 0);
    }
    #pragma unroll
    for (int mt = 0; mt < 2; mt++) {
        int jbase = j0 + w * 32 + mt * 16 + kg * 4;
        float dv[4];
        #pragma unroll
        for (int r = 0; r < 4; r++) dv[r] = dinv[jbase + r];
        #pragma unroll
        for (int nt = 0; nt < 2; nt++) {
            int g = nt * 16 + fr;
            s16x4 pk;
            #pragma unroll
            for (int r = 0; r < 4; r++)
                pk[r] = (short)f2bf(acc[mt][nt][r] * dv[r]);
            *(s16x4*)(ZT + (size_t)(b * DOUT + g) * NN + jbase) = pk;
        }
    }
}

// ---------- gsm2: gemm2 64x128 tile, deep-pipelined (R8 pattern) + fused softmax ----------
__global__ __launch_bounds__(256) void gsm2(
    const unsigned short* __restrict__ A, const unsigned short* __restrict__ Bt,
    float* __restrict__ out, const float* __restrict__ dinv,
    const float* __restrict__ bias)
{
    constexpr int K = NN;
    constexpr int NT = K / 64;     // 64
    __shared__ __align__(16) unsigned short Asm[2][64 * 64];    // 2 x 8 KB
    __shared__ __align__(16) unsigned short Bsm[2][128 * 64];   // 2 x 16 KB
    const int tid = threadIdx.x;
    const int lane = tid & 63;
    const int w = tid >> 6;
    const int wm = w >> 1, wn = w & 1;     // 2 x 2 wave grid; per-wave 32 x 64
    const int c0 = blockIdx.x * 128;
    const int j0 = blockIdx.y * 64;
    const int fr = lane & 15, kg = lane >> 4;

    int srcA[2], srcB[4];
    #pragma unroll
    for (int q = 0; q < 2; q++) {
        int cid = q * 256 + tid;
        int row = cid >> 3, kc = cid & 7;
        srcA[q] = row * K + ((kc ^ (row & 7)) << 3);
    }
    #pragma unroll
    for (int q = 0; q < 4; q++) {
        int cid = q * 256 + tid;
        int row = cid >> 3, kc = cid & 7;
        srcB[q] = row * K + ((kc ^ (row & 7)) << 3);
    }
    const unsigned short* Abase = A + (size_t)j0 * K;
    const unsigned short* Bbase = Bt + (size_t)c0 * K;

#define STAGE_T(buf, kt) do { \
    _Pragma("unroll") \
    for (int q = 0; q < 2; q++) \
        gload16(Abase + (kt) + srcA[q], &Asm[buf][(q * 256 + tid) * 8]); \
    _Pragma("unroll") \
    for (int q = 0; q < 4; q++) \
        gload16(Bbase + (kt) + srcB[q], &Bsm[buf][(q * 256 + tid) * 8]); } while (0)

    STAGE_T(0, 0);
    STAGE_T(1, 64);
    asm volatile("s_waitcnt vmcnt(6)" ::: "memory");
    bar();

    const int x0 = (kg ^ (fr & 7)) << 4;
    const int x1 = ((4 + kg) ^ (fr & 7)) << 4;
    int aOff[2], bOff[4];
    #pragma unroll
    for (int m = 0; m < 2; m++) aOff[m] = (wm * 32 + m * 16 + fr) * 128;
    #pragma unroll
    for (int n = 0; n < 4; n++) bOff[n] = (wn * 64 + n * 16 + fr) * 128;

    s16x8 afc[2][2], bfc[2][4];
    #pragma unroll
    for (int ks = 0; ks < 2; ks++) {
        int xk = ks ? x1 : x0;
        #pragma unroll
        for (int m = 0; m < 2; m++) afc[ks][m] = *(const s16x8*)((const char*)Asm[0] + aOff[m] + xk);
        #pragma unroll
        for (int n = 0; n < 4; n++) bfc[ks][n] = *(const s16x8*)((const char*)Bsm[0] + bOff[n] + xk);
    }
    asm volatile("s_waitcnt lgkmcnt(0)" ::: "memory");
    bar();

    f32x4 acc[2][4] = {};

    for (int t = 0; t < NT; t++) {
        const int P = t & 1;
        const bool s1 = (t + 1) < NT, s2 = (t + 2) < NT;

        if (s2) STAGE_T(P, (t + 2) * 64);
        __builtin_amdgcn_s_setprio(1);
        #pragma unroll
        for (int m = 0; m < 2; m++)
            #pragma unroll
            for (int n = 0; n < 4; n++)
                acc[m][n] = __builtin_amdgcn_mfma_f32_16x16x32_bf16(afc[0][m], bfc[0][n], acc[m][n], 0, 0, 0);
        __builtin_amdgcn_s_setprio(0);
        if (s2) asm volatile("s_waitcnt vmcnt(6)" ::: "memory");
        else    asm volatile("s_waitcnt vmcnt(0)" ::: "memory");
        bar();

        s16x8 afn[2][2], bfn[2][4];
        if (s1) {
            const char* Aq = (const char*)Asm[P ^ 1];
            const char* Bq = (const char*)Bsm[P ^ 1];
            #pragma unroll
            for (int ks = 0; ks < 2; ks++) {
                int xk = ks ? x1 : x0;
                #pragma unroll
                for (int m = 0; m < 2; m++) afn[ks][m] = *(const s16x8*)(Aq + aOff[m] + xk);
                #pragma unroll
                for (int n = 0; n < 4; n++) bfn[ks][n] = *(const s16x8*)(Bq + bOff[n] + xk);
            }
        }
        __builtin_amdgcn_s_setprio(1);
        #pragma unroll
        for (int m = 0; m < 2; m++)
            #pragma unroll
            for (int n = 0; n < 4; n++)
                acc[m][n] = __builtin_amdgcn_mfma_f32_16x16x32_bf16(afc[1][m], bfc[1][n], acc[m][n], 0, 0, 0);
        __builtin_amdgcn_s_setprio(0);
        asm volatile("s_waitcnt lgkmcnt(0)" ::: "memory");
        bar();
        if (s1) {
            #pragma unroll
            for (int ks = 0; ks < 2; ks++) {
                #pragma unroll
                for (int m = 0; m < 2; m++) afc[ks][m] = afn[ks][m];
                #pragma unroll
                for (int n = 0; n < 4; n++) bfc[ks][n] = bfn[ks][n];
            }
        }
    }
#undef STAGE_T

    const float b_lo = bias[fr], b_hi = bias[fr + 16];
    #pragma unroll
    for (int m = 0; m < 2; m++) {
        int rbase = j0 + wm * 32 + m * 16 + kg * 4;
        float dv[4];
        #pragma unroll
        for (int r = 0; r < 4; r++) dv[r] = dinv[rbase + r];
        #pragma unroll
        for (int np = 0; np < 2; np++) {
            int bg = (c0 >> 5) + wn * 2 + np;       // batch index 0..31
            #pragma unroll
            for (int r = 0; r < 4; r++) {
                int row = rbase + r;                 // node j
                float v0 = acc[m][np * 2][r]     * dv[r] + b_lo;   // g = fr
                float v1 = acc[m][np * 2 + 1][r] * dv[r] + b_hi;   // g = fr+16
                float mx = fmaxf(v0, v1);
                #pragma unroll
                for (int d = 8; d; d >>= 1) mx = fmaxf(mx, __shfl_xor(mx, d));
                float e0 = expf(v0 - mx), e1 = expf(v1 - mx);
                float s = e0 + e1;
                #pragma unroll
                for (int d = 8; d; d >>= 1) s += __shfl_xor(s, d);
                float inv = 1.0f / s;
                size_t ob = ((size_t)bg * NN + row) * DOUT;
                out[ob + fr]      = e0 * inv;
                out[ob + fr + 16] = e1 * inv;
            }
        }
    }
}

extern "C" void kernel_launch(void* const* d_in, const int* in_sizes, int n_in,
                              void* d_out, int out_size, void* d_ws, size_t ws_size,
                              hipStream_t stream)
{
    (void)in_sizes; (void)n_in; (void)out_size; (void)ws_size;
    const float* x    = (const float*)d_in[0];
    const float* emb1 = (const float*)d_in[1];
    const float* emb2 = (const float*)d_in[2];
    const float* l1w  = (const float*)d_in[3];
    const float* l1b  = (const float*)d_in[4];
    const float* l2w  = (const float*)d_in[5];
    const float* l2b  = (const float*)d_in[6];
    const float* g1w  = (const float*)d_in[7];
    const float* g1b  = (const float*)d_in[8];
    const float* g2w  = (const float*)d_in[9];
    const float* g2b  = (const float*)d_in[10];
    float* out = (float*)d_out;

    char* w = (char*)d_ws;
    int* deg = (int*)w;                       w += NN * 4;
    float* dinv = (float*)w;                  w += NN * 4;
    unsigned short* MT = (unsigned short*)w;  w += (size_t)NN * NN * 2;
    unsigned short* YT = (unsigned short*)w;  w += (size_t)NN * NN * 2;
    unsigned short* H  = (unsigned short*)w;  w += (size_t)NN * NN * 2;
    unsigned short* ZT = (unsigned short*)w;  w += (size_t)(NB * DOUT) * NN * 2;
    // Ux/Vx live in YT's region (dead until k_y1m, which runs after gemm_adj8)
    unsigned short* Ux = YT;
    unsigned short* Vx = YT + (size_t)NN * KADJ;

    k_embuv<<<256, 256, 0, stream>>>(emb1, emb2, l1w, l1b, l2w, l2b, Ux, Vx, deg);
    gemm_adj8<<<256, 512, 0, stream>>>(Vx, Ux, MT, deg);
    k_dinv<<<16, 256, 0, stream>>>(deg, dinv);
    k_y1m<<<dim3(32, 32), 256, 0, stream>>>(x, g1w, dinv, YT);
    gemm8q<<<256, 512, 0, stream>>>(MT, YT, H, dinv, g1b);
    k_z2<<<dim3(32, 32), 256, 0, stream>>>(H, g2w, dinv, ZT);
    gsm2<<<dim3(8, 64), 256, 0, stream>>>(MT, ZT, out, dinv, g2b);
}

// Round 15
// 224.570 us; speedup vs baseline: 1.4325x; 1.1308x over previous
//
#include <hip/hip_runtime.h>

typedef float f32x4 __attribute__((ext_vector_type(4)));
typedef short s16x8 __attribute__((ext_vector_type(8)));
typedef short s16x4 __attribute__((ext_vector_type(4)));
typedef int i32x4 __attribute__((ext_vector_type(4)));

#define NN 4096
#define NB 32
#define DIN 64
#define DH 128
#define DOUT 32
#define DIM 40
#define KADJ 512   // 6 split-blocks x 80, zero-padded to 512

__device__ __forceinline__ unsigned short f2bf(float f) {
    unsigned int u = __float_as_uint(f);
    unsigned int r = (u + 0x7FFFu + ((u >> 16) & 1u)) >> 16;
    return (unsigned short)r;
}
__device__ __forceinline__ float bf2f(unsigned short h) {
    return __uint_as_float(((unsigned int)h) << 16);
}
__device__ __forceinline__ void gload16(const void* g, void* l) {
    __builtin_amdgcn_global_load_lds(
        (const __attribute__((address_space(1))) unsigned int*)g,
        (__attribute__((address_space(3))) unsigned int*)l, 16, 0, 0);
}
__device__ __forceinline__ void bar() {
    asm volatile("" ::: "memory");
    __builtin_amdgcn_s_barrier();
    asm volatile("" ::: "memory");
}

// ---------------- fused: n1/n2 = tanh(3*(emb @ W + b)) -> 3-way bf16 split operands ----------------
__global__ __launch_bounds__(256) void k_embuv(
    const float* __restrict__ emb1, const float* __restrict__ emb2,
    const float* __restrict__ l1w, const float* __restrict__ l1b,
    const float* __restrict__ l2w, const float* __restrict__ l2b,
    unsigned short* __restrict__ Ux, unsigned short* __restrict__ Vx,
    int* __restrict__ deg)
{
    __shared__ float e1s[16 * DIM], e2s[16 * DIM];
    __shared__ float w1s[DIM * DIM], w2s[DIM * DIM], b1s[DIM], b2s[DIM];
    __shared__ unsigned short Ul[16][KADJ], Vl[16][KADJ];
    const int tid = threadIdx.x;
    const int node0 = blockIdx.x * 16;
    if (tid < 16) deg[node0 + tid] = 0;
    for (int i = tid; i < 16 * DIM; i += 256) {
        e1s[i] = emb1[node0 * DIM + i];
        e2s[i] = emb2[node0 * DIM + i];
    }
    for (int i = tid; i < DIM * DIM; i += 256) { w1s[i] = l1w[i]; w2s[i] = l2w[i]; }
    if (tid < DIM) { b1s[tid] = l1b[tid]; b2s[tid] = l2b[tid]; }
    __syncthreads();
    const int r = tid >> 4;
    const int k0 = (tid & 15) * 5;
    const int PMAP[6] = {0, 0, 1, 1, 0, 2};
    const int QMAP[6] = {0, 1, 0, 1, 2, 0};
    #pragma unroll
    for (int e = 0; e < 5; e++) {
        int k = k0 + e;
        int kp = (k < DIM) ? k : k - DIM;
        float acc1 = b1s[kp], acc2 = b2s[kp];
        for (int kk = 0; kk < DIM; kk++) {
            acc1 += e1s[r * DIM + kk] * w1s[kk * DIM + kp];
            acc2 += e2s[r * DIM + kk] * w2s[kk * DIM + kp];
        }
        float n1v = tanhf(3.0f * acc1), n2v = tanhf(3.0f * acc2);
        float a = (k < DIM) ? n1v : -n2v;
        float b = (k < DIM) ? n2v : n1v;
        unsigned short u0 = f2bf(a); float ra = a - bf2f(u0);
        unsigned short u1 = f2bf(ra); ra -= bf2f(u1);
        unsigned short u2 = f2bf(ra);
        unsigned short v0 = f2bf(b); float rb = b - bf2f(v0);
        unsigned short v1 = f2bf(rb); rb -= bf2f(v1);
        unsigned short v2 = f2bf(rb);
        unsigned short uu[3] = {u0, u1, u2}, vv[3] = {v0, v1, v2};
        #pragma unroll
        for (int bq = 0; bq < 6; bq++) {
            Ul[r][80 * bq + k] = uu[PMAP[bq]];
            Vl[r][80 * bq + k] = vv[QMAP[bq]];
        }
    }
    {
        int c = tid & 15;
        Ul[r][480 + c * 2]     = 0; Vl[r][480 + c * 2]     = 0;
        Ul[r][480 + c * 2 + 1] = 0; Vl[r][480 + c * 2 + 1] = 0;
    }
    __syncthreads();
    #pragma unroll
    for (int q = 0; q < 4; q++) {
        int idx = q * 256 + tid;
        int rr = idx >> 6, c8 = idx & 63;
        size_t off = ((size_t)(node0 + rr)) * KADJ + c8 * 8;
        *(s16x8*)(Ux + off) = *(s16x8*)&Ul[rr][c8 * 8];
        *(s16x8*)(Vx + off) = *(s16x8*)&Vl[rr][c8 * 8];
    }
}

// ---------------- adjacency GEMM (bf16 operands), epilogue -> Mi8 (i8 0/1) + deg ----------------
__global__ __launch_bounds__(512, 2) void gemm_adj8(
    const unsigned short* __restrict__ A, const unsigned short* __restrict__ Bt,
    char* __restrict__ Mi8, int* __restrict__ deg)
{
    constexpr int K = KADJ;        // 512
    constexpr int NT = K / 64;     // 8 K-tiles
    __shared__ __align__(16) unsigned short As[2][256 * 64];
    __shared__ __align__(16) unsigned short Bs[2][256 * 64];

    const int tid = threadIdx.x;
    const int lane = tid & 63;
    const int w = tid >> 6;
    const int wm = w >> 2, wn = w & 3;
    const int fr = lane & 15, kg = lane >> 4;

    const int bid = blockIdx.x;
    const int swz = (bid & 7) * 32 + (bid >> 3);
    const int bx = swz & 15, by = swz >> 4;
    const int c0 = bx * 256, j0 = by * 256;

    const int cid0 = w * 128 + lane, cid1 = cid0 + 64;
    const int r0 = cid0 >> 3, k0c = cid0 & 7;
    const int r1 = cid1 >> 3, k1c = cid1 & 7;
    const int so0 = r0 * K + ((k0c ^ (r0 & 7)) << 3);
    const int so1 = r1 * K + ((k1c ^ (r1 & 7)) << 3);
    const int lb0 = (w * 2 + 0) * 512;
    const int lb1 = (w * 2 + 1) * 512;

    const unsigned short* Aj = A + (size_t)j0 * K;
    const unsigned short* Bc = Bt + (size_t)c0 * K;

#define STAGE_A(buf, half, kt) do { \
    const unsigned short* g_ = Aj + (size_t)((half) * 128) * K + (kt); \
    gload16(g_ + so0, &As[buf][(half) * 8192 + lb0]); \
    gload16(g_ + so1, &As[buf][(half) * 8192 + lb1]); } while (0)
#define STAGE_B(buf, half, kt) do { \
    const unsigned short* g_ = Bc + (size_t)((half) * 128) * K + (kt); \
    gload16(g_ + so0, &Bs[buf][(half) * 8192 + lb0]); \
    gload16(g_ + so1, &Bs[buf][(half) * 8192 + lb1]); } while (0)

    STAGE_A(0, 0, 0);  STAGE_A(0, 1, 0);
    STAGE_B(0, 0, 0);  STAGE_B(0, 1, 0);
    STAGE_A(1, 0, 64); STAGE_A(1, 1, 64);
    STAGE_B(1, 0, 64);
    asm volatile("s_waitcnt vmcnt(6)" ::: "memory");
    bar();

    const int x0 = ((kg) ^ (fr & 7)) << 4;
    const int x1 = ((4 + kg) ^ (fr & 7)) << 4;
    int aOff[8], bOff[4];
    #pragma unroll
    for (int m = 0; m < 8; m++) aOff[m] = (wm * 128 + m * 16 + fr) * 128;
    #pragma unroll
    for (int n = 0; n < 4; n++) bOff[n] = (wn * 64 + n * 16 + fr) * 128;

    s16x8 af0c[4], bf0c[4];
    #pragma unroll
    for (int m = 0; m < 4; m++) af0c[m] = *(const s16x8*)((const char*)As[0] + aOff[m] + x0);
    #pragma unroll
    for (int n = 0; n < 4; n++) bf0c[n] = *(const s16x8*)((const char*)Bs[0] + bOff[n] + x0);

    f32x4 acc[8][4] = {};

    for (int t = 0; t < NT; t++) {
        const int P = t & 1;
        const char* Ap = (const char*)As[P];
        const char* Bp = (const char*)Bs[P];
        const char* Aq = (const char*)As[P ^ 1];
        const char* Bq = (const char*)Bs[P ^ 1];
        const int kt1 = (t + 1) * 64, kt2 = (t + 2) * 64;
        const bool s1 = (t + 1) < NT, s2 = (t + 2) < NT;
        s16x8 af0h[4], af1l[4], af1h[4], bf1[4], af0n[4], bf0n[4];

        #pragma unroll
        for (int m = 0; m < 4; m++) af0h[m] = *(const s16x8*)(Ap + aOff[m + 4] + x0);
        #pragma unroll
        for (int m = 0; m < 4; m++) af1l[m] = *(const s16x8*)(Ap + aOff[m] + x1);
        if (s1) STAGE_B(P ^ 1, 1, kt1);
        __builtin_amdgcn_s_setprio(1);
        #pragma unroll
        for (int m = 0; m < 4; m++)
            #pragma unroll
            for (int n = 0; n < 4; n++)
                acc[m][n] = __builtin_amdgcn_mfma_f32_16x16x32_bf16(af0c[m], bf0c[n], acc[m][n], 0, 0, 0);
        __builtin_amdgcn_s_setprio(0);

        #pragma unroll
        for (int m = 0; m < 4; m++) af1h[m] = *(const s16x8*)(Ap + aOff[m + 4] + x1);
        #pragma unroll
        for (int n = 0; n < 4; n++) bf1[n] = *(const s16x8*)(Bp + bOff[n] + x1);
        __builtin_amdgcn_s_setprio(1);
        #pragma unroll
        for (int m = 4; m < 8; m++)
            #pragma unroll
            for (int n = 0; n < 4; n++)
                acc[m][n] = __builtin_amdgcn_mfma_f32_16x16x32_bf16(af0h[m - 4], bf0c[n], acc[m][n], 0, 0, 0);
        __builtin_amdgcn_s_setprio(0);
        asm volatile("s_waitcnt lgkmcnt(0)" ::: "memory");
        bar();

        __builtin_amdgcn_s_setprio(1);
        #pragma unroll
        for (int m = 0; m < 4; m++)
            #pragma unroll
            for (int n = 0; n < 4; n++)
                acc[m][n] = __builtin_amdgcn_mfma_f32_16x16x32_bf16(af1l[m], bf1[n], acc[m][n], 0, 0, 0);
        __builtin_amdgcn_s_setprio(0);
        if (s2) {
            STAGE_A(P, 0, kt2);
            STAGE_A(P, 1, kt2);
            STAGE_B(P, 0, kt2);
            asm volatile("s_waitcnt vmcnt(6)" ::: "memory");
        } else {
            asm volatile("s_waitcnt vmcnt(0)" ::: "memory");
        }
        bar();

        if (s1) {
            #pragma unroll
            for (int m = 0; m < 4; m++) af0n[m] = *(const s16x8*)(Aq + aOff[m] + x0);
            #pragma unroll
            for (int n = 0; n < 4; n++) bf0n[n] = *(const s16x8*)(Bq + bOff[n] + x0);
        }
        __builtin_amdgcn_s_setprio(1);
        #pragma unroll
        for (int m = 4; m < 8; m++)
            #pragma unroll
            for (int n = 0; n < 4; n++)
                acc[m][n] = __builtin_amdgcn_mfma_f32_16x16x32_bf16(af1h[m - 4], bf1[n], acc[m][n], 0, 0, 0);
        __builtin_amdgcn_s_setprio(0);
        if (s1) {
            #pragma unroll
            for (int m = 0; m < 4; m++) af0c[m] = af0n[m];
            #pragma unroll
            for (int n = 0; n < 4; n++) bf0c[n] = bf0n[n];
        }
    }
#undef STAGE_A
#undef STAGE_B

    #pragma unroll
    for (int m = 0; m < 8; m++) {
        int rbase = j0 + wm * 128 + m * 16 + kg * 4;
        #pragma unroll
        for (int r = 0; r < 4; r++) {
            int row = rbase + r;
            int cnt = 0;
            #pragma unroll
            for (int n = 0; n < 4; n++) {
                int col = c0 + wn * 64 + n * 16 + fr;
                bool bit = (acc[m][n][r] > 0.f) || (row == col);
                Mi8[(size_t)row * NN + col] = bit ? (char)1 : (char)0;
                cnt += bit ? 1 : 0;
            }
            cnt += __shfl_xor(cnt, 1);
            cnt += __shfl_xor(cnt, 2);
            cnt += __shfl_xor(cnt, 4);
            cnt += __shfl_xor(cnt, 8);
            if (fr == 0) atomicAdd(&deg[row], cnt);
        }
    }
}

__global__ void k_dinv(const int* __restrict__ deg, float* __restrict__ dinv,
                       unsigned int* __restrict__ smY) {
    int i = blockIdx.x * 256 + threadIdx.x;
    if (i < NN) { dinv[i] = 1.0f / sqrtf((float)deg[i]); smY[i] = 0u; }
}

// ---------------- k_y1m: MFMA YT bf16 + per-row absmax for quantization ----------------
__global__ __launch_bounds__(256) void k_y1m(
    const float* __restrict__ x, const float* __restrict__ W1,
    const float* __restrict__ dinv, unsigned short* __restrict__ YT,
    unsigned int* __restrict__ smY)
{
    __shared__ __align__(16) unsigned short Xs[128 * 64];
    __shared__ __align__(16) unsigned short Ws[128 * 64];
    const int tid = threadIdx.x;
    const int i0 = blockIdx.x * 128, b = blockIdx.y;

    const float* xg = x + ((size_t)(b * NN + i0)) * DIN;
    #pragma unroll
    for (int q = 0; q < 8; q++) {
        int idx = q * 256 + tid;
        int row = idx >> 4, c4 = idx & 15;
        f32x4 v = *(const f32x4*)(xg + (size_t)row * DIN + c4 * 4);
        s16x4 pk;
        #pragma unroll
        for (int e = 0; e < 4; e++) pk[e] = (short)f2bf(v[e]);
        int chunk = (c4 >> 1) ^ (row & 7);
        *(s16x4*)((char*)Xs + row * 128 + (chunk << 4) + (c4 & 1) * 8) = pk;
    }
    #pragma unroll
    for (int q = 0; q < 8; q++) {
        int idx = q * 256 + tid;
        int k = idx >> 5, f4 = (idx & 31) * 4;
        f32x4 v = ((const f32x4*)W1)[idx];
        #pragma unroll
        for (int e = 0; e < 4; e++) {
            int f = f4 + e;
            int chunk = (k >> 3) ^ (f & 7);
            *(unsigned short*)((char*)Ws + f * 128 + (chunk << 4) + (k & 7) * 2) = f2bf(v[e]);
        }
    }
    __syncthreads();

    const int lane = tid & 63, w = tid >> 6;
    const int wm = w >> 1, wn = w & 1;
    const int fr = lane & 15, kg = lane >> 4;
    f32x4 acc[4][4] = {};
    #pragma unroll
    for (int ks = 0; ks < 2; ks++) {
        int kc = ks * 4 + kg;
        s16x8 af[4], bf[4];
        #pragma unroll
        for (int mt = 0; mt < 4; mt++) {
            int row = wm * 64 + mt * 16 + fr;
            af[mt] = *(const s16x8*)((const char*)Xs + row * 128 + ((kc ^ (row & 7)) << 4));
        }
        #pragma unroll
        for (int nt = 0; nt < 4; nt++) {
            int f = wn * 64 + nt * 16 + fr;
            bf[nt] = *(const s16x8*)((const char*)Ws + f * 128 + ((kc ^ (f & 7)) << 4));
        }
        #pragma unroll
        for (int mt = 0; mt < 4; mt++)
            #pragma unroll
            for (int nt = 0; nt < 4; nt++)
                acc[mt][nt] = __builtin_amdgcn_mfma_f32_16x16x32_bf16(af[mt], bf[nt], acc[mt][nt], 0, 0, 0);
    }
    float am[4] = {0.f, 0.f, 0.f, 0.f};
    #pragma unroll
    for (int mt = 0; mt < 4; mt++) {
        int ibase = i0 + wm * 64 + mt * 16 + kg * 4;
        float dv[4];
        #pragma unroll
        for (int r = 0; r < 4; r++) dv[r] = dinv[ibase + r];
        #pragma unroll
        for (int nt = 0; nt < 4; nt++) {
            int f = wn * 64 + nt * 16 + fr;
            s16x4 pk;
            #pragma unroll
            for (int r = 0; r < 4; r++) {
                float v = acc[mt][nt][r] * dv[r];
                am[nt] = fmaxf(am[nt], fabsf(v));
                pk[r] = (short)f2bf(v);
            }
            *(s16x4*)(YT + (size_t)(b * DH + f) * NN + ibase) = pk;
        }
    }
    #pragma unroll
    for (int nt = 0; nt < 4; nt++) {
        float mv = am[nt];
        mv = fmaxf(mv, __shfl_xor(mv, 16));
        mv = fmaxf(mv, __shfl_xor(mv, 32));
        if (kg == 0)
            atomicMax(&smY[b * DH + wn * 64 + nt * 16 + fr], __float_as_uint(mv));
    }
}

// ---------------- quantize bf16 rows -> i8 with per-row scale max/127 ----------------
__global__ __launch_bounds__(256) void k_quant(
    const unsigned short* __restrict__ src, const unsigned int* __restrict__ smax,
    char* __restrict__ dst)
{
    const int c = blockIdx.x;
    const float s = __uint_as_float(smax[c]);
    const float inv = s > 0.f ? 127.0f / s : 0.f;
    const unsigned short* row = src + (size_t)c * NN;
    char* orow = dst + (size_t)c * NN;
    const int base = threadIdx.x * 16;
    s16x8 a = *(const s16x8*)(row + base);
    s16x8 b = *(const s16x8*)(row + base + 8);
    union { char c8[16]; i32x4 v; } u;
    #pragma unroll
    for (int e = 0; e < 8; e++) {
        int q = (int)rintf(bf2f((unsigned short)a[e]) * inv);
        q = q > 127 ? 127 : (q < -127 ? -127 : q);
        u.c8[e] = (char)q;
    }
    #pragma unroll
    for (int e = 0; e < 8; e++) {
        int q = (int)rintf(bf2f((unsigned short)b[e]) * inv);
        q = q > 127 ? 127 : (q < -127 ? -127 : q);
        u.c8[8 + e] = (char)q;
    }
    *(i32x4*)(orow + base) = u.v;
}

// ======== gemm1 (i8): 256x256, BK=128 i8, 8 waves; 8-phase quadrant schedule ========
__global__ __launch_bounds__(512, 2) void gemm8qi(
    const char* __restrict__ A, const char* __restrict__ Bt,
    unsigned short* __restrict__ H, const float* __restrict__ dinv,
    const unsigned int* __restrict__ smY, const float* __restrict__ bias)
{
    constexpr int KB = NN;         // 4096 bytes per row
    constexpr int NT = 32;         // K-tiles of 128 i8
    __shared__ __align__(16) char As[2][256 * 128];   // 32 KB each
    __shared__ __align__(16) char Bs[2][256 * 128];

    const int tid = threadIdx.x;
    const int lane = tid & 63;
    const int w = tid >> 6;
    const int wm = w >> 2, wn = w & 3;
    const int fr = lane & 15, kg = lane >> 4;

    const int bid = blockIdx.x;
    const int swz = (bid & 7) * 32 + (bid >> 3);
    const int bx = swz & 15, by = swz >> 4;
    const int c0 = bx * 256, j0 = by * 256;

    const char* Aj = A + (size_t)j0 * KB;
    const char* Bc = Bt + (size_t)c0 * KB;

    const int lr = tid >> 3, kcs = tid & 7;

#define STAGE_AQ(buf, q, kt) do { \
    int ra_ = (q) * 64 + lr; \
    int rb_ = ra_ + 128; \
    gload16(Aj + (size_t)ra_ * KB + (kt) + ((kcs ^ (ra_ & 7)) << 4), \
            &As[buf][(q) * 8192 + tid * 16]); \
    gload16(Aj + (size_t)rb_ * KB + (kt) + ((kcs ^ (rb_ & 7)) << 4), \
            &As[buf][(q) * 8192 + 16384 + tid * 16]); \
} while (0)
#define STAGE_BQ(buf, nh, kt) do { \
    int ca_ = tid, cb_ = tid + 512; \
    int r0_ = (ca_ >> 8) * 64 + (nh) * 32 + ((ca_ >> 3) & 31); \
    int r1_ = (cb_ >> 8) * 64 + (nh) * 32 + ((cb_ >> 3) & 31); \
    gload16(Bc + (size_t)r0_ * KB + (kt) + (((ca_ & 7) ^ (r0_ & 7)) << 4), \
            &Bs[buf][(ca_ >> 8) * 8192 + (nh) * 4096 + (ca_ & 255) * 16]); \
    gload16(Bc + (size_t)r1_ * KB + (kt) + (((cb_ & 7) ^ (r1_ & 7)) << 4), \
            &Bs[buf][(cb_ >> 8) * 8192 + (nh) * 4096 + (cb_ & 255) * 16]); \
} while (0)

    STAGE_AQ(0, 0, 0); STAGE_AQ(0, 1, 0);
    STAGE_BQ(0, 0, 0); STAGE_BQ(0, 1, 0);
    STAGE_BQ(1, 0, 128); STAGE_BQ(1, 1, 128);
    asm volatile("s_waitcnt vmcnt(4)" ::: "memory");
    bar();

    const int x0 = ((kg) ^ (fr & 7)) << 4;
    const int x1 = ((4 + kg) ^ (fr & 7)) << 4;
    int aOff[8], bOff[4];
    #pragma unroll
    for (int m = 0; m < 8; m++) aOff[m] = (wm * 128 + m * 16 + fr) * 128;
    #pragma unroll
    for (int n = 0; n < 4; n++) bOff[n] = (wn * 64 + n * 16 + fr) * 128;

    i32x4 acc[8][4] = {};
    const char* A0p = (const char*)As[0];
    const char* B0p = (const char*)Bs[0];
    const char* A1p = (const char*)As[1];
    const char* B1p = (const char*)Bs[1];

#define MFMA_Q(MB, NB_, AF0, AF1, BK0, BK1) do { \
    __builtin_amdgcn_s_setprio(1); \
    _Pragma("unroll") \
    for (int m = 0; m < 4; m++) { \
        _Pragma("unroll") \
        for (int n = 0; n < 2; n++) { \
            acc[(MB) + m][(NB_) + n] = __builtin_amdgcn_mfma_i32_16x16x64_i8( \
                AF0[m], BK0[n], acc[(MB) + m][(NB_) + n], 0, 0, 0); \
            acc[(MB) + m][(NB_) + n] = __builtin_amdgcn_mfma_i32_16x16x64_i8( \
                AF1[m], BK1[n], acc[(MB) + m][(NB_) + n], 0, 0, 0); \
        } \
    } \
    __builtin_amdgcn_s_setprio(0); \
} while (0)

    i32x4 af0[4], af1[4], b0k0[2], b0k1[2], b1k0[2], b1k1[2];

    for (int T = 0; T < NT; T += 2) {
        const bool s2 = (T + 2) < NT, s3 = (T + 3) < NT;
        const int kt1 = (T + 1) * 128, kt2 = (T + 2) * 128, kt3 = (T + 3) * 128;

        #pragma unroll
        for (int m = 0; m < 4; m++) { af0[m] = *(const i32x4*)(A0p + aOff[m] + x0);
                                      af1[m] = *(const i32x4*)(A0p + aOff[m] + x1); }
        #pragma unroll
        for (int n = 0; n < 2; n++) { b0k0[n] = *(const i32x4*)(B0p + bOff[n] + x0);
                                      b0k1[n] = *(const i32x4*)(B0p + bOff[n] + x1); }
        STAGE_AQ(1, 0, kt1);
        bar();
        MFMA_Q(0, 0, af0, af1, b0k0, b0k1);
        bar();

        #pragma unroll
        for (int n = 0; n < 2; n++) { b1k0[n] = *(const i32x4*)(B0p + bOff[n + 2] + x0);
                                      b1k1[n] = *(const i32x4*)(B0p + bOff[n + 2] + x1); }
        STAGE_AQ(1, 1, kt1);
        bar();
        MFMA_Q(0, 2, af0, af1, b1k0, b1k1);
        bar();

        #pragma unroll
        for (int m = 0; m < 4; m++) { af0[m] = *(const i32x4*)(A0p + aOff[m + 4] + x0);
                                      af1[m] = *(const i32x4*)(A0p + aOff[m + 4] + x1); }
        if (s2) STAGE_BQ(0, 0, kt2);
        bar();
        MFMA_Q(4, 0, af0, af1, b0k0, b0k1);
        bar();

        if (s2) { STAGE_BQ(0, 1, kt2);
                  asm volatile("s_waitcnt vmcnt(4)" ::: "memory"); }
        else    { asm volatile("s_waitcnt vmcnt(0)" ::: "memory"); }
        bar();
        MFMA_Q(4, 2, af0, af1, b1k0, b1k1);
        bar();

        #pragma unroll
        for (int m = 0; m < 4; m++) { af0[m] = *(const i32x4*)(A1p + aOff[m] + x0);
                                      af1[m] = *(const i32x4*)(A1p + aOff[m] + x1); }
        #pragma unroll
        for (int n = 0; n < 2; n++) { b0k0[n] = *(const i32x4*)(B1p + bOff[n] + x0);
                                      b0k1[n] = *(const i32x4*)(B1p + bOff[n] + x1); }
        if (s2) STAGE_AQ(0, 0, kt2);
        bar();
        MFMA_Q(0, 0, af0, af1, b0k0, b0k1);
        bar();

        #pragma unroll
        for (int n = 0; n < 2; n++) { b1k0[n] = *(const i32x4*)(B1p + bOff[n + 2] + x0);
                                      b1k1[n] = *(const i32x4*)(B1p + bOff[n + 2] + x1); }
        if (s2) STAGE_AQ(0, 1, kt2);
        bar();
        MFMA_Q(0, 2, af0, af1, b1k0, b1k1);
        bar();

        #pragma unroll
        for (int m = 0; m < 4; m++) { af0[m] = *(const i32x4*)(A1p + aOff[m + 4] + x0);
                                      af1[m] = *(const i32x4*)(A1p + aOff[m + 4] + x1); }
        if (s3) STAGE_BQ(1, 0, kt3);
        bar();
        MFMA_Q(4, 0, af0, af1, b0k0, b0k1);
        bar();

        if (s3) { STAGE_BQ(1, 1, kt3);
                  asm volatile("s_waitcnt vmcnt(4)" ::: "memory"); }
        else    { asm volatile("s_waitcnt vmcnt(0)" ::: "memory"); }
        bar();
        MFMA_Q(4, 2, af0, af1, b1k0, b1k1);
        bar();
    }
#undef MFMA_Q
#undef STAGE_AQ
#undef STAGE_BQ

    #pragma unroll
    for (int m = 0; m < 8; m++) {
        int rbase = j0 + wm * 128 + m * 16 + kg * 4;
        float dv[4];
        #pragma unroll
        for (int r = 0; r < 4; r++) dv[r] = dinv[rbase + r];
        #pragma unroll
        for (int n = 0; n < 4; n++) {
            int gcol = c0 + wn * 64 + n * 16 + fr;
            float bb = bias[gcol & (DH - 1)];
            float sc = __uint_as_float(smY[gcol]) * (1.0f / 127.0f);
            #pragma unroll
            for (int r = 0; r < 4; r++) {
                float v = (float)acc[m][n][r] * sc * dv[r] + bb;
                v = v > 0.f ? v : 0.f;
                H[(size_t)(rbase + r) * NN + gcol] = f2bf(v);
            }
        }
    }
}

// ---------- k_z2: MFMA-based ZT = dinv_j * (H_b @ W2) (bf16, R13 proven) ----------
__global__ __launch_bounds__(256) void k_z2(
    const unsigned short* __restrict__ H, const float* __restrict__ W2,
    const float* __restrict__ dinv, unsigned short* __restrict__ ZT)
{
    __shared__ __align__(16) unsigned short Hs[128 * DH];
    __shared__ __align__(16) unsigned short W2Ts[DOUT * DH];
    const int tid = threadIdx.x;
    const int j0 = blockIdx.x * 128, b = blockIdx.y;
    const unsigned short* Hb = H + (size_t)j0 * NN + b * DH;

    #pragma unroll
    for (int q = 0; q < 8; q++) {
        int cid = q * 256 + tid;
        int row = cid >> 4, kc = cid & 15;
        gload16(Hb + (size_t)row * NN + kc * 8, &Hs[cid * 8]);
    }
    #pragma unroll
    for (int q = 0; q < 16; q++) {
        int idx = q * 256 + tid;
        int f = idx >> 5, g = idx & 31;
        W2Ts[g * DH + f] = f2bf(W2[f * DOUT + g]);
    }
    __syncthreads();

    const int lane = tid & 63, w = tid >> 6;
    const int fr = lane & 15, kg = lane >> 4;
    f32x4 acc[2][2] = {};
    #pragma unroll
    for (int ks = 0; ks < 4; ks++) {
        s16x8 af[2], bf[2];
        #pragma unroll
        for (int mt = 0; mt < 2; mt++) {
            int row = w * 32 + mt * 16 + fr;
            af[mt] = *(const s16x8*)&Hs[row * DH + ks * 32 + kg * 8];
        }
        #pragma unroll
        for (int nt = 0; nt < 2; nt++) {
            int g = nt * 16 + fr;
            bf[nt] = *(const s16x8*)&W2Ts[g * DH + ks * 32 + kg * 8];
        }
        #pragma unroll
        for (int mt = 0; mt < 2; mt++)
            #pragma unroll
            for (int nt = 0; nt < 2; nt++)
                acc[mt][nt] = __builtin_amdgcn_mfma_f32_16x16x32_bf16(af[mt], bf[nt], acc[mt][nt], 0, 0, 0);
    }
    #pragma unroll
    for (int mt = 0; mt < 2; mt++) {
        int jbase = j0 + w * 32 + mt * 16 + kg * 4;
        float dv[4];
        #pragma unroll
        for (int r = 0; r < 4; r++) dv[r] = dinv[jbase + r];
        #pragma unroll
        for (int nt = 0; nt < 2; nt++) {
            int g = nt * 16 + fr;
            s16x4 pk;
            #pragma unroll
            for (int r = 0; r < 4; r++)
                pk[r] = (short)f2bf(acc[mt][nt][r] * dv[r]);
            *(s16x4*)(ZT + (size_t)(b * DOUT + g) * NN + jbase) = pk;
        }
    }
}

// ---------- gsm2h: gemm2 64x128, A = Mi8 expanded to bf16 in-register, B = ZT bf16 ----------
// R13 gsm2 schedule; 5 loads/tile (1 A + 4 B) -> vmcnt(5) = tile t+1 landed.
__global__ __launch_bounds__(256) void gsm2h(
    const char* __restrict__ Mi8, const unsigned short* __restrict__ Bt,
    float* __restrict__ out, const float* __restrict__ dinv,
    const float* __restrict__ bias)
{
    constexpr int KB = NN;         // bytes per Mi8 row
    constexpr int K = NN;          // bf16 elems per ZT row
    constexpr int NT = K / 64;     // 64
    __shared__ __align__(16) char AsmI[2][64 * 64];             // 2 x 4 KB
    __shared__ __align__(16) unsigned short Bsm[2][128 * 64];   // 2 x 16 KB
    const int tid = threadIdx.x;
    const int lane = tid & 63;
    const int w = tid >> 6;
    const int wm = w >> 1, wn = w & 1;     // 2 x 2 waves; per-wave 32 x 64
    const int c0 = blockIdx.x * 128;
    const int j0 = blockIdx.y * 64;
    const int fr = lane & 15, kg = lane >> 4;

    // A staging: 256 chunks of 16B (64 rows x 4 chunks); row = tid>>2, kc = tid&3
    const int rowA = tid >> 2, kcA = tid & 3;
    const int srcA = rowA * KB + ((kcA ^ (rowA & 3)) << 4);
    int srcB[4];
    #pragma unroll
    for (int q = 0; q < 4; q++) {
        int cid = q * 256 + tid;
        int row = cid >> 3, kc = cid & 7;
        srcB[q] = row * K + ((kc ^ (row & 7)) << 3);
    }
    const char* Abase = Mi8 + (size_t)j0 * KB;
    const unsigned short* Bbase = Bt + (size_t)c0 * K;

#define STAGE_T(buf, kt) do { \
    gload16(Abase + (kt) + srcA, &AsmI[buf][tid * 16]); \
    _Pragma("unroll") \
    for (int q = 0; q < 4; q++) \
        gload16(Bbase + (kt) + srcB[q], &Bsm[buf][(q * 256 + tid) * 8]); } while (0)

    STAGE_T(0, 0);
    STAGE_T(1, 64);
    asm volatile("s_waitcnt vmcnt(5)" ::: "memory");
    bar();

    const int x0 = (kg ^ (fr & 7)) << 4;
    const int x1 = ((4 + kg) ^ (fr & 7)) << 4;
    int aRow[2], bOff[4];
    #pragma unroll
    for (int m = 0; m < 2; m++) aRow[m] = wm * 32 + m * 16 + fr;
    #pragma unroll
    for (int n = 0; n < 4; n++) bOff[n] = (wn * 64 + n * 16 + fr) * 128;

    // i8 M frag load + expand to bf16 (0 or 1.0)
#define LOAD_AM(dst, Abuf, m_, ks_) do { \
    int kc_ = (ks_) * 2 + (kg >> 1); \
    const char* p_ = (Abuf) + aRow[m_] * 64 + ((kc_ ^ (aRow[m_] & 3)) << 4) + (kg & 1) * 8; \
    int v0_ = *(const int*)p_; \
    int v1_ = *(const int*)(p_ + 4); \
    _Pragma("unroll") \
    for (int e_ = 0; e_ < 4; e_++) dst[e_]     = ((v0_ >> (8 * e_)) & 0xFF) ? (short)0x3F80 : (short)0; \
    _Pragma("unroll") \
    for (int e_ = 0; e_ < 4; e_++) dst[4 + e_] = ((v1_ >> (8 * e_)) & 0xFF) ? (short)0x3F80 : (short)0; \
} while (0)

    s16x8 afc[2][2], bfc[2][4];
    #pragma unroll
    for (int ks = 0; ks < 2; ks++) {
        int xk = ks ? x1 : x0;
        #pragma unroll
        for (int m = 0; m < 2; m++) LOAD_AM(afc[ks][m], (const char*)AsmI[0], m, ks);
        #pragma unroll
        for (int n = 0; n < 4; n++) bfc[ks][n] = *(const s16x8*)((const char*)Bsm[0] + bOff[n] + xk);
    }
    asm volatile("s_waitcnt lgkmcnt(0)" ::: "memory");
    bar();

    f32x4 acc[2][4] = {};

    for (int t = 0; t < NT; t++) {
        const int P = t & 1;
        const bool s1 = (t + 1) < NT, s2 = (t + 2) < NT;

        // phA: stage t+2 -> P; MFMA ks0 (carried); counted vmcnt; bar
        if (s2) STAGE_T(P, (t + 2) * 64);
        __builtin_amdgcn_s_setprio(1);
        #pragma unroll
        for (int m = 0; m < 2; m++)
            #pragma unroll
            for (int n = 0; n < 4; n++)
                acc[m][n] = __builtin_amdgcn_mfma_f32_16x16x32_bf16(afc[0][m], bfc[0][n], acc[m][n], 0, 0, 0);
        __builtin_amdgcn_s_setprio(0);
        if (s2) asm volatile("s_waitcnt vmcnt(5)" ::: "memory");
        else    asm volatile("s_waitcnt vmcnt(0)" ::: "memory");
        bar();

        // phB: read t+1 frags from P^1; MFMA ks1 (carried); lgkm drain; bar
        s16x8 afn[2][2], bfn[2][4];
        if (s1) {
            const char* Aq = (const char*)AsmI[P ^ 1];
            const char* Bq = (const char*)Bsm[P ^ 1];
            #pragma unroll
            for (int ks = 0; ks < 2; ks++) {
                int xk = ks ? x1 : x0;
                #pragma unroll
                for (int m = 0; m < 2; m++) LOAD_AM(afn[ks][m], Aq, m, ks);
                #pragma unroll
                for (int n = 0; n < 4; n++) bfn[ks][n] = *(const s16x8*)(Bq + bOff[n] + xk);
            }
        }
        __builtin_amdgcn_s_setprio(1);
        #pragma unroll
        for (int m = 0; m < 2; m++)
            #pragma unroll
            for (int n = 0; n < 4; n++)
                acc[m][n] = __builtin_amdgcn_mfma_f32_16x16x32_bf16(afc[1][m], bfc[1][n], acc[m][n], 0, 0, 0);
        __builtin_amdgcn_s_setprio(0);
        asm volatile("s_waitcnt lgkmcnt(0)" ::: "memory");
        bar();
        if (s1) {
            #pragma unroll
            for (int ks = 0; ks < 2; ks++) {
                #pragma unroll
                for (int m = 0; m < 2; m++) afc[ks][m] = afn[ks][m];
                #pragma unroll
                for (int n = 0; n < 4; n++) bfc[ks][n] = bfn[ks][n];
            }
        }
    }
#undef STAGE_T
#undef LOAD_AM

    const float b_lo = bias[fr], b_hi = bias[fr + 16];
    #pragma unroll
    for (int m = 0; m < 2; m++) {
        int rbase = j0 + wm * 32 + m * 16 + kg * 4;
        float dv[4];
        #pragma unroll
        for (int r = 0; r < 4; r++) dv[r] = dinv[rbase + r];
        #pragma unroll
        for (int np = 0; np < 2; np++) {
            int bg = (c0 >> 5) + wn * 2 + np;       // batch index 0..31
            #pragma unroll
            for (int r = 0; r < 4; r++) {
                int row = rbase + r;
                float v0 = acc[m][np * 2][r]     * dv[r] + b_lo;   // g = fr
                float v1 = acc[m][np * 2 + 1][r] * dv[r] + b_hi;   // g = fr+16
                float mx = fmaxf(v0, v1);
                #pragma unroll
                for (int d = 8; d; d >>= 1) mx = fmaxf(mx, __shfl_xor(mx, d));
                float e0 = expf(v0 - mx), e1 = expf(v1 - mx);
                float s = e0 + e1;
                #pragma unroll
                for (int d = 8; d; d >>= 1) s += __shfl_xor(s, d);
                float inv = 1.0f / s;
                size_t ob = ((size_t)bg * NN + row) * DOUT;
                out[ob + fr]      = e0 * inv;
                out[ob + fr + 16] = e1 * inv;
            }
        }
    }
}

extern "C" void kernel_launch(void* const* d_in, const int* in_sizes, int n_in,
                              void* d_out, int out_size, void* d_ws, size_t ws_size,
                              hipStream_t stream)
{
    (void)in_sizes; (void)n_in; (void)out_size; (void)ws_size;
    const float* x    = (const float*)d_in[0];
    const float* emb1 = (const float*)d_in[1];
    const float* emb2 = (const float*)d_in[2];
    const float* l1w  = (const float*)d_in[3];
    const float* l1b  = (const float*)d_in[4];
    const float* l2w  = (const float*)d_in[5];
    const float* l2b  = (const float*)d_in[6];
    const float* g1w  = (const float*)d_in[7];
    const float* g1b  = (const float*)d_in[8];
    const float* g2w  = (const float*)d_in[9];
    const float* g2b  = (const float*)d_in[10];
    float* out = (float*)d_out;

    char* w = (char*)d_ws;
    int* deg = (int*)w;                       w += NN * 4;
    float* dinv = (float*)w;                  w += NN * 4;
    unsigned int* smY = (unsigned int*)w;     w += NN * 4;
    char* Mi8 = (char*)w;                     w += (size_t)NN * NN;
    unsigned short* YT = (unsigned short*)w;  w += (size_t)NN * NN * 2;
    char* Yq = (char*)w;                      w += (size_t)NN * NN;
    unsigned short* H  = (unsigned short*)w;  w += (size_t)NN * NN * 2;
    unsigned short* ZT = (unsigned short*)w;  w += (size_t)(NB * DOUT) * NN * 2;
    // Ux/Vx live in YT's region (dead until k_y1m, which runs after gemm_adj8)
    unsigned short* Ux = YT;
    unsigned short* Vx = YT + (size_t)NN * KADJ;

    k_embuv<<<256, 256, 0, stream>>>(emb1, emb2, l1w, l1b, l2w, l2b, Ux, Vx, deg);
    gemm_adj8<<<256, 512, 0, stream>>>(Vx, Ux, Mi8, deg);
    k_dinv<<<16, 256, 0, stream>>>(deg, dinv, smY);
    k_y1m<<<dim3(32, 32), 256, 0, stream>>>(x, g1w, dinv, YT, smY);
    k_quant<<<NN, 256, 0, stream>>>(YT, smY, Yq);
    gemm8qi<<<256, 512, 0, stream>>>(Mi8, Yq, H, dinv, smY, g1b);
    k_z2<<<dim3(32, 32), 256, 0, stream>>>(H, g2w, dinv, ZT);
    gsm2h<<<dim3(8, 64), 256, 0, stream>>>(Mi8, ZT, out, dinv, g2b);
}

// Round 16
// 222.334 us; speedup vs baseline: 1.4469x; 1.0101x over previous
//
#include <hip/hip_runtime.h>

typedef float f32x4 __attribute__((ext_vector_type(4)));
typedef short s16x8 __attribute__((ext_vector_type(8)));
typedef short s16x4 __attribute__((ext_vector_type(4)));
typedef int i32x4 __attribute__((ext_vector_type(4)));

#define NN 4096
#define NB 32
#define DIN 64
#define DH 128
#define DOUT 32
#define DIM 40
#define KADJ 512   // 6 split-blocks x 80, zero-padded to 512

__device__ __forceinline__ unsigned short f2bf(float f) {
    unsigned int u = __float_as_uint(f);
    unsigned int r = (u + 0x7FFFu + ((u >> 16) & 1u)) >> 16;
    return (unsigned short)r;
}
__device__ __forceinline__ float bf2f(unsigned short h) {
    return __uint_as_float(((unsigned int)h) << 16);
}
__device__ __forceinline__ void gload16(const void* g, void* l) {
    __builtin_amdgcn_global_load_lds(
        (const __attribute__((address_space(1))) unsigned int*)g,
        (__attribute__((address_space(3))) unsigned int*)l, 16, 0, 0);
}
__device__ __forceinline__ void bar() {
    asm volatile("" ::: "memory");
    __builtin_amdgcn_s_barrier();
    asm volatile("" ::: "memory");
}

// ---------------- fused: n1/n2 = tanh(3*(emb @ W + b)) -> 3-way bf16 split operands ----------------
__global__ __launch_bounds__(256) void k_embuv(
    const float* __restrict__ emb1, const float* __restrict__ emb2,
    const float* __restrict__ l1w, const float* __restrict__ l1b,
    const float* __restrict__ l2w, const float* __restrict__ l2b,
    unsigned short* __restrict__ Ux, unsigned short* __restrict__ Vx,
    int* __restrict__ deg)
{
    __shared__ float e1s[16 * DIM], e2s[16 * DIM];
    __shared__ float w1s[DIM * DIM], w2s[DIM * DIM], b1s[DIM], b2s[DIM];
    __shared__ unsigned short Ul[16][KADJ], Vl[16][KADJ];
    const int tid = threadIdx.x;
    const int node0 = blockIdx.x * 16;
    if (tid < 16) deg[node0 + tid] = 0;
    for (int i = tid; i < 16 * DIM; i += 256) {
        e1s[i] = emb1[node0 * DIM + i];
        e2s[i] = emb2[node0 * DIM + i];
    }
    for (int i = tid; i < DIM * DIM; i += 256) { w1s[i] = l1w[i]; w2s[i] = l2w[i]; }
    if (tid < DIM) { b1s[tid] = l1b[tid]; b2s[tid] = l2b[tid]; }
    __syncthreads();
    const int r = tid >> 4;
    const int k0 = (tid & 15) * 5;
    const int PMAP[6] = {0, 0, 1, 1, 0, 2};
    const int QMAP[6] = {0, 1, 0, 1, 2, 0};
    #pragma unroll
    for (int e = 0; e < 5; e++) {
        int k = k0 + e;
        int kp = (k < DIM) ? k : k - DIM;
        float acc1 = b1s[kp], acc2 = b2s[kp];
        for (int kk = 0; kk < DIM; kk++) {
            acc1 += e1s[r * DIM + kk] * w1s[kk * DIM + kp];
            acc2 += e2s[r * DIM + kk] * w2s[kk * DIM + kp];
        }
        float n1v = tanhf(3.0f * acc1), n2v = tanhf(3.0f * acc2);
        float a = (k < DIM) ? n1v : -n2v;
        float b = (k < DIM) ? n2v : n1v;
        unsigned short u0 = f2bf(a); float ra = a - bf2f(u0);
        unsigned short u1 = f2bf(ra); ra -= bf2f(u1);
        unsigned short u2 = f2bf(ra);
        unsigned short v0 = f2bf(b); float rb = b - bf2f(v0);
        unsigned short v1 = f2bf(rb); rb -= bf2f(v1);
        unsigned short v2 = f2bf(rb);
        unsigned short uu[3] = {u0, u1, u2}, vv[3] = {v0, v1, v2};
        #pragma unroll
        for (int bq = 0; bq < 6; bq++) {
            Ul[r][80 * bq + k] = uu[PMAP[bq]];
            Vl[r][80 * bq + k] = vv[QMAP[bq]];
        }
    }
    {
        int c = tid & 15;
        Ul[r][480 + c * 2]     = 0; Vl[r][480 + c * 2]     = 0;
        Ul[r][480 + c * 2 + 1] = 0; Vl[r][480 + c * 2 + 1] = 0;
    }
    __syncthreads();
    #pragma unroll
    for (int q = 0; q < 4; q++) {
        int idx = q * 256 + tid;
        int rr = idx >> 6, c8 = idx & 63;
        size_t off = ((size_t)(node0 + rr)) * KADJ + c8 * 8;
        *(s16x8*)(Ux + off) = *(s16x8*)&Ul[rr][c8 * 8];
        *(s16x8*)(Vx + off) = *(s16x8*)&Vl[rr][c8 * 8];
    }
}

// ---------------- adjacency GEMM (bf16 operands), epilogue -> Mi8 (i8 0/1) + deg ----------------
__global__ __launch_bounds__(512, 2) void gemm_adj8(
    const unsigned short* __restrict__ A, const unsigned short* __restrict__ Bt,
    char* __restrict__ Mi8, int* __restrict__ deg)
{
    constexpr int K = KADJ;        // 512
    constexpr int NT = K / 64;     // 8 K-tiles
    __shared__ __align__(16) unsigned short As[2][256 * 64];
    __shared__ __align__(16) unsigned short Bs[2][256 * 64];

    const int tid = threadIdx.x;
    const int lane = tid & 63;
    const int w = tid >> 6;
    const int wm = w >> 2, wn = w & 3;
    const int fr = lane & 15, kg = lane >> 4;

    const int bid = blockIdx.x;
    const int swz = (bid & 7) * 32 + (bid >> 3);
    const int bx = swz & 15, by = swz >> 4;
    const int c0 = bx * 256, j0 = by * 256;

    const int cid0 = w * 128 + lane, cid1 = cid0 + 64;
    const int r0 = cid0 >> 3, k0c = cid0 & 7;
    const int r1 = cid1 >> 3, k1c = cid1 & 7;
    const int so0 = r0 * K + ((k0c ^ (r0 & 7)) << 3);
    const int so1 = r1 * K + ((k1c ^ (r1 & 7)) << 3);
    const int lb0 = (w * 2 + 0) * 512;
    const int lb1 = (w * 2 + 1) * 512;

    const unsigned short* Aj = A + (size_t)j0 * K;
    const unsigned short* Bc = Bt + (size_t)c0 * K;

#define STAGE_A(buf, half, kt) do { \
    const unsigned short* g_ = Aj + (size_t)((half) * 128) * K + (kt); \
    gload16(g_ + so0, &As[buf][(half) * 8192 + lb0]); \
    gload16(g_ + so1, &As[buf][(half) * 8192 + lb1]); } while (0)
#define STAGE_B(buf, half, kt) do { \
    const unsigned short* g_ = Bc + (size_t)((half) * 128) * K + (kt); \
    gload16(g_ + so0, &Bs[buf][(half) * 8192 + lb0]); \
    gload16(g_ + so1, &Bs[buf][(half) * 8192 + lb1]); } while (0)

    STAGE_A(0, 0, 0);  STAGE_A(0, 1, 0);
    STAGE_B(0, 0, 0);  STAGE_B(0, 1, 0);
    STAGE_A(1, 0, 64); STAGE_A(1, 1, 64);
    STAGE_B(1, 0, 64);
    asm volatile("s_waitcnt vmcnt(6)" ::: "memory");
    bar();

    const int x0 = ((kg) ^ (fr & 7)) << 4;
    const int x1 = ((4 + kg) ^ (fr & 7)) << 4;
    int aOff[8], bOff[4];
    #pragma unroll
    for (int m = 0; m < 8; m++) aOff[m] = (wm * 128 + m * 16 + fr) * 128;
    #pragma unroll
    for (int n = 0; n < 4; n++) bOff[n] = (wn * 64 + n * 16 + fr) * 128;

    s16x8 af0c[4], bf0c[4];
    #pragma unroll
    for (int m = 0; m < 4; m++) af0c[m] = *(const s16x8*)((const char*)As[0] + aOff[m] + x0);
    #pragma unroll
    for (int n = 0; n < 4; n++) bf0c[n] = *(const s16x8*)((const char*)Bs[0] + bOff[n] + x0);

    f32x4 acc[8][4] = {};

    for (int t = 0; t < NT; t++) {
        const int P = t & 1;
        const char* Ap = (const char*)As[P];
        const char* Bp = (const char*)Bs[P];
        const char* Aq = (const char*)As[P ^ 1];
        const char* Bq = (const char*)Bs[P ^ 1];
        const int kt1 = (t + 1) * 64, kt2 = (t + 2) * 64;
        const bool s1 = (t + 1) < NT, s2 = (t + 2) < NT;
        s16x8 af0h[4], af1l[4], af1h[4], bf1[4], af0n[4], bf0n[4];

        #pragma unroll
        for (int m = 0; m < 4; m++) af0h[m] = *(const s16x8*)(Ap + aOff[m + 4] + x0);
        #pragma unroll
        for (int m = 0; m < 4; m++) af1l[m] = *(const s16x8*)(Ap + aOff[m] + x1);
        if (s1) STAGE_B(P ^ 1, 1, kt1);
        __builtin_amdgcn_s_setprio(1);
        #pragma unroll
        for (int m = 0; m < 4; m++)
            #pragma unroll
            for (int n = 0; n < 4; n++)
                acc[m][n] = __builtin_amdgcn_mfma_f32_16x16x32_bf16(af0c[m], bf0c[n], acc[m][n], 0, 0, 0);
        __builtin_amdgcn_s_setprio(0);

        #pragma unroll
        for (int m = 0; m < 4; m++) af1h[m] = *(const s16x8*)(Ap + aOff[m + 4] + x1);
        #pragma unroll
        for (int n = 0; n < 4; n++) bf1[n] = *(const s16x8*)(Bp + bOff[n] + x1);
        __builtin_amdgcn_s_setprio(1);
        #pragma unroll
        for (int m = 4; m < 8; m++)
            #pragma unroll
            for (int n = 0; n < 4; n++)
                acc[m][n] = __builtin_amdgcn_mfma_f32_16x16x32_bf16(af0h[m - 4], bf0c[n], acc[m][n], 0, 0, 0);
        __builtin_amdgcn_s_setprio(0);
        asm volatile("s_waitcnt lgkmcnt(0)" ::: "memory");
        bar();

        __builtin_amdgcn_s_setprio(1);
        #pragma unroll
        for (int m = 0; m < 4; m++)
            #pragma unroll
            for (int n = 0; n < 4; n++)
                acc[m][n] = __builtin_amdgcn_mfma_f32_16x16x32_bf16(af1l[m], bf1[n], acc[m][n], 0, 0, 0);
        __builtin_amdgcn_s_setprio(0);
        if (s2) {
            STAGE_A(P, 0, kt2);
            STAGE_A(P, 1, kt2);
            STAGE_B(P, 0, kt2);
            asm volatile("s_waitcnt vmcnt(6)" ::: "memory");
        } else {
            asm volatile("s_waitcnt vmcnt(0)" ::: "memory");
        }
        bar();

        if (s1) {
            #pragma unroll
            for (int m = 0; m < 4; m++) af0n[m] = *(const s16x8*)(Aq + aOff[m] + x0);
            #pragma unroll
            for (int n = 0; n < 4; n++) bf0n[n] = *(const s16x8*)(Bq + bOff[n] + x0);
        }
        __builtin_amdgcn_s_setprio(1);
        #pragma unroll
        for (int m = 4; m < 8; m++)
            #pragma unroll
            for (int n = 0; n < 4; n++)
                acc[m][n] = __builtin_amdgcn_mfma_f32_16x16x32_bf16(af1h[m - 4], bf1[n], acc[m][n], 0, 0, 0);
        __builtin_amdgcn_s_setprio(0);
        if (s1) {
            #pragma unroll
            for (int m = 0; m < 4; m++) af0c[m] = af0n[m];
            #pragma unroll
            for (int n = 0; n < 4; n++) bf0c[n] = bf0n[n];
        }
    }
#undef STAGE_A
#undef STAGE_B

    #pragma unroll
    for (int m = 0; m < 8; m++) {
        int rbase = j0 + wm * 128 + m * 16 + kg * 4;
        #pragma unroll
        for (int r = 0; r < 4; r++) {
            int row = rbase + r;
            int cnt = 0;
            #pragma unroll
            for (int n = 0; n < 4; n++) {
                int col = c0 + wn * 64 + n * 16 + fr;
                bool bit = (acc[m][n][r] > 0.f) || (row == col);
                Mi8[(size_t)row * NN + col] = bit ? (char)1 : (char)0;
                cnt += bit ? 1 : 0;
            }
            cnt += __shfl_xor(cnt, 1);
            cnt += __shfl_xor(cnt, 2);
            cnt += __shfl_xor(cnt, 4);
            cnt += __shfl_xor(cnt, 8);
            if (fr == 0) atomicAdd(&deg[row], cnt);
        }
    }
}

__global__ void k_dinv(const int* __restrict__ deg, float* __restrict__ dinv,
                       unsigned int* __restrict__ smY) {
    int i = blockIdx.x * 256 + threadIdx.x;
    if (i < NN) { dinv[i] = 1.0f / sqrtf((float)deg[i]); smY[i] = 0u; }
}

// ---------------- k_y1m: MFMA YT bf16 + per-row absmax for quantization ----------------
__global__ __launch_bounds__(256) void k_y1m(
    const float* __restrict__ x, const float* __restrict__ W1,
    const float* __restrict__ dinv, unsigned short* __restrict__ YT,
    unsigned int* __restrict__ smY)
{
    __shared__ __align__(16) unsigned short Xs[128 * 64];
    __shared__ __align__(16) unsigned short Ws[128 * 64];
    const int tid = threadIdx.x;
    const int i0 = blockIdx.x * 128, b = blockIdx.y;

    const float* xg = x + ((size_t)(b * NN + i0)) * DIN;
    #pragma unroll
    for (int q = 0; q < 8; q++) {
        int idx = q * 256 + tid;
        int row = idx >> 4, c4 = idx & 15;
        f32x4 v = *(const f32x4*)(xg + (size_t)row * DIN + c4 * 4);
        s16x4 pk;
        #pragma unroll
        for (int e = 0; e < 4; e++) pk[e] = (short)f2bf(v[e]);
        int chunk = (c4 >> 1) ^ (row & 7);
        *(s16x4*)((char*)Xs + row * 128 + (chunk << 4) + (c4 & 1) * 8) = pk;
    }
    #pragma unroll
    for (int q = 0; q < 8; q++) {
        int idx = q * 256 + tid;
        int k = idx >> 5, f4 = (idx & 31) * 4;
        f32x4 v = ((const f32x4*)W1)[idx];
        #pragma unroll
        for (int e = 0; e < 4; e++) {
            int f = f4 + e;
            int chunk = (k >> 3) ^ (f & 7);
            *(unsigned short*)((char*)Ws + f * 128 + (chunk << 4) + (k & 7) * 2) = f2bf(v[e]);
        }
    }
    __syncthreads();

    const int lane = tid & 63, w = tid >> 6;
    const int wm = w >> 1, wn = w & 1;
    const int fr = lane & 15, kg = lane >> 4;
    f32x4 acc[4][4] = {};
    #pragma unroll
    for (int ks = 0; ks < 2; ks++) {
        int kc = ks * 4 + kg;
        s16x8 af[4], bf[4];
        #pragma unroll
        for (int mt = 0; mt < 4; mt++) {
            int row = wm * 64 + mt * 16 + fr;
            af[mt] = *(const s16x8*)((const char*)Xs + row * 128 + ((kc ^ (row & 7)) << 4));
        }
        #pragma unroll
        for (int nt = 0; nt < 4; nt++) {
            int f = wn * 64 + nt * 16 + fr;
            bf[nt] = *(const s16x8*)((const char*)Ws + f * 128 + ((kc ^ (f & 7)) << 4));
        }
        #pragma unroll
        for (int mt = 0; mt < 4; mt++)
            #pragma unroll
            for (int nt = 0; nt < 4; nt++)
                acc[mt][nt] = __builtin_amdgcn_mfma_f32_16x16x32_bf16(af[mt], bf[nt], acc[mt][nt], 0, 0, 0);
    }
    float am[4] = {0.f, 0.f, 0.f, 0.f};
    #pragma unroll
    for (int mt = 0; mt < 4; mt++) {
        int ibase = i0 + wm * 64 + mt * 16 + kg * 4;
        float dv[4];
        #pragma unroll
        for (int r = 0; r < 4; r++) dv[r] = dinv[ibase + r];
        #pragma unroll
        for (int nt = 0; nt < 4; nt++) {
            int f = wn * 64 + nt * 16 + fr;
            s16x4 pk;
            #pragma unroll
            for (int r = 0; r < 4; r++) {
                float v = acc[mt][nt][r] * dv[r];
                am[nt] = fmaxf(am[nt], fabsf(v));
                pk[r] = (short)f2bf(v);
            }
            *(s16x4*)(YT + (size_t)(b * DH + f) * NN + ibase) = pk;
        }
    }
    #pragma unroll
    for (int nt = 0; nt < 4; nt++) {
        float mv = am[nt];
        mv = fmaxf(mv, __shfl_xor(mv, 16));
        mv = fmaxf(mv, __shfl_xor(mv, 32));
        if (kg == 0)
            atomicMax(&smY[b * DH + wn * 64 + nt * 16 + fr], __float_as_uint(mv));
    }
}

// ---------------- quantize bf16 rows -> i8 with per-row scale max/127 ----------------
__global__ __launch_bounds__(256) void k_quant(
    const unsigned short* __restrict__ src, const unsigned int* __restrict__ smax,
    char* __restrict__ dst)
{
    const int c = blockIdx.x;
    const float s = __uint_as_float(smax[c]);
    const float inv = s > 0.f ? 127.0f / s : 0.f;
    const unsigned short* row = src + (size_t)c * NN;
    char* orow = dst + (size_t)c * NN;
    const int base = threadIdx.x * 16;
    s16x8 a = *(const s16x8*)(row + base);
    s16x8 b = *(const s16x8*)(row + base + 8);
    union { char c8[16]; i32x4 v; } u;
    #pragma unroll
    for (int e = 0; e < 8; e++) {
        int q = (int)rintf(bf2f((unsigned short)a[e]) * inv);
        q = q > 127 ? 127 : (q < -127 ? -127 : q);
        u.c8[e] = (char)q;
    }
    #pragma unroll
    for (int e = 0; e < 8; e++) {
        int q = (int)rintf(bf2f((unsigned short)b[e]) * inv);
        q = q > 127 ? 127 : (q < -127 ? -127 : q);
        u.c8[8 + e] = (char)q;
    }
    *(i32x4*)(orow + base) = u.v;
}

// ======== gemm1 (i8): 256x256, BK=128 i8, 8 waves; 8-phase quadrant schedule ========
__global__ __launch_bounds__(512, 2) void gemm8qi(
    const char* __restrict__ A, const char* __restrict__ Bt,
    unsigned short* __restrict__ H, const float* __restrict__ dinv,
    const unsigned int* __restrict__ smY, const float* __restrict__ bias)
{
    constexpr int KB = NN;         // 4096 bytes per row
    constexpr int NT = 32;         // K-tiles of 128 i8
    __shared__ __align__(16) char As[2][256 * 128];   // 32 KB each
    __shared__ __align__(16) char Bs[2][256 * 128];

    const int tid = threadIdx.x;
    const int lane = tid & 63;
    const int w = tid >> 6;
    const int wm = w >> 2, wn = w & 3;
    const int fr = lane & 15, kg = lane >> 4;

    const int bid = blockIdx.x;
    const int swz = (bid & 7) * 32 + (bid >> 3);
    const int bx = swz & 15, by = swz >> 4;
    const int c0 = bx * 256, j0 = by * 256;

    const char* Aj = A + (size_t)j0 * KB;
    const char* Bc = Bt + (size_t)c0 * KB;

    const int lr = tid >> 3, kcs = tid & 7;

#define STAGE_AQ(buf, q, kt) do { \
    int ra_ = (q) * 64 + lr; \
    int rb_ = ra_ + 128; \
    gload16(Aj + (size_t)ra_ * KB + (kt) + ((kcs ^ (ra_ & 7)) << 4), \
            &As[buf][(q) * 8192 + tid * 16]); \
    gload16(Aj + (size_t)rb_ * KB + (kt) + ((kcs ^ (rb_ & 7)) << 4), \
            &As[buf][(q) * 8192 + 16384 + tid * 16]); \
} while (0)
#define STAGE_BQ(buf, nh, kt) do { \
    int ca_ = tid, cb_ = tid + 512; \
    int r0_ = (ca_ >> 8) * 64 + (nh) * 32 + ((ca_ >> 3) & 31); \
    int r1_ = (cb_ >> 8) * 64 + (nh) * 32 + ((cb_ >> 3) & 31); \
    gload16(Bc + (size_t)r0_ * KB + (kt) + (((ca_ & 7) ^ (r0_ & 7)) << 4), \
            &Bs[buf][(ca_ >> 8) * 8192 + (nh) * 4096 + (ca_ & 255) * 16]); \
    gload16(Bc + (size_t)r1_ * KB + (kt) + (((cb_ & 7) ^ (r1_ & 7)) << 4), \
            &Bs[buf][(cb_ >> 8) * 8192 + (nh) * 4096 + (cb_ & 255) * 16]); \
} while (0)

    STAGE_AQ(0, 0, 0); STAGE_AQ(0, 1, 0);
    STAGE_BQ(0, 0, 0); STAGE_BQ(0, 1, 0);
    STAGE_BQ(1, 0, 128); STAGE_BQ(1, 1, 128);
    asm volatile("s_waitcnt vmcnt(4)" ::: "memory");
    bar();

    const int x0 = ((kg) ^ (fr & 7)) << 4;
    const int x1 = ((4 + kg) ^ (fr & 7)) << 4;
    int aOff[8], bOff[4];
    #pragma unroll
    for (int m = 0; m < 8; m++) aOff[m] = (wm * 128 + m * 16 + fr) * 128;
    #pragma unroll
    for (int n = 0; n < 4; n++) bOff[n] = (wn * 64 + n * 16 + fr) * 128;

    i32x4 acc[8][4] = {};
    const char* A0p = (const char*)As[0];
    const char* B0p = (const char*)Bs[0];
    const char* A1p = (const char*)As[1];
    const char* B1p = (const char*)Bs[1];

#define MFMA_Q(MB, NB_, AF0, AF1, BK0, BK1) do { \
    __builtin_amdgcn_s_setprio(1); \
    _Pragma("unroll") \
    for (int m = 0; m < 4; m++) { \
        _Pragma("unroll") \
        for (int n = 0; n < 2; n++) { \
            acc[(MB) + m][(NB_) + n] = __builtin_amdgcn_mfma_i32_16x16x64_i8( \
                AF0[m], BK0[n], acc[(MB) + m][(NB_) + n], 0, 0, 0); \
            acc[(MB) + m][(NB_) + n] = __builtin_amdgcn_mfma_i32_16x16x64_i8( \
                AF1[m], BK1[n], acc[(MB) + m][(NB_) + n], 0, 0, 0); \
        } \
    } \
    __builtin_amdgcn_s_setprio(0); \
} while (0)

    i32x4 af0[4], af1[4], b0k0[2], b0k1[2], b1k0[2], b1k1[2];

    for (int T = 0; T < NT; T += 2) {
        const bool s2 = (T + 2) < NT, s3 = (T + 3) < NT;
        const int kt1 = (T + 1) * 128, kt2 = (T + 2) * 128, kt3 = (T + 3) * 128;

        #pragma unroll
        for (int m = 0; m < 4; m++) { af0[m] = *(const i32x4*)(A0p + aOff[m] + x0);
                                      af1[m] = *(const i32x4*)(A0p + aOff[m] + x1); }
        #pragma unroll
        for (int n = 0; n < 2; n++) { b0k0[n] = *(const i32x4*)(B0p + bOff[n] + x0);
                                      b0k1[n] = *(const i32x4*)(B0p + bOff[n] + x1); }
        STAGE_AQ(1, 0, kt1);
        bar();
        MFMA_Q(0, 0, af0, af1, b0k0, b0k1);
        bar();

        #pragma unroll
        for (int n = 0; n < 2; n++) { b1k0[n] = *(const i32x4*)(B0p + bOff[n + 2] + x0);
                                      b1k1[n] = *(const i32x4*)(B0p + bOff[n + 2] + x1); }
        STAGE_AQ(1, 1, kt1);
        bar();
        MFMA_Q(0, 2, af0, af1, b1k0, b1k1);
        bar();

        #pragma unroll
        for (int m = 0; m < 4; m++) { af0[m] = *(const i32x4*)(A0p + aOff[m + 4] + x0);
                                      af1[m] = *(const i32x4*)(A0p + aOff[m + 4] + x1); }
        if (s2) STAGE_BQ(0, 0, kt2);
        bar();
        MFMA_Q(4, 0, af0, af1, b0k0, b0k1);
        bar();

        if (s2) { STAGE_BQ(0, 1, kt2);
                  asm volatile("s_waitcnt vmcnt(4)" ::: "memory"); }
        else    { asm volatile("s_waitcnt vmcnt(0)" ::: "memory"); }
        bar();
        MFMA_Q(4, 2, af0, af1, b1k0, b1k1);
        bar();

        #pragma unroll
        for (int m = 0; m < 4; m++) { af0[m] = *(const i32x4*)(A1p + aOff[m] + x0);
                                      af1[m] = *(const i32x4*)(A1p + aOff[m] + x1); }
        #pragma unroll
        for (int n = 0; n < 2; n++) { b0k0[n] = *(const i32x4*)(B1p + bOff[n] + x0);
                                      b0k1[n] = *(const i32x4*)(B1p + bOff[n] + x1); }
        if (s2) STAGE_AQ(0, 0, kt2);
        bar();
        MFMA_Q(0, 0, af0, af1, b0k0, b0k1);
        bar();

        #pragma unroll
        for (int n = 0; n < 2; n++) { b1k0[n] = *(const i32x4*)(B1p + bOff[n + 2] + x0);
                                      b1k1[n] = *(const i32x4*)(B1p + bOff[n + 2] + x1); }
        if (s2) STAGE_AQ(0, 1, kt2);
        bar();
        MFMA_Q(0, 2, af0, af1, b1k0, b1k1);
        bar();

        #pragma unroll
        for (int m = 0; m < 4; m++) { af0[m] = *(const i32x4*)(A1p + aOff[m + 4] + x0);
                                      af1[m] = *(const i32x4*)(A1p + aOff[m + 4] + x1); }
        if (s3) STAGE_BQ(1, 0, kt3);
        bar();
        MFMA_Q(4, 0, af0, af1, b0k0, b0k1);
        bar();

        if (s3) { STAGE_BQ(1, 1, kt3);
                  asm volatile("s_waitcnt vmcnt(4)" ::: "memory"); }
        else    { asm volatile("s_waitcnt vmcnt(0)" ::: "memory"); }
        bar();
        MFMA_Q(4, 2, af0, af1, b1k0, b1k1);
        bar();
    }
#undef MFMA_Q
#undef STAGE_AQ
#undef STAGE_BQ

    #pragma unroll
    for (int m = 0; m < 8; m++) {
        int rbase = j0 + wm * 128 + m * 16 + kg * 4;
        float dv[4];
        #pragma unroll
        for (int r = 0; r < 4; r++) dv[r] = dinv[rbase + r];
        #pragma unroll
        for (int n = 0; n < 4; n++) {
            int gcol = c0 + wn * 64 + n * 16 + fr;
            float bb = bias[gcol & (DH - 1)];
            float sc = __uint_as_float(smY[gcol]) * (1.0f / 127.0f);
            #pragma unroll
            for (int r = 0; r < 4; r++) {
                float v = (float)acc[m][n][r] * sc * dv[r] + bb;
                v = v > 0.f ? v : 0.f;
                H[(size_t)(rbase + r) * NN + gcol] = f2bf(v);
            }
        }
    }
}

// ---------- k_z2: MFMA-based ZT = dinv_j * (H_b @ W2) (bf16) ----------
__global__ __launch_bounds__(256) void k_z2(
    const unsigned short* __restrict__ H, const float* __restrict__ W2,
    const float* __restrict__ dinv, unsigned short* __restrict__ ZT)
{
    __shared__ __align__(16) unsigned short Hs[128 * DH];
    __shared__ __align__(16) unsigned short W2Ts[DOUT * DH];
    const int tid = threadIdx.x;
    const int j0 = blockIdx.x * 128, b = blockIdx.y;
    const unsigned short* Hb = H + (size_t)j0 * NN + b * DH;

    #pragma unroll
    for (int q = 0; q < 8; q++) {
        int cid = q * 256 + tid;
        int row = cid >> 4, kc = cid & 15;
        gload16(Hb + (size_t)row * NN + kc * 8, &Hs[cid * 8]);
    }
    #pragma unroll
    for (int q = 0; q < 16; q++) {
        int idx = q * 256 + tid;
        int f = idx >> 5, g = idx & 31;
        W2Ts[g * DH + f] = f2bf(W2[f * DOUT + g]);
    }
    __syncthreads();

    const int lane = tid & 63, w = tid >> 6;
    const int fr = lane & 15, kg = lane >> 4;
    f32x4 acc[2][2] = {};
    #pragma unroll
    for (int ks = 0; ks < 4; ks++) {
        s16x8 af[2], bf[2];
        #pragma unroll
        for (int mt = 0; mt < 2; mt++) {
            int row = w * 32 + mt * 16 + fr;
            af[mt] = *(const s16x8*)&Hs[row * DH + ks * 32 + kg * 8];
        }
        #pragma unroll
        for (int nt = 0; nt < 2; nt++) {
            int g = nt * 16 + fr;
            bf[nt] = *(const s16x8*)&W2Ts[g * DH + ks * 32 + kg * 8];
        }
        #pragma unroll
        for (int mt = 0; mt < 2; mt++)
            #pragma unroll
            for (int nt = 0; nt < 2; nt++)
                acc[mt][nt] = __builtin_amdgcn_mfma_f32_16x16x32_bf16(af[mt], bf[nt], acc[mt][nt], 0, 0, 0);
    }
    #pragma unroll
    for (int mt = 0; mt < 2; mt++) {
        int jbase = j0 + w * 32 + mt * 16 + kg * 4;
        float dv[4];
        #pragma unroll
        for (int r = 0; r < 4; r++) dv[r] = dinv[jbase + r];
        #pragma unroll
        for (int nt = 0; nt < 2; nt++) {
            int g = nt * 16 + fr;
            s16x4 pk;
            #pragma unroll
            for (int r = 0; r < 4; r++)
                pk[r] = (short)f2bf(acc[mt][nt][r] * dv[r]);
            *(s16x4*)(ZT + (size_t)(b * DOUT + g) * NN + jbase) = pk;
        }
    }
}

// ---------- gsm3: gemm2 64x128; Mi8 expanded ONCE per K-tile into proven-layout bf16 LDS ----------
// Per tile: stage (gload_lds: 1 A i8-chunk + 4 B) deep t+2, vmcnt(5).
// phB: expand t+1's AsmI -> Abf (pre-swizzled linear layout, identical to gload_lds convention);
//      lgkm+bar; frag-read t+1 (proven 0-conflict pattern); MFMA ks1; lgkm+bar.
__global__ __launch_bounds__(256) void gsm3(
    const char* __restrict__ Mi8, const unsigned short* __restrict__ Bt,
    float* __restrict__ out, const float* __restrict__ dinv,
    const float* __restrict__ bias)
{
    constexpr int KB = NN;         // bytes per Mi8 row
    constexpr int K = NN;          // bf16 elems per ZT row
    constexpr int NT = K / 64;     // 64
    __shared__ __align__(16) char AsmI[2][64 * 64];             // 2 x 4 KB (natural layout)
    __shared__ __align__(16) unsigned short Abf[2][64 * 64];    // 2 x 8 KB (pre-swizzled bf16)
    __shared__ __align__(16) unsigned short Bsm[2][128 * 64];   // 2 x 16 KB
    const int tid = threadIdx.x;
    const int lane = tid & 63;
    const int w = tid >> 6;
    const int wm = w >> 1, wn = w & 1;     // 2 x 2 waves; per-wave 32 x 64
    const int c0 = blockIdx.x * 128;
    const int j0 = blockIdx.y * 64;
    const int fr = lane & 15, kg = lane >> 4;

    // A staging: natural layout; thread -> (row=tid>>2, 16B chunk kc=tid&3), LDS linear tid*16
    const int srcA = (tid >> 2) * KB + (tid & 3) * 16;
    int srcB[4];
    #pragma unroll
    for (int q = 0; q < 4; q++) {
        int cid = q * 256 + tid;
        int row = cid >> 3, kc = cid & 7;
        srcB[q] = row * K + ((kc ^ (row & 7)) << 3);
    }
    const char* Abase = Mi8 + (size_t)j0 * KB;
    const unsigned short* Bbase = Bt + (size_t)c0 * K;

#define STAGE_T(buf, kt) do { \
    gload16(Abase + (kt) + srcA, &AsmI[buf][tid * 16]); \
    _Pragma("unroll") \
    for (int q = 0; q < 4; q++) \
        gload16(Bbase + (kt) + srcB[q], &Bsm[buf][(q * 256 + tid) * 8]); } while (0)

    // expand buffer Q: AsmI natural -> Abf pre-swizzled (linear pos (row,xc) holds chunk xc^(row&7))
#define EXPAND_A(Q) do { \
    int r0_ = tid >> 3, xc_ = tid & 7; \
    int c_ = xc_ ^ (r0_ & 7); \
    unsigned long long v0_ = *(const unsigned long long*)&AsmI[Q][r0_ * 64 + c_ * 8]; \
    unsigned long long v1_ = *(const unsigned long long*)&AsmI[Q][(r0_ + 32) * 64 + c_ * 8]; \
    s16x8 e0_, e1_; \
    _Pragma("unroll") \
    for (int e_ = 0; e_ < 8; e_++) { \
        e0_[e_] = (short)(-(short)((v0_ >> (8 * e_)) & 1ULL) & (short)0x3F80); \
        e1_[e_] = (short)(-(short)((v1_ >> (8 * e_)) & 1ULL) & (short)0x3F80); \
    } \
    *(s16x8*)((char*)Abf[Q] + tid * 16) = e0_; \
    *(s16x8*)((char*)Abf[Q] + 4096 + tid * 16) = e1_; \
} while (0)

    // prologue: stage T0, T1; land T0; expand T0; frag-read T0; drain
    STAGE_T(0, 0);
    STAGE_T(1, 64);
    asm volatile("s_waitcnt vmcnt(5)" ::: "memory");
    bar();
    EXPAND_A(0);
    asm volatile("s_waitcnt lgkmcnt(0)" ::: "memory");
    bar();

    const int x0 = (kg ^ (fr & 7)) << 4;
    const int x1 = ((4 + kg) ^ (fr & 7)) << 4;
    int aOff[2], bOff[4];
    #pragma unroll
    for (int m = 0; m < 2; m++) aOff[m] = (wm * 32 + m * 16 + fr) * 128;
    #pragma unroll
    for (int n = 0; n < 4; n++) bOff[n] = (wn * 64 + n * 16 + fr) * 128;

    s16x8 afc[2][2], bfc[2][4];
    #pragma unroll
    for (int ks = 0; ks < 2; ks++) {
        int xk = ks ? x1 : x0;
        #pragma unroll
        for (int m = 0; m < 2; m++) afc[ks][m] = *(const s16x8*)((const char*)Abf[0] + aOff[m] + xk);
        #pragma unroll
        for (int n = 0; n < 4; n++) bfc[ks][n] = *(const s16x8*)((const char*)Bsm[0] + bOff[n] + xk);
    }
    asm volatile("s_waitcnt lgkmcnt(0)" ::: "memory");
    bar();   // prologue frag reads drained before t=0 phA stages into buf0

    f32x4 acc[2][4] = {};

    for (int t = 0; t < NT; t++) {
        const int P = t & 1;
        const bool s1 = (t + 1) < NT, s2 = (t + 2) < NT;

        // ---- phA: stage t+2 -> P; MFMA ks0 (carried); counted vmcnt; bar
        if (s2) STAGE_T(P, (t + 2) * 64);
        __builtin_amdgcn_s_setprio(1);
        #pragma unroll
        for (int m = 0; m < 2; m++)
            #pragma unroll
            for (int n = 0; n < 4; n++)
                acc[m][n] = __builtin_amdgcn_mfma_f32_16x16x32_bf16(afc[0][m], bfc[0][n], acc[m][n], 0, 0, 0);
        __builtin_amdgcn_s_setprio(0);
        if (s2) asm volatile("s_waitcnt vmcnt(5)" ::: "memory");
        else    asm volatile("s_waitcnt vmcnt(0)" ::: "memory");
        bar();                                   // tile t+1 fully landed (all waves)

        // ---- phB: expand t+1; visible; frag-read t+1; MFMA ks1 (carried); drain
        if (s1) EXPAND_A(P ^ 1);
        asm volatile("s_waitcnt lgkmcnt(0)" ::: "memory");
        bar();                                   // expand writes visible to all lanes
        s16x8 afn[2][2], bfn[2][4];
        if (s1) {
            const char* Aq = (const char*)Abf[P ^ 1];
            const char* Bq = (const char*)Bsm[P ^ 1];
            #pragma unroll
            for (int ks = 0; ks < 2; ks++) {
                int xk = ks ? x1 : x0;
                #pragma unroll
                for (int m = 0; m < 2; m++) afn[ks][m] = *(const s16x8*)(Aq + aOff[m] + xk);
                #pragma unroll
                for (int n = 0; n < 4; n++) bfn[ks][n] = *(const s16x8*)(Bq + bOff[n] + xk);
            }
        }
        __builtin_amdgcn_s_setprio(1);
        #pragma unroll
        for (int m = 0; m < 2; m++)
            #pragma unroll
            for (int n = 0; n < 4; n++)
                acc[m][n] = __builtin_amdgcn_mfma_f32_16x16x32_bf16(afc[1][m], bfc[1][n], acc[m][n], 0, 0, 0);
        __builtin_amdgcn_s_setprio(0);
        asm volatile("s_waitcnt lgkmcnt(0)" ::: "memory");
        bar();                                   // frag reads drained before next overwrite
        if (s1) {
            #pragma unroll
            for (int ks = 0; ks < 2; ks++) {
                #pragma unroll
                for (int m = 0; m < 2; m++) afc[ks][m] = afn[ks][m];
                #pragma unroll
                for (int n = 0; n < 4; n++) bfc[ks][n] = bfn[ks][n];
            }
        }
    }
#undef STAGE_T
#undef EXPAND_A

    const float b_lo = bias[fr], b_hi = bias[fr + 16];
    #pragma unroll
    for (int m = 0; m < 2; m++) {
        int rbase = j0 + wm * 32 + m * 16 + kg * 4;
        float dv[4];
        #pragma unroll
        for (int r = 0; r < 4; r++) dv[r] = dinv[rbase + r];
        #pragma unroll
        for (int np = 0; np < 2; np++) {
            int bg = (c0 >> 5) + wn * 2 + np;       // batch index 0..31
            #pragma unroll
            for (int r = 0; r < 4; r++) {
                int row = rbase + r;
                float v0 = acc[m][np * 2][r]     * dv[r] + b_lo;   // g = fr
                float v1 = acc[m][np * 2 + 1][r] * dv[r] + b_hi;   // g = fr+16
                float mx = fmaxf(v0, v1);
                #pragma unroll
                for (int d = 8; d; d >>= 1) mx = fmaxf(mx, __shfl_xor(mx, d));
                float e0 = expf(v0 - mx), e1 = expf(v1 - mx);
                float s = e0 + e1;
                #pragma unroll
                for (int d = 8; d; d >>= 1) s += __shfl_xor(s, d);
                float inv = 1.0f / s;
                size_t ob = ((size_t)bg * NN + row) * DOUT;
                out[ob + fr]      = e0 * inv;
                out[ob + fr + 16] = e1 * inv;
            }
        }
    }
}

extern "C" void kernel_launch(void* const* d_in, const int* in_sizes, int n_in,
                              void* d_out, int out_size, void* d_ws, size_t ws_size,
                              hipStream_t stream)
{
    (void)in_sizes; (void)n_in; (void)out_size; (void)ws_size;
    const float* x    = (const float*)d_in[0];
    const float* emb1 = (const float*)d_in[1];
    const float* emb2 = (const float*)d_in[2];
    const float* l1w  = (const float*)d_in[3];
    const float* l1b  = (const float*)d_in[4];
    const float* l2w  = (const float*)d_in[5];
    const float* l2b  = (const float*)d_in[6];
    const float* g1w  = (const float*)d_in[7];
    const float* g1b  = (const float*)d_in[8];
    const float* g2w  = (const float*)d_in[9];
    const float* g2b  = (const float*)d_in[10];
    float* out = (float*)d_out;

    char* w = (char*)d_ws;
    int* deg = (int*)w;                       w += NN * 4;
    float* dinv = (float*)w;                  w += NN * 4;
    unsigned int* smY = (unsigned int*)w;     w += NN * 4;
    char* Mi8 = (char*)w;                     w += (size_t)NN * NN;
    unsigned short* YT = (unsigned short*)w;  w += (size_t)NN * NN * 2;
    char* Yq = (char*)w;                      w += (size_t)NN * NN;
    unsigned short* H  = (unsigned short*)w;  w += (size_t)NN * NN * 2;
    unsigned short* ZT = (unsigned short*)w;  w += (size_t)(NB * DOUT) * NN * 2;
    // Ux/Vx live in YT's region (dead until k_y1m, which runs after gemm_adj8)
    unsigned short* Ux = YT;
    unsigned short* Vx = YT + (size_t)NN * KADJ;

    k_embuv<<<256, 256, 0, stream>>>(emb1, emb2, l1w, l1b, l2w, l2b, Ux, Vx, deg);
    gemm_adj8<<<256, 512, 0, stream>>>(Vx, Ux, Mi8, deg);
    k_dinv<<<16, 256, 0, stream>>>(deg, dinv, smY);
    k_y1m<<<dim3(32, 32), 256, 0, stream>>>(x, g1w, dinv, YT, smY);
    k_quant<<<NN, 256, 0, stream>>>(YT, smY, Yq);
    gemm8qi<<<256, 512, 0, stream>>>(Mi8, Yq, H, dinv, smY, g1b);
    k_z2<<<dim3(32, 32), 256, 0, stream>>>(H, g2w, dinv, ZT);
    gsm3<<<dim3(8, 64), 256, 0, stream>>>(Mi8, ZT, out, dinv, g2b);
}

// Round 17
// 205.999 us; speedup vs baseline: 1.5617x; 1.0793x over previous
//
#include <hip/hip_runtime.h>

typedef float f32x4 __attribute__((ext_vector_type(4)));
typedef short s16x8 __attribute__((ext_vector_type(8)));
typedef short s16x4 __attribute__((ext_vector_type(4)));
typedef int i32x4 __attribute__((ext_vector_type(4)));

#define NN 4096
#define NB 32
#define DIN 64
#define DH 128
#define DOUT 32
#define DIM 40
#define KADJ 512   // 6 split-blocks x 80, zero-padded to 512

__device__ __forceinline__ unsigned short f2bf(float f) {
    unsigned int u = __float_as_uint(f);
    unsigned int r = (u + 0x7FFFu + ((u >> 16) & 1u)) >> 16;
    return (unsigned short)r;
}
__device__ __forceinline__ float bf2f(unsigned short h) {
    return __uint_as_float(((unsigned int)h) << 16);
}
__device__ __forceinline__ void gload16(const void* g, void* l) {
    __builtin_amdgcn_global_load_lds(
        (const __attribute__((address_space(1))) unsigned int*)g,
        (__attribute__((address_space(3))) unsigned int*)l, 16, 0, 0);
}
__device__ __forceinline__ void bar() {
    asm volatile("" ::: "memory");
    __builtin_amdgcn_s_barrier();
    asm volatile("" ::: "memory");
}

// ---------------- fused: n1/n2 = tanh(3*(emb @ W + b)) -> 3-way bf16 split operands ----------------
__global__ __launch_bounds__(256) void k_embuv(
    const float* __restrict__ emb1, const float* __restrict__ emb2,
    const float* __restrict__ l1w, const float* __restrict__ l1b,
    const float* __restrict__ l2w, const float* __restrict__ l2b,
    unsigned short* __restrict__ Ux, unsigned short* __restrict__ Vx,
    int* __restrict__ deg)
{
    __shared__ float e1s[16 * DIM], e2s[16 * DIM];
    __shared__ float w1s[DIM * DIM], w2s[DIM * DIM], b1s[DIM], b2s[DIM];
    __shared__ unsigned short Ul[16][KADJ], Vl[16][KADJ];
    const int tid = threadIdx.x;
    const int node0 = blockIdx.x * 16;
    if (tid < 16) deg[node0 + tid] = 0;
    for (int i = tid; i < 16 * DIM; i += 256) {
        e1s[i] = emb1[node0 * DIM + i];
        e2s[i] = emb2[node0 * DIM + i];
    }
    for (int i = tid; i < DIM * DIM; i += 256) { w1s[i] = l1w[i]; w2s[i] = l2w[i]; }
    if (tid < DIM) { b1s[tid] = l1b[tid]; b2s[tid] = l2b[tid]; }
    __syncthreads();
    const int r = tid >> 4;
    const int k0 = (tid & 15) * 5;
    const int PMAP[6] = {0, 0, 1, 1, 0, 2};
    const int QMAP[6] = {0, 1, 0, 1, 2, 0};
    #pragma unroll
    for (int e = 0; e < 5; e++) {
        int k = k0 + e;
        int kp = (k < DIM) ? k : k - DIM;
        float acc1 = b1s[kp], acc2 = b2s[kp];
        for (int kk = 0; kk < DIM; kk++) {
            acc1 += e1s[r * DIM + kk] * w1s[kk * DIM + kp];
            acc2 += e2s[r * DIM + kk] * w2s[kk * DIM + kp];
        }
        float n1v = tanhf(3.0f * acc1), n2v = tanhf(3.0f * acc2);
        float a = (k < DIM) ? n1v : -n2v;
        float b = (k < DIM) ? n2v : n1v;
        unsigned short u0 = f2bf(a); float ra = a - bf2f(u0);
        unsigned short u1 = f2bf(ra); ra -= bf2f(u1);
        unsigned short u2 = f2bf(ra);
        unsigned short v0 = f2bf(b); float rb = b - bf2f(v0);
        unsigned short v1 = f2bf(rb); rb -= bf2f(v1);
        unsigned short v2 = f2bf(rb);
        unsigned short uu[3] = {u0, u1, u2}, vv[3] = {v0, v1, v2};
        #pragma unroll
        for (int bq = 0; bq < 6; bq++) {
            Ul[r][80 * bq + k] = uu[PMAP[bq]];
            Vl[r][80 * bq + k] = vv[QMAP[bq]];
        }
    }
    {
        int c = tid & 15;
        Ul[r][480 + c * 2]     = 0; Vl[r][480 + c * 2]     = 0;
        Ul[r][480 + c * 2 + 1] = 0; Vl[r][480 + c * 2 + 1] = 0;
    }
    __syncthreads();
    #pragma unroll
    for (int q = 0; q < 4; q++) {
        int idx = q * 256 + tid;
        int rr = idx >> 6, c8 = idx & 63;
        size_t off = ((size_t)(node0 + rr)) * KADJ + c8 * 8;
        *(s16x8*)(Ux + off) = *(s16x8*)&Ul[rr][c8 * 8];
        *(s16x8*)(Vx + off) = *(s16x8*)&Vl[rr][c8 * 8];
    }
}

// ---------------- adjacency GEMM (bf16 operands), epilogue -> Mi8 (i8 0/1) + deg ----------------
__global__ __launch_bounds__(512, 2) void gemm_adj8(
    const unsigned short* __restrict__ A, const unsigned short* __restrict__ Bt,
    char* __restrict__ Mi8, int* __restrict__ deg)
{
    constexpr int K = KADJ;        // 512
    constexpr int NT = K / 64;     // 8 K-tiles
    __shared__ __align__(16) unsigned short As[2][256 * 64];
    __shared__ __align__(16) unsigned short Bs[2][256 * 64];

    const int tid = threadIdx.x;
    const int lane = tid & 63;
    const int w = tid >> 6;
    const int wm = w >> 2, wn = w & 3;
    const int fr = lane & 15, kg = lane >> 4;

    const int bid = blockIdx.x;
    const int swz = (bid & 7) * 32 + (bid >> 3);
    const int bx = swz & 15, by = swz >> 4;
    const int c0 = bx * 256, j0 = by * 256;

    const int cid0 = w * 128 + lane, cid1 = cid0 + 64;
    const int r0 = cid0 >> 3, k0c = cid0 & 7;
    const int r1 = cid1 >> 3, k1c = cid1 & 7;
    const int so0 = r0 * K + ((k0c ^ (r0 & 7)) << 3);
    const int so1 = r1 * K + ((k1c ^ (r1 & 7)) << 3);
    const int lb0 = (w * 2 + 0) * 512;
    const int lb1 = (w * 2 + 1) * 512;

    const unsigned short* Aj = A + (size_t)j0 * K;
    const unsigned short* Bc = Bt + (size_t)c0 * K;

#define STAGE_A(buf, half, kt) do { \
    const unsigned short* g_ = Aj + (size_t)((half) * 128) * K + (kt); \
    gload16(g_ + so0, &As[buf][(half) * 8192 + lb0]); \
    gload16(g_ + so1, &As[buf][(half) * 8192 + lb1]); } while (0)
#define STAGE_B(buf, half, kt) do { \
    const unsigned short* g_ = Bc + (size_t)((half) * 128) * K + (kt); \
    gload16(g_ + so0, &Bs[buf][(half) * 8192 + lb0]); \
    gload16(g_ + so1, &Bs[buf][(half) * 8192 + lb1]); } while (0)

    STAGE_A(0, 0, 0);  STAGE_A(0, 1, 0);
    STAGE_B(0, 0, 0);  STAGE_B(0, 1, 0);
    STAGE_A(1, 0, 64); STAGE_A(1, 1, 64);
    STAGE_B(1, 0, 64);
    asm volatile("s_waitcnt vmcnt(6)" ::: "memory");
    bar();

    const int x0 = ((kg) ^ (fr & 7)) << 4;
    const int x1 = ((4 + kg) ^ (fr & 7)) << 4;
    int aOff[8], bOff[4];
    #pragma unroll
    for (int m = 0; m < 8; m++) aOff[m] = (wm * 128 + m * 16 + fr) * 128;
    #pragma unroll
    for (int n = 0; n < 4; n++) bOff[n] = (wn * 64 + n * 16 + fr) * 128;

    s16x8 af0c[4], bf0c[4];
    #pragma unroll
    for (int m = 0; m < 4; m++) af0c[m] = *(const s16x8*)((const char*)As[0] + aOff[m] + x0);
    #pragma unroll
    for (int n = 0; n < 4; n++) bf0c[n] = *(const s16x8*)((const char*)Bs[0] + bOff[n] + x0);

    f32x4 acc[8][4] = {};

    for (int t = 0; t < NT; t++) {
        const int P = t & 1;
        const char* Ap = (const char*)As[P];
        const char* Bp = (const char*)Bs[P];
        const char* Aq = (const char*)As[P ^ 1];
        const char* Bq = (const char*)Bs[P ^ 1];
        const int kt1 = (t + 1) * 64, kt2 = (t + 2) * 64;
        const bool s1 = (t + 1) < NT, s2 = (t + 2) < NT;
        s16x8 af0h[4], af1l[4], af1h[4], bf1[4], af0n[4], bf0n[4];

        #pragma unroll
        for (int m = 0; m < 4; m++) af0h[m] = *(const s16x8*)(Ap + aOff[m + 4] + x0);
        #pragma unroll
        for (int m = 0; m < 4; m++) af1l[m] = *(const s16x8*)(Ap + aOff[m] + x1);
        if (s1) STAGE_B(P ^ 1, 1, kt1);
        __builtin_amdgcn_s_setprio(1);
        #pragma unroll
        for (int m = 0; m < 4; m++)
            #pragma unroll
            for (int n = 0; n < 4; n++)
                acc[m][n] = __builtin_amdgcn_mfma_f32_16x16x32_bf16(af0c[m], bf0c[n], acc[m][n], 0, 0, 0);
        __builtin_amdgcn_s_setprio(0);

        #pragma unroll
        for (int m = 0; m < 4; m++) af1h[m] = *(const s16x8*)(Ap + aOff[m + 4] + x1);
        #pragma unroll
        for (int n = 0; n < 4; n++) bf1[n] = *(const s16x8*)(Bp + bOff[n] + x1);
        __builtin_amdgcn_s_setprio(1);
        #pragma unroll
        for (int m = 4; m < 8; m++)
            #pragma unroll
            for (int n = 0; n < 4; n++)
                acc[m][n] = __builtin_amdgcn_mfma_f32_16x16x32_bf16(af0h[m - 4], bf0c[n], acc[m][n], 0, 0, 0);
        __builtin_amdgcn_s_setprio(0);
        asm volatile("s_waitcnt lgkmcnt(0)" ::: "memory");
        bar();

        __builtin_amdgcn_s_setprio(1);
        #pragma unroll
        for (int m = 0; m < 4; m++)
            #pragma unroll
            for (int n = 0; n < 4; n++)
                acc[m][n] = __builtin_amdgcn_mfma_f32_16x16x32_bf16(af1l[m], bf1[n], acc[m][n], 0, 0, 0);
        __builtin_amdgcn_s_setprio(0);
        if (s2) {
            STAGE_A(P, 0, kt2);
            STAGE_A(P, 1, kt2);
            STAGE_B(P, 0, kt2);
            asm volatile("s_waitcnt vmcnt(6)" ::: "memory");
        } else {
            asm volatile("s_waitcnt vmcnt(0)" ::: "memory");
        }
        bar();

        if (s1) {
            #pragma unroll
            for (int m = 0; m < 4; m++) af0n[m] = *(const s16x8*)(Aq + aOff[m] + x0);
            #pragma unroll
            for (int n = 0; n < 4; n++) bf0n[n] = *(const s16x8*)(Bq + bOff[n] + x0);
        }
        __builtin_amdgcn_s_setprio(1);
        #pragma unroll
        for (int m = 4; m < 8; m++)
            #pragma unroll
            for (int n = 0; n < 4; n++)
                acc[m][n] = __builtin_amdgcn_mfma_f32_16x16x32_bf16(af1h[m - 4], bf1[n], acc[m][n], 0, 0, 0);
        __builtin_amdgcn_s_setprio(0);
        if (s1) {
            #pragma unroll
            for (int m = 0; m < 4; m++) af0c[m] = af0n[m];
            #pragma unroll
            for (int n = 0; n < 4; n++) bf0c[n] = bf0n[n];
        }
    }
#undef STAGE_A
#undef STAGE_B

    #pragma unroll
    for (int m = 0; m < 8; m++) {
        int rbase = j0 + wm * 128 + m * 16 + kg * 4;
        #pragma unroll
        for (int r = 0; r < 4; r++) {
            int row = rbase + r;
            int cnt = 0;
            #pragma unroll
            for (int n = 0; n < 4; n++) {
                int col = c0 + wn * 64 + n * 16 + fr;
                bool bit = (acc[m][n][r] > 0.f) || (row == col);
                Mi8[(size_t)row * NN + col] = bit ? (char)1 : (char)0;
                cnt += bit ? 1 : 0;
            }
            cnt += __shfl_xor(cnt, 1);
            cnt += __shfl_xor(cnt, 2);
            cnt += __shfl_xor(cnt, 4);
            cnt += __shfl_xor(cnt, 8);
            if (fr == 0) atomicAdd(&deg[row], cnt);
        }
    }
}

__global__ void k_dinv(const int* __restrict__ deg, float* __restrict__ dinv,
                       unsigned int* __restrict__ smY, unsigned int* __restrict__ smZ) {
    int i = blockIdx.x * 256 + threadIdx.x;
    if (i < NN) { dinv[i] = 1.0f / sqrtf((float)deg[i]); smY[i] = 0u; }
    if (i < NB * DOUT) smZ[i] = 0u;
}

// ---------------- k_y1m: MFMA YT bf16 + per-row absmax for quantization ----------------
__global__ __launch_bounds__(256) void k_y1m(
    const float* __restrict__ x, const float* __restrict__ W1,
    const float* __restrict__ dinv, unsigned short* __restrict__ YT,
    unsigned int* __restrict__ smY)
{
    __shared__ __align__(16) unsigned short Xs[128 * 64];
    __shared__ __align__(16) unsigned short Ws[128 * 64];
    const int tid = threadIdx.x;
    const int i0 = blockIdx.x * 128, b = blockIdx.y;

    const float* xg = x + ((size_t)(b * NN + i0)) * DIN;
    #pragma unroll
    for (int q = 0; q < 8; q++) {
        int idx = q * 256 + tid;
        int row = idx >> 4, c4 = idx & 15;
        f32x4 v = *(const f32x4*)(xg + (size_t)row * DIN + c4 * 4);
        s16x4 pk;
        #pragma unroll
        for (int e = 0; e < 4; e++) pk[e] = (short)f2bf(v[e]);
        int chunk = (c4 >> 1) ^ (row & 7);
        *(s16x4*)((char*)Xs + row * 128 + (chunk << 4) + (c4 & 1) * 8) = pk;
    }
    #pragma unroll
    for (int q = 0; q < 8; q++) {
        int idx = q * 256 + tid;
        int k = idx >> 5, f4 = (idx & 31) * 4;
        f32x4 v = ((const f32x4*)W1)[idx];
        #pragma unroll
        for (int e = 0; e < 4; e++) {
            int f = f4 + e;
            int chunk = (k >> 3) ^ (f & 7);
            *(unsigned short*)((char*)Ws + f * 128 + (chunk << 4) + (k & 7) * 2) = f2bf(v[e]);
        }
    }
    __syncthreads();

    const int lane = tid & 63, w = tid >> 6;
    const int wm = w >> 1, wn = w & 1;
    const int fr = lane & 15, kg = lane >> 4;
    f32x4 acc[4][4] = {};
    #pragma unroll
    for (int ks = 0; ks < 2; ks++) {
        int kc = ks * 4 + kg;
        s16x8 af[4], bf[4];
        #pragma unroll
        for (int mt = 0; mt < 4; mt++) {
            int row = wm * 64 + mt * 16 + fr;
            af[mt] = *(const s16x8*)((const char*)Xs + row * 128 + ((kc ^ (row & 7)) << 4));
        }
        #pragma unroll
        for (int nt = 0; nt < 4; nt++) {
            int f = wn * 64 + nt * 16 + fr;
            bf[nt] = *(const s16x8*)((const char*)Ws + f * 128 + ((kc ^ (f & 7)) << 4));
        }
        #pragma unroll
        for (int mt = 0; mt < 4; mt++)
            #pragma unroll
            for (int nt = 0; nt < 4; nt++)
                acc[mt][nt] = __builtin_amdgcn_mfma_f32_16x16x32_bf16(af[mt], bf[nt], acc[mt][nt], 0, 0, 0);
    }
    float am[4] = {0.f, 0.f, 0.f, 0.f};
    #pragma unroll
    for (int mt = 0; mt < 4; mt++) {
        int ibase = i0 + wm * 64 + mt * 16 + kg * 4;
        float dv[4];
        #pragma unroll
        for (int r = 0; r < 4; r++) dv[r] = dinv[ibase + r];
        #pragma unroll
        for (int nt = 0; nt < 4; nt++) {
            int f = wn * 64 + nt * 16 + fr;
            s16x4 pk;
            #pragma unroll
            for (int r = 0; r < 4; r++) {
                float v = acc[mt][nt][r] * dv[r];
                am[nt] = fmaxf(am[nt], fabsf(v));
                pk[r] = (short)f2bf(v);
            }
            *(s16x4*)(YT + (size_t)(b * DH + f) * NN + ibase) = pk;
        }
    }
    #pragma unroll
    for (int nt = 0; nt < 4; nt++) {
        float mv = am[nt];
        mv = fmaxf(mv, __shfl_xor(mv, 16));
        mv = fmaxf(mv, __shfl_xor(mv, 32));
        if (kg == 0)
            atomicMax(&smY[b * DH + wn * 64 + nt * 16 + fr], __float_as_uint(mv));
    }
}

// ---------------- quantize bf16 rows -> i8 with per-row scale max/127 ----------------
__global__ __launch_bounds__(256) void k_quant(
    const unsigned short* __restrict__ src, const unsigned int* __restrict__ smax,
    char* __restrict__ dst)
{
    const int c = blockIdx.x;
    const float s = __uint_as_float(smax[c]);
    const float inv = s > 0.f ? 127.0f / s : 0.f;
    const unsigned short* row = src + (size_t)c * NN;
    char* orow = dst + (size_t)c * NN;
    const int base = threadIdx.x * 16;
    s16x8 a = *(const s16x8*)(row + base);
    s16x8 b = *(const s16x8*)(row + base + 8);
    union { char c8[16]; i32x4 v; } u;
    #pragma unroll
    for (int e = 0; e < 8; e++) {
        int q = (int)rintf(bf2f((unsigned short)a[e]) * inv);
        q = q > 127 ? 127 : (q < -127 ? -127 : q);
        u.c8[e] = (char)q;
    }
    #pragma unroll
    for (int e = 0; e < 8; e++) {
        int q = (int)rintf(bf2f((unsigned short)b[e]) * inv);
        q = q > 127 ? 127 : (q < -127 ? -127 : q);
        u.c8[8 + e] = (char)q;
    }
    *(i32x4*)(orow + base) = u.v;
}

// ---------------- quantize bf16 rows -> dual-plane i8 (hi + lo residual) ----------------
// z ~ (s/127)*(q_hi + q_lo/127); hi at dst[c], lo at dst[1024 + c].
__global__ __launch_bounds__(256) void k_quant2(
    const unsigned short* __restrict__ src, const unsigned int* __restrict__ smax,
    char* __restrict__ dst)
{
    const int c = blockIdx.x;
    const float s = __uint_as_float(smax[c]);
    const float inv = s > 0.f ? 127.0f / s : 0.f;
    const unsigned short* row = src + (size_t)c * NN;
    char* ohi = dst + (size_t)c * NN;
    char* olo = dst + (size_t)(NB * DOUT + c) * NN;
    const int base = threadIdx.x * 16;
    union { char c8[16]; i32x4 v; } uh, ul;
    #pragma unroll
    for (int e = 0; e < 16; e++) {
        float t = bf2f(row[base + e]) * inv;
        int qh = (int)rintf(t);
        qh = qh > 127 ? 127 : (qh < -127 ? -127 : qh);
        float r = (t - (float)qh) * 127.0f;
        int ql = (int)rintf(r);
        ql = ql > 127 ? 127 : (ql < -127 ? -127 : ql);
        uh.c8[e] = (char)qh;
        ul.c8[e] = (char)ql;
    }
    *(i32x4*)(ohi + base) = uh.v;
    *(i32x4*)(olo + base) = ul.v;
}

// ======== gemm1 (i8): 256x256, BK=128 i8, 8 waves; 8-phase quadrant schedule ========
__global__ __launch_bounds__(512, 2) void gemm8qi(
    const char* __restrict__ A, const char* __restrict__ Bt,
    unsigned short* __restrict__ H, const float* __restrict__ dinv,
    const unsigned int* __restrict__ smY, const float* __restrict__ bias)
{
    constexpr int KB = NN;         // 4096 bytes per row
    constexpr int NT = 32;         // K-tiles of 128 i8
    __shared__ __align__(16) char As[2][256 * 128];   // 32 KB each
    __shared__ __align__(16) char Bs[2][256 * 128];

    const int tid = threadIdx.x;
    const int lane = tid & 63;
    const int w = tid >> 6;
    const int wm = w >> 2, wn = w & 3;
    const int fr = lane & 15, kg = lane >> 4;

    const int bid = blockIdx.x;
    const int swz = (bid & 7) * 32 + (bid >> 3);
    const int bx = swz & 15, by = swz >> 4;
    const int c0 = bx * 256, j0 = by * 256;

    const char* Aj = A + (size_t)j0 * KB;
    const char* Bc = Bt + (size_t)c0 * KB;

    const int lr = tid >> 3, kcs = tid & 7;

#define STAGE_AQ(buf, q, kt) do { \
    int ra_ = (q) * 64 + lr; \
    int rb_ = ra_ + 128; \
    gload16(Aj + (size_t)ra_ * KB + (kt) + ((kcs ^ (ra_ & 7)) << 4), \
            &As[buf][(q) * 8192 + tid * 16]); \
    gload16(Aj + (size_t)rb_ * KB + (kt) + ((kcs ^ (rb_ & 7)) << 4), \
            &As[buf][(q) * 8192 + 16384 + tid * 16]); \
} while (0)
#define STAGE_BQ(buf, nh, kt) do { \
    int ca_ = tid, cb_ = tid + 512; \
    int r0_ = (ca_ >> 8) * 64 + (nh) * 32 + ((ca_ >> 3) & 31); \
    int r1_ = (cb_ >> 8) * 64 + (nh) * 32 + ((cb_ >> 3) & 31); \
    gload16(Bc + (size_t)r0_ * KB + (kt) + (((ca_ & 7) ^ (r0_ & 7)) << 4), \
            &Bs[buf][(ca_ >> 8) * 8192 + (nh) * 4096 + (ca_ & 255) * 16]); \
    gload16(Bc + (size_t)r1_ * KB + (kt) + (((cb_ & 7) ^ (r1_ & 7)) << 4), \
            &Bs[buf][(cb_ >> 8) * 8192 + (nh) * 4096 + (cb_ & 255) * 16]); \
} while (0)

    STAGE_AQ(0, 0, 0); STAGE_AQ(0, 1, 0);
    STAGE_BQ(0, 0, 0); STAGE_BQ(0, 1, 0);
    STAGE_BQ(1, 0, 128); STAGE_BQ(1, 1, 128);
    asm volatile("s_waitcnt vmcnt(4)" ::: "memory");
    bar();

    const int x0 = ((kg) ^ (fr & 7)) << 4;
    const int x1 = ((4 + kg) ^ (fr & 7)) << 4;
    int aOff[8], bOff[4];
    #pragma unroll
    for (int m = 0; m < 8; m++) aOff[m] = (wm * 128 + m * 16 + fr) * 128;
    #pragma unroll
    for (int n = 0; n < 4; n++) bOff[n] = (wn * 64 + n * 16 + fr) * 128;

    i32x4 acc[8][4] = {};
    const char* A0p = (const char*)As[0];
    const char* B0p = (const char*)Bs[0];
    const char* A1p = (const char*)As[1];
    const char* B1p = (const char*)Bs[1];

#define MFMA_Q(MB, NB_, AF0, AF1, BK0, BK1) do { \
    __builtin_amdgcn_s_setprio(1); \
    _Pragma("unroll") \
    for (int m = 0; m < 4; m++) { \
        _Pragma("unroll") \
        for (int n = 0; n < 2; n++) { \
            acc[(MB) + m][(NB_) + n] = __builtin_amdgcn_mfma_i32_16x16x64_i8( \
                AF0[m], BK0[n], acc[(MB) + m][(NB_) + n], 0, 0, 0); \
            acc[(MB) + m][(NB_) + n] = __builtin_amdgcn_mfma_i32_16x16x64_i8( \
                AF1[m], BK1[n], acc[(MB) + m][(NB_) + n], 0, 0, 0); \
        } \
    } \
    __builtin_amdgcn_s_setprio(0); \
} while (0)

    i32x4 af0[4], af1[4], b0k0[2], b0k1[2], b1k0[2], b1k1[2];

    for (int T = 0; T < NT; T += 2) {
        const bool s2 = (T + 2) < NT, s3 = (T + 3) < NT;
        const int kt1 = (T + 1) * 128, kt2 = (T + 2) * 128, kt3 = (T + 3) * 128;

        #pragma unroll
        for (int m = 0; m < 4; m++) { af0[m] = *(const i32x4*)(A0p + aOff[m] + x0);
                                      af1[m] = *(const i32x4*)(A0p + aOff[m] + x1); }
        #pragma unroll
        for (int n = 0; n < 2; n++) { b0k0[n] = *(const i32x4*)(B0p + bOff[n] + x0);
                                      b0k1[n] = *(const i32x4*)(B0p + bOff[n] + x1); }
        STAGE_AQ(1, 0, kt1);
        bar();
        MFMA_Q(0, 0, af0, af1, b0k0, b0k1);
        bar();

        #pragma unroll
        for (int n = 0; n < 2; n++) { b1k0[n] = *(const i32x4*)(B0p + bOff[n + 2] + x0);
                                      b1k1[n] = *(const i32x4*)(B0p + bOff[n + 2] + x1); }
        STAGE_AQ(1, 1, kt1);
        bar();
        MFMA_Q(0, 2, af0, af1, b1k0, b1k1);
        bar();

        #pragma unroll
        for (int m = 0; m < 4; m++) { af0[m] = *(const i32x4*)(A0p + aOff[m + 4] + x0);
                                      af1[m] = *(const i32x4*)(A0p + aOff[m + 4] + x1); }
        if (s2) STAGE_BQ(0, 0, kt2);
        bar();
        MFMA_Q(4, 0, af0, af1, b0k0, b0k1);
        bar();

        if (s2) { STAGE_BQ(0, 1, kt2);
                  asm volatile("s_waitcnt vmcnt(4)" ::: "memory"); }
        else    { asm volatile("s_waitcnt vmcnt(0)" ::: "memory"); }
        bar();
        MFMA_Q(4, 2, af0, af1, b1k0, b1k1);
        bar();

        #pragma unroll
        for (int m = 0; m < 4; m++) { af0[m] = *(const i32x4*)(A1p + aOff[m] + x0);
                                      af1[m] = *(const i32x4*)(A1p + aOff[m] + x1); }
        #pragma unroll
        for (int n = 0; n < 2; n++) { b0k0[n] = *(const i32x4*)(B1p + bOff[n] + x0);
                                      b0k1[n] = *(const i32x4*)(B1p + bOff[n] + x1); }
        if (s2) STAGE_AQ(0, 0, kt2);
        bar();
        MFMA_Q(0, 0, af0, af1, b0k0, b0k1);
        bar();

        #pragma unroll
        for (int n = 0; n < 2; n++) { b1k0[n] = *(const i32x4*)(B1p + bOff[n + 2] + x0);
                                      b1k1[n] = *(const i32x4*)(B1p + bOff[n + 2] + x1); }
        if (s2) STAGE_AQ(0, 1, kt2);
        bar();
        MFMA_Q(0, 2, af0, af1, b1k0, b1k1);
        bar();

        #pragma unroll
        for (int m = 0; m < 4; m++) { af0[m] = *(const i32x4*)(A1p + aOff[m + 4] + x0);
                                      af1[m] = *(const i32x4*)(A1p + aOff[m + 4] + x1); }
        if (s3) STAGE_BQ(1, 0, kt3);
        bar();
        MFMA_Q(4, 0, af0, af1, b0k0, b0k1);
        bar();

        if (s3) { STAGE_BQ(1, 1, kt3);
                  asm volatile("s_waitcnt vmcnt(4)" ::: "memory"); }
        else    { asm volatile("s_waitcnt vmcnt(0)" ::: "memory"); }
        bar();
        MFMA_Q(4, 2, af0, af1, b1k0, b1k1);
        bar();
    }
#undef MFMA_Q
#undef STAGE_AQ
#undef STAGE_BQ

    #pragma unroll
    for (int m = 0; m < 8; m++) {
        int rbase = j0 + wm * 128 + m * 16 + kg * 4;
        float dv[4];
        #pragma unroll
        for (int r = 0; r < 4; r++) dv[r] = dinv[rbase + r];
        #pragma unroll
        for (int n = 0; n < 4; n++) {
            int gcol = c0 + wn * 64 + n * 16 + fr;
            float bb = bias[gcol & (DH - 1)];
            float sc = __uint_as_float(smY[gcol]) * (1.0f / 127.0f);
            #pragma unroll
            for (int r = 0; r < 4; r++) {
                float v = (float)acc[m][n][r] * sc * dv[r] + bb;
                v = v > 0.f ? v : 0.f;
                H[(size_t)(rbase + r) * NN + gcol] = f2bf(v);
            }
        }
    }
}

// ---------- k_z2: MFMA ZT bf16 + per-row absmax ----------
__global__ __launch_bounds__(256) void k_z2(
    const unsigned short* __restrict__ H, const float* __restrict__ W2,
    const float* __restrict__ dinv, unsigned short* __restrict__ ZT,
    unsigned int* __restrict__ smZ)
{
    __shared__ __align__(16) unsigned short Hs[128 * DH];
    __shared__ __align__(16) unsigned short W2Ts[DOUT * DH];
    const int tid = threadIdx.x;
    const int j0 = blockIdx.x * 128, b = blockIdx.y;
    const unsigned short* Hb = H + (size_t)j0 * NN + b * DH;

    #pragma unroll
    for (int q = 0; q < 8; q++) {
        int cid = q * 256 + tid;
        int row = cid >> 4, kc = cid & 15;
        gload16(Hb + (size_t)row * NN + kc * 8, &Hs[cid * 8]);
    }
    #pragma unroll
    for (int q = 0; q < 16; q++) {
        int idx = q * 256 + tid;
        int f = idx >> 5, g = idx & 31;
        W2Ts[g * DH + f] = f2bf(W2[f * DOUT + g]);
    }
    __syncthreads();

    const int lane = tid & 63, w = tid >> 6;
    const int fr = lane & 15, kg = lane >> 4;
    f32x4 acc[2][2] = {};
    #pragma unroll
    for (int ks = 0; ks < 4; ks++) {
        s16x8 af[2], bf[2];
        #pragma unroll
        for (int mt = 0; mt < 2; mt++) {
            int row = w * 32 + mt * 16 + fr;
            af[mt] = *(const s16x8*)&Hs[row * DH + ks * 32 + kg * 8];
        }
        #pragma unroll
        for (int nt = 0; nt < 2; nt++) {
            int g = nt * 16 + fr;
            bf[nt] = *(const s16x8*)&W2Ts[g * DH + ks * 32 + kg * 8];
        }
        #pragma unroll
        for (int mt = 0; mt < 2; mt++)
            #pragma unroll
            for (int nt = 0; nt < 2; nt++)
                acc[mt][nt] = __builtin_amdgcn_mfma_f32_16x16x32_bf16(af[mt], bf[nt], acc[mt][nt], 0, 0, 0);
    }
    float am[2] = {0.f, 0.f};
    #pragma unroll
    for (int mt = 0; mt < 2; mt++) {
        int jbase = j0 + w * 32 + mt * 16 + kg * 4;
        float dv[4];
        #pragma unroll
        for (int r = 0; r < 4; r++) dv[r] = dinv[jbase + r];
        #pragma unroll
        for (int nt = 0; nt < 2; nt++) {
            int g = nt * 16 + fr;
            s16x4 pk;
            #pragma unroll
            for (int r = 0; r < 4; r++) {
                float v = acc[mt][nt][r] * dv[r];
                am[nt] = fmaxf(am[nt], fabsf(v));
                pk[r] = (short)f2bf(v);
            }
            *(s16x4*)(ZT + (size_t)(b * DOUT + g) * NN + jbase) = pk;
        }
    }
    #pragma unroll
    for (int nt = 0; nt < 2; nt++) {
        float mv = am[nt];
        mv = fmaxf(mv, __shfl_xor(mv, 16));
        mv = fmaxf(mv, __shfl_xor(mv, 32));
        if (kg == 0)
            atomicMax(&smZ[b * DOUT + nt * 16 + fr], __float_as_uint(mv));
    }
}

// ---------- gsm2d: gemm2 64x128 dual-plane i8, BK=128 (NT=32), fused softmax ----------
// B planes: hi rows at Zq[c], lo rows at Zq[1024 + c]. 10 loads/tile -> vmcnt(10).
// logit = dinv_j * (s_c/127) * (acc_hi + acc_lo/127) + bias.
__global__ __launch_bounds__(256) void gsm2d(
    const char* __restrict__ Mi8, const char* __restrict__ Zq,
    float* __restrict__ out, const float* __restrict__ dinv,
    const unsigned int* __restrict__ smZ, const float* __restrict__ bias)
{
    constexpr int KB = NN;         // bytes per row
    constexpr int NT = 32;         // K-tiles of 128 bytes
    __shared__ __align__(16) char Asm[2][64 * 128];    // 2 x 8 KB
    __shared__ __align__(16) char Bhi[2][128 * 128];   // 2 x 16 KB
    __shared__ __align__(16) char Blo[2][128 * 128];   // 2 x 16 KB  (total 80 KB)
    const int tid = threadIdx.x;
    const int lane = tid & 63;
    const int w = tid >> 6;
    const int wm = w >> 1, wn = w & 1;     // 2 x 2 waves; per-wave 32 x 64
    const int c0 = blockIdx.x * 128;
    const int j0 = blockIdx.y * 64;
    const int fr = lane & 15, kg = lane >> 4;

    int srcA[2], srcB[4];
    #pragma unroll
    for (int q = 0; q < 2; q++) {
        int cid = q * 256 + tid;
        int row = cid >> 3, kc = cid & 7;
        srcA[q] = row * KB + ((kc ^ (row & 7)) << 4);
    }
    #pragma unroll
    for (int q = 0; q < 4; q++) {
        int cid = q * 256 + tid;
        int row = cid >> 3, kc = cid & 7;
        srcB[q] = row * KB + ((kc ^ (row & 7)) << 4);
    }
    const char* Abase = Mi8 + (size_t)j0 * KB;
    const char* Bh = Zq + (size_t)c0 * KB;
    const char* Bl = Zq + (size_t)(NB * DOUT + c0) * KB;

#define STAGE_T(buf, kt) do { \
    _Pragma("unroll") \
    for (int q = 0; q < 2; q++) \
        gload16(Abase + (kt) + srcA[q], &Asm[buf][(q * 256 + tid) * 16]); \
    _Pragma("unroll") \
    for (int q = 0; q < 4; q++) \
        gload16(Bh + (kt) + srcB[q], &Bhi[buf][(q * 256 + tid) * 16]); \
    _Pragma("unroll") \
    for (int q = 0; q < 4; q++) \
        gload16(Bl + (kt) + srcB[q], &Blo[buf][(q * 256 + tid) * 16]); } while (0)

    STAGE_T(0, 0);
    STAGE_T(1, 128);
    asm volatile("s_waitcnt vmcnt(10)" ::: "memory");
    bar();

    const int x0 = (kg ^ (fr & 7)) << 4;
    const int x1 = ((4 + kg) ^ (fr & 7)) << 4;
    int aOff[2], bOff[4];
    #pragma unroll
    for (int m = 0; m < 2; m++) aOff[m] = (wm * 32 + m * 16 + fr) * 128;
    #pragma unroll
    for (int n = 0; n < 4; n++) bOff[n] = (wn * 64 + n * 16 + fr) * 128;

    i32x4 afc[2][2], bhc[2][4], blc[2][4];
    #pragma unroll
    for (int ks = 0; ks < 2; ks++) {
        int xk = ks ? x1 : x0;
        #pragma unroll
        for (int m = 0; m < 2; m++) afc[ks][m] = *(const i32x4*)((const char*)Asm[0] + aOff[m] + xk);
        #pragma unroll
        for (int n = 0; n < 4; n++) {
            bhc[ks][n] = *(const i32x4*)((const char*)Bhi[0] + bOff[n] + xk);
            blc[ks][n] = *(const i32x4*)((const char*)Blo[0] + bOff[n] + xk);
        }
    }
    asm volatile("s_waitcnt lgkmcnt(0)" ::: "memory");
    bar();   // prologue reads of buf0 drained before t=0 phA overwrites buf0

    i32x4 ah[2][4] = {};   // hi accumulators
    i32x4 al[2][4] = {};   // lo accumulators

    for (int t = 0; t < NT; t++) {
        const int P = t & 1;
        const bool s1 = (t + 1) < NT, s2 = (t + 2) < NT;

        // ---- phA: stage t+2 -> P; MFMA ks0 (hi+lo, carried); counted vmcnt; bar
        if (s2) STAGE_T(P, (t + 2) * 128);
        __builtin_amdgcn_s_setprio(1);
        #pragma unroll
        for (int m = 0; m < 2; m++)
            #pragma unroll
            for (int n = 0; n < 4; n++) {
                ah[m][n] = __builtin_amdgcn_mfma_i32_16x16x64_i8(afc[0][m], bhc[0][n], ah[m][n], 0, 0, 0);
                al[m][n] = __builtin_amdgcn_mfma_i32_16x16x64_i8(afc[0][m], blc[0][n], al[m][n], 0, 0, 0);
            }
        __builtin_amdgcn_s_setprio(0);
        if (s2) asm volatile("s_waitcnt vmcnt(10)" ::: "memory");
        else    asm volatile("s_waitcnt vmcnt(0)" ::: "memory");
        bar();

        // ---- phB: read t+1 frags from P^1; MFMA ks1 (hi+lo, carried); drain; swap
        i32x4 afn[2][2], bhn[2][4], bln[2][4];
        if (s1) {
            const char* Aq = (const char*)Asm[P ^ 1];
            const char* Bhq = (const char*)Bhi[P ^ 1];
            const char* Blq = (const char*)Blo[P ^ 1];
            #pragma unroll
            for (int ks = 0; ks < 2; ks++) {
                int xk = ks ? x1 : x0;
                #pragma unroll
                for (int m = 0; m < 2; m++) afn[ks][m] = *(const i32x4*)(Aq + aOff[m] + xk);
                #pragma unroll
                for (int n = 0; n < 4; n++) {
                    bhn[ks][n] = *(const i32x4*)(Bhq + bOff[n] + xk);
                    bln[ks][n] = *(const i32x4*)(Blq + bOff[n] + xk);
                }
            }
        }
        __builtin_amdgcn_s_setprio(1);
        #pragma unroll
        for (int m = 0; m < 2; m++)
            #pragma unroll
            for (int n = 0; n < 4; n++) {
                ah[m][n] = __builtin_amdgcn_mfma_i32_16x16x64_i8(afc[1][m], bhc[1][n], ah[m][n], 0, 0, 0);
                al[m][n] = __builtin_amdgcn_mfma_i32_16x16x64_i8(afc[1][m], blc[1][n], al[m][n], 0, 0, 0);
            }
        __builtin_amdgcn_s_setprio(0);
        asm volatile("s_waitcnt lgkmcnt(0)" ::: "memory");
        bar();
        if (s1) {
            #pragma unroll
            for (int ks = 0; ks < 2; ks++) {
                #pragma unroll
                for (int m = 0; m < 2; m++) afc[ks][m] = afn[ks][m];
                #pragma unroll
                for (int n = 0; n < 4; n++) { bhc[ks][n] = bhn[ks][n]; blc[ks][n] = bln[ks][n]; }
            }
        }
    }
#undef STAGE_T

    const float b_lo = bias[fr], b_hi = bias[fr + 16];
    #pragma unroll
    for (int m = 0; m < 2; m++) {
        int rbase = j0 + wm * 32 + m * 16 + kg * 4;
        float dv[4];
        #pragma unroll
        for (int r = 0; r < 4; r++) dv[r] = dinv[rbase + r];
        #pragma unroll
        for (int np = 0; np < 2; np++) {
            int bg = (c0 >> 5) + wn * 2 + np;       // batch index 0..31
            float sc0 = __uint_as_float(smZ[c0 + wn * 64 + np * 32 + fr])      * (1.0f / 127.0f);
            float sc1 = __uint_as_float(smZ[c0 + wn * 64 + np * 32 + fr + 16]) * (1.0f / 127.0f);
            #pragma unroll
            for (int r = 0; r < 4; r++) {
                int row = rbase + r;
                float v0 = ((float)ah[m][np * 2][r]     + (float)al[m][np * 2][r]     * (1.0f / 127.0f)) * sc0 * dv[r] + b_lo;
                float v1 = ((float)ah[m][np * 2 + 1][r] + (float)al[m][np * 2 + 1][r] * (1.0f / 127.0f)) * sc1 * dv[r] + b_hi;
                float mx = fmaxf(v0, v1);
                #pragma unroll
                for (int d = 8; d; d >>= 1) mx = fmaxf(mx, __shfl_xor(mx, d));
                float e0 = expf(v0 - mx), e1 = expf(v1 - mx);
                float s = e0 + e1;
                #pragma unroll
                for (int d = 8; d; d >>= 1) s += __shfl_xor(s, d);
                float inv = 1.0f / s;
                size_t ob = ((size_t)bg * NN + row) * DOUT;
                out[ob + fr]      = e0 * inv;
                out[ob + fr + 16] = e1 * inv;
            }
        }
    }
}

extern "C" void kernel_launch(void* const* d_in, const int* in_sizes, int n_in,
                              void* d_out, int out_size, void* d_ws, size_t ws_size,
                              hipStream_t stream)
{
    (void)in_sizes; (void)n_in; (void)out_size; (void)ws_size;
    const float* x    = (const float*)d_in[0];
    const float* emb1 = (const float*)d_in[1];
    const float* emb2 = (const float*)d_in[2];
    const float* l1w  = (const float*)d_in[3];
    const float* l1b  = (const float*)d_in[4];
    const float* l2w  = (const float*)d_in[5];
    const float* l2b  = (const float*)d_in[6];
    const float* g1w  = (const float*)d_in[7];
    const float* g1b  = (const float*)d_in[8];
    const float* g2w  = (const float*)d_in[9];
    const float* g2b  = (const float*)d_in[10];
    float* out = (float*)d_out;

    char* w = (char*)d_ws;
    int* deg = (int*)w;                       w += NN * 4;
    float* dinv = (float*)w;                  w += NN * 4;
    unsigned int* smY = (unsigned int*)w;     w += NN * 4;
    unsigned int* smZ = (unsigned int*)w;     w += NB * DOUT * 4;
    char* Mi8 = (char*)w;                     w += (size_t)NN * NN;
    unsigned short* YT = (unsigned short*)w;  w += (size_t)NN * NN * 2;
    char* Yq = (char*)w;                      w += (size_t)NN * NN;
    unsigned short* H  = (unsigned short*)w;  w += (size_t)NN * NN * 2;
    unsigned short* ZT = (unsigned short*)w;  w += (size_t)(NB * DOUT) * NN * 2;
    // Ux/Vx live in YT's region (dead until k_y1m); ZTq2 (8MB) lives in Yq's
    // region (Yq dead after gemm8qi; k_quant2/gsm2d run after it).
    unsigned short* Ux = YT;
    unsigned short* Vx = YT + (size_t)NN * KADJ;
    char* ZTq2 = Yq;   // 2 x 1024 x 4096 i8 = 8MB <= 16MB

    k_embuv<<<256, 256, 0, stream>>>(emb1, emb2, l1w, l1b, l2w, l2b, Ux, Vx, deg);
    gemm_adj8<<<256, 512, 0, stream>>>(Vx, Ux, Mi8, deg);
    k_dinv<<<16, 256, 0, stream>>>(deg, dinv, smY, smZ);
    k_y1m<<<dim3(32, 32), 256, 0, stream>>>(x, g1w, dinv, YT, smY);
    k_quant<<<NN, 256, 0, stream>>>(YT, smY, Yq);
    gemm8qi<<<256, 512, 0, stream>>>(Mi8, Yq, H, dinv, smY, g1b);
    k_z2<<<dim3(32, 32), 256, 0, stream>>>(H, g2w, dinv, ZT, smZ);
    k_quant2<<<NB * DOUT, 256, 0, stream>>>(ZT, smZ, ZTq2);
    gsm2d<<<dim3(8, 64), 256, 0, stream>>>(Mi8, ZTq2, out, dinv, smZ, g2b);
}

// Round 18
// 200.812 us; speedup vs baseline: 1.6020x; 1.0258x over previous
//
#include <hip/hip_runtime.h>

typedef float f32x4 __attribute__((ext_vector_type(4)));
typedef short s16x8 __attribute__((ext_vector_type(8)));
typedef short s16x4 __attribute__((ext_vector_type(4)));
typedef int i32x4 __attribute__((ext_vector_type(4)));

#define NN 4096
#define NB 32
#define DIN 64
#define DH 128
#define DOUT 32
#define DIM 40
#define KADJ 320   // 4 split-blocks x 80 = exact (u0+u1)(v0+v1); 320 % 64 == 0

__device__ __forceinline__ unsigned short f2bf(float f) {
    unsigned int u = __float_as_uint(f);
    unsigned int r = (u + 0x7FFFu + ((u >> 16) & 1u)) >> 16;
    return (unsigned short)r;
}
__device__ __forceinline__ float bf2f(unsigned short h) {
    return __uint_as_float(((unsigned int)h) << 16);
}
__device__ __forceinline__ void gload16(const void* g, void* l) {
    __builtin_amdgcn_global_load_lds(
        (const __attribute__((address_space(1))) unsigned int*)g,
        (__attribute__((address_space(3))) unsigned int*)l, 16, 0, 0);
}
__device__ __forceinline__ void bar() {
    asm volatile("" ::: "memory");
    __builtin_amdgcn_s_barrier();
    asm volatile("" ::: "memory");
}

// ---------------- fused: n1/n2 = tanh(3*(emb @ W + b)) -> 2-term bf16 split operands ----------------
// u = (n1, -n2), v = (n2, n1) dim 80; u ~ u0+u1 (bf16 + bf16 residual), v likewise.
// K-blocks {00,01,10,11}: sum = (u0+u1)·(v0+v1) exactly; dropped u2/v2 level ~ 2^-16 rel.
__global__ __launch_bounds__(256) void k_embuv(
    const float* __restrict__ emb1, const float* __restrict__ emb2,
    const float* __restrict__ l1w, const float* __restrict__ l1b,
    const float* __restrict__ l2w, const float* __restrict__ l2b,
    unsigned short* __restrict__ Ux, unsigned short* __restrict__ Vx,
    int* __restrict__ deg)
{
    __shared__ float e1s[16 * DIM], e2s[16 * DIM];
    __shared__ float w1s[DIM * DIM], w2s[DIM * DIM], b1s[DIM], b2s[DIM];
    __shared__ unsigned short Ul[16][KADJ], Vl[16][KADJ];
    const int tid = threadIdx.x;
    const int node0 = blockIdx.x * 16;
    if (tid < 16) deg[node0 + tid] = 0;
    for (int i = tid; i < 16 * DIM; i += 256) {
        e1s[i] = emb1[node0 * DIM + i];
        e2s[i] = emb2[node0 * DIM + i];
    }
    for (int i = tid; i < DIM * DIM; i += 256) { w1s[i] = l1w[i]; w2s[i] = l2w[i]; }
    if (tid < DIM) { b1s[tid] = l1b[tid]; b2s[tid] = l2b[tid]; }
    __syncthreads();
    const int r = tid >> 4;
    const int k0 = (tid & 15) * 5;
    const int PMAP[4] = {0, 0, 1, 1};
    const int QMAP[4] = {0, 1, 0, 1};
    #pragma unroll
    for (int e = 0; e < 5; e++) {
        int k = k0 + e;
        int kp = (k < DIM) ? k : k - DIM;
        float acc1 = b1s[kp], acc2 = b2s[kp];
        for (int kk = 0; kk < DIM; kk++) {
            acc1 += e1s[r * DIM + kk] * w1s[kk * DIM + kp];
            acc2 += e2s[r * DIM + kk] * w2s[kk * DIM + kp];
        }
        float n1v = tanhf(3.0f * acc1), n2v = tanhf(3.0f * acc2);
        float a = (k < DIM) ? n1v : -n2v;
        float b = (k < DIM) ? n2v : n1v;
        unsigned short u0 = f2bf(a); float ra = a - bf2f(u0);
        unsigned short u1 = f2bf(ra);
        unsigned short v0 = f2bf(b); float rb = b - bf2f(v0);
        unsigned short v1 = f2bf(rb);
        unsigned short uu[2] = {u0, u1}, vv[2] = {v0, v1};
        #pragma unroll
        for (int bq = 0; bq < 4; bq++) {
            Ul[r][80 * bq + k] = uu[PMAP[bq]];
            Vl[r][80 * bq + k] = vv[QMAP[bq]];
        }
    }
    __syncthreads();
    for (int idx = tid; idx < 16 * KADJ / 8; idx += 256) {   // 640 chunks
        int rr = idx / 40, c8 = idx - rr * 40;
        size_t off = ((size_t)(node0 + rr)) * KADJ + c8 * 8;
        *(s16x8*)(Ux + off) = *(s16x8*)&Ul[rr][c8 * 8];
        *(s16x8*)(Vx + off) = *(s16x8*)&Vl[rr][c8 * 8];
    }
}

// ---------------- adjacency GEMM (bf16 operands), K=320, epilogue -> Mi8 + deg ----------------
__global__ __launch_bounds__(512, 2) void gemm_adj8(
    const unsigned short* __restrict__ A, const unsigned short* __restrict__ Bt,
    char* __restrict__ Mi8, int* __restrict__ deg)
{
    constexpr int K = KADJ;        // 320
    constexpr int NT = K / 64;     // 5 K-tiles
    __shared__ __align__(16) unsigned short As[2][256 * 64];
    __shared__ __align__(16) unsigned short Bs[2][256 * 64];

    const int tid = threadIdx.x;
    const int lane = tid & 63;
    const int w = tid >> 6;
    const int wm = w >> 2, wn = w & 3;
    const int fr = lane & 15, kg = lane >> 4;

    const int bid = blockIdx.x;
    const int swz = (bid & 7) * 32 + (bid >> 3);
    const int bx = swz & 15, by = swz >> 4;
    const int c0 = bx * 256, j0 = by * 256;

    const int cid0 = w * 128 + lane, cid1 = cid0 + 64;
    const int r0 = cid0 >> 3, k0c = cid0 & 7;
    const int r1 = cid1 >> 3, k1c = cid1 & 7;
    const int so0 = r0 * K + ((k0c ^ (r0 & 7)) << 3);
    const int so1 = r1 * K + ((k1c ^ (r1 & 7)) << 3);
    const int lb0 = (w * 2 + 0) * 512;
    const int lb1 = (w * 2 + 1) * 512;

    const unsigned short* Aj = A + (size_t)j0 * K;
    const unsigned short* Bc = Bt + (size_t)c0 * K;

#define STAGE_A(buf, half, kt) do { \
    const unsigned short* g_ = Aj + (size_t)((half) * 128) * K + (kt); \
    gload16(g_ + so0, &As[buf][(half) * 8192 + lb0]); \
    gload16(g_ + so1, &As[buf][(half) * 8192 + lb1]); } while (0)
#define STAGE_B(buf, half, kt) do { \
    const unsigned short* g_ = Bc + (size_t)((half) * 128) * K + (kt); \
    gload16(g_ + so0, &Bs[buf][(half) * 8192 + lb0]); \
    gload16(g_ + so1, &Bs[buf][(half) * 8192 + lb1]); } while (0)

    STAGE_A(0, 0, 0);  STAGE_A(0, 1, 0);
    STAGE_B(0, 0, 0);  STAGE_B(0, 1, 0);
    STAGE_A(1, 0, 64); STAGE_A(1, 1, 64);
    STAGE_B(1, 0, 64);
    asm volatile("s_waitcnt vmcnt(6)" ::: "memory");
    bar();

    const int x0 = ((kg) ^ (fr & 7)) << 4;
    const int x1 = ((4 + kg) ^ (fr & 7)) << 4;
    int aOff[8], bOff[4];
    #pragma unroll
    for (int m = 0; m < 8; m++) aOff[m] = (wm * 128 + m * 16 + fr) * 128;
    #pragma unroll
    for (int n = 0; n < 4; n++) bOff[n] = (wn * 64 + n * 16 + fr) * 128;

    s16x8 af0c[4], bf0c[4];
    #pragma unroll
    for (int m = 0; m < 4; m++) af0c[m] = *(const s16x8*)((const char*)As[0] + aOff[m] + x0);
    #pragma unroll
    for (int n = 0; n < 4; n++) bf0c[n] = *(const s16x8*)((const char*)Bs[0] + bOff[n] + x0);

    f32x4 acc[8][4] = {};

    for (int t = 0; t < NT; t++) {
        const int P = t & 1;
        const char* Ap = (const char*)As[P];
        const char* Bp = (const char*)Bs[P];
        const char* Aq = (const char*)As[P ^ 1];
        const char* Bq = (const char*)Bs[P ^ 1];
        const int kt1 = (t + 1) * 64, kt2 = (t + 2) * 64;
        const bool s1 = (t + 1) < NT, s2 = (t + 2) < NT;
        s16x8 af0h[4], af1l[4], af1h[4], bf1[4], af0n[4], bf0n[4];

        #pragma unroll
        for (int m = 0; m < 4; m++) af0h[m] = *(const s16x8*)(Ap + aOff[m + 4] + x0);
        #pragma unroll
        for (int m = 0; m < 4; m++) af1l[m] = *(const s16x8*)(Ap + aOff[m] + x1);
        if (s1) STAGE_B(P ^ 1, 1, kt1);
        __builtin_amdgcn_s_setprio(1);
        #pragma unroll
        for (int m = 0; m < 4; m++)
            #pragma unroll
            for (int n = 0; n < 4; n++)
                acc[m][n] = __builtin_amdgcn_mfma_f32_16x16x32_bf16(af0c[m], bf0c[n], acc[m][n], 0, 0, 0);
        __builtin_amdgcn_s_setprio(0);

        #pragma unroll
        for (int m = 0; m < 4; m++) af1h[m] = *(const s16x8*)(Ap + aOff[m + 4] + x1);
        #pragma unroll
        for (int n = 0; n < 4; n++) bf1[n] = *(const s16x8*)(Bp + bOff[n] + x1);
        __builtin_amdgcn_s_setprio(1);
        #pragma unroll
        for (int m = 4; m < 8; m++)
            #pragma unroll
            for (int n = 0; n < 4; n++)
                acc[m][n] = __builtin_amdgcn_mfma_f32_16x16x32_bf16(af0h[m - 4], bf0c[n], acc[m][n], 0, 0, 0);
        __builtin_amdgcn_s_setprio(0);
        asm volatile("s_waitcnt lgkmcnt(0)" ::: "memory");
        bar();

        __builtin_amdgcn_s_setprio(1);
        #pragma unroll
        for (int m = 0; m < 4; m++)
            #pragma unroll
            for (int n = 0; n < 4; n++)
                acc[m][n] = __builtin_amdgcn_mfma_f32_16x16x32_bf16(af1l[m], bf1[n], acc[m][n], 0, 0, 0);
        __builtin_amdgcn_s_setprio(0);
        if (s2) {
            STAGE_A(P, 0, kt2);
            STAGE_A(P, 1, kt2);
            STAGE_B(P, 0, kt2);
            asm volatile("s_waitcnt vmcnt(6)" ::: "memory");
        } else {
            asm volatile("s_waitcnt vmcnt(0)" ::: "memory");
        }
        bar();

        if (s1) {
            #pragma unroll
            for (int m = 0; m < 4; m++) af0n[m] = *(const s16x8*)(Aq + aOff[m] + x0);
            #pragma unroll
            for (int n = 0; n < 4; n++) bf0n[n] = *(const s16x8*)(Bq + bOff[n] + x0);
        }
        __builtin_amdgcn_s_setprio(1);
        #pragma unroll
        for (int m = 4; m < 8; m++)
            #pragma unroll
            for (int n = 0; n < 4; n++)
                acc[m][n] = __builtin_amdgcn_mfma_f32_16x16x32_bf16(af1h[m - 4], bf1[n], acc[m][n], 0, 0, 0);
        __builtin_amdgcn_s_setprio(0);
        if (s1) {
            #pragma unroll
            for (int m = 0; m < 4; m++) af0c[m] = af0n[m];
            #pragma unroll
            for (int n = 0; n < 4; n++) bf0c[n] = bf0n[n];
        }
    }
#undef STAGE_A
#undef STAGE_B

    #pragma unroll
    for (int m = 0; m < 8; m++) {
        int rbase = j0 + wm * 128 + m * 16 + kg * 4;
        #pragma unroll
        for (int r = 0; r < 4; r++) {
            int row = rbase + r;
            int cnt = 0;
            #pragma unroll
            for (int n = 0; n < 4; n++) {
                int col = c0 + wn * 64 + n * 16 + fr;
                bool bit = (acc[m][n][r] > 0.f) || (row == col);
                Mi8[(size_t)row * NN + col] = bit ? (char)1 : (char)0;
                cnt += bit ? 1 : 0;
            }
            cnt += __shfl_xor(cnt, 1);
            cnt += __shfl_xor(cnt, 2);
            cnt += __shfl_xor(cnt, 4);
            cnt += __shfl_xor(cnt, 8);
            if (fr == 0) atomicAdd(&deg[row], cnt);
        }
    }
}

__global__ void k_dinv(const int* __restrict__ deg, float* __restrict__ dinv,
                       unsigned int* __restrict__ smY, unsigned int* __restrict__ smZ) {
    int i = blockIdx.x * 256 + threadIdx.x;
    if (i < NN) { dinv[i] = 1.0f / sqrtf((float)deg[i]); smY[i] = 0u; }
    if (i < NB * DOUT) smZ[i] = 0u;
}

// ---------------- k_y1m: MFMA YT bf16 + per-row absmax for quantization ----------------
__global__ __launch_bounds__(256) void k_y1m(
    const float* __restrict__ x, const float* __restrict__ W1,
    const float* __restrict__ dinv, unsigned short* __restrict__ YT,
    unsigned int* __restrict__ smY)
{
    __shared__ __align__(16) unsigned short Xs[128 * 64];
    __shared__ __align__(16) unsigned short Ws[128 * 64];
    const int tid = threadIdx.x;
    const int i0 = blockIdx.x * 128, b = blockIdx.y;

    const float* xg = x + ((size_t)(b * NN + i0)) * DIN;
    #pragma unroll
    for (int q = 0; q < 8; q++) {
        int idx = q * 256 + tid;
        int row = idx >> 4, c4 = idx & 15;
        f32x4 v = *(const f32x4*)(xg + (size_t)row * DIN + c4 * 4);
        s16x4 pk;
        #pragma unroll
        for (int e = 0; e < 4; e++) pk[e] = (short)f2bf(v[e]);
        int chunk = (c4 >> 1) ^ (row & 7);
        *(s16x4*)((char*)Xs + row * 128 + (chunk << 4) + (c4 & 1) * 8) = pk;
    }
    #pragma unroll
    for (int q = 0; q < 8; q++) {
        int idx = q * 256 + tid;
        int k = idx >> 5, f4 = (idx & 31) * 4;
        f32x4 v = ((const f32x4*)W1)[idx];
        #pragma unroll
        for (int e = 0; e < 4; e++) {
            int f = f4 + e;
            int chunk = (k >> 3) ^ (f & 7);
            *(unsigned short*)((char*)Ws + f * 128 + (chunk << 4) + (k & 7) * 2) = f2bf(v[e]);
        }
    }
    __syncthreads();

    const int lane = tid & 63, w = tid >> 6;
    const int wm = w >> 1, wn = w & 1;
    const int fr = lane & 15, kg = lane >> 4;
    f32x4 acc[4][4] = {};
    #pragma unroll
    for (int ks = 0; ks < 2; ks++) {
        int kc = ks * 4 + kg;
        s16x8 af[4], bf[4];
        #pragma unroll
        for (int mt = 0; mt < 4; mt++) {
            int row = wm * 64 + mt * 16 + fr;
            af[mt] = *(const s16x8*)((const char*)Xs + row * 128 + ((kc ^ (row & 7)) << 4));
        }
        #pragma unroll
        for (int nt = 0; nt < 4; nt++) {
            int f = wn * 64 + nt * 16 + fr;
            bf[nt] = *(const s16x8*)((const char*)Ws + f * 128 + ((kc ^ (f & 7)) << 4));
        }
        #pragma unroll
        for (int mt = 0; mt < 4; mt++)
            #pragma unroll
            for (int nt = 0; nt < 4; nt++)
                acc[mt][nt] = __builtin_amdgcn_mfma_f32_16x16x32_bf16(af[mt], bf[nt], acc[mt][nt], 0, 0, 0);
    }
    float am[4] = {0.f, 0.f, 0.f, 0.f};
    #pragma unroll
    for (int mt = 0; mt < 4; mt++) {
        int ibase = i0 + wm * 64 + mt * 16 + kg * 4;
        float dv[4];
        #pragma unroll
        for (int r = 0; r < 4; r++) dv[r] = dinv[ibase + r];
        #pragma unroll
        for (int nt = 0; nt < 4; nt++) {
            int f = wn * 64 + nt * 16 + fr;
            s16x4 pk;
            #pragma unroll
            for (int r = 0; r < 4; r++) {
                float v = acc[mt][nt][r] * dv[r];
                am[nt] = fmaxf(am[nt], fabsf(v));
                pk[r] = (short)f2bf(v);
            }
            *(s16x4*)(YT + (size_t)(b * DH + f) * NN + ibase) = pk;
        }
    }
    #pragma unroll
    for (int nt = 0; nt < 4; nt++) {
        float mv = am[nt];
        mv = fmaxf(mv, __shfl_xor(mv, 16));
        mv = fmaxf(mv, __shfl_xor(mv, 32));
        if (kg == 0)
            atomicMax(&smY[b * DH + wn * 64 + nt * 16 + fr], __float_as_uint(mv));
    }
}

// ---------------- quantize bf16 rows -> i8 with per-row scale max/127 ----------------
__global__ __launch_bounds__(256) void k_quant(
    const unsigned short* __restrict__ src, const unsigned int* __restrict__ smax,
    char* __restrict__ dst)
{
    const int c = blockIdx.x;
    const float s = __uint_as_float(smax[c]);
    const float inv = s > 0.f ? 127.0f / s : 0.f;
    const unsigned short* row = src + (size_t)c * NN;
    char* orow = dst + (size_t)c * NN;
    const int base = threadIdx.x * 16;
    s16x8 a = *(const s16x8*)(row + base);
    s16x8 b = *(const s16x8*)(row + base + 8);
    union { char c8[16]; i32x4 v; } u;
    #pragma unroll
    for (int e = 0; e < 8; e++) {
        int q = (int)rintf(bf2f((unsigned short)a[e]) * inv);
        q = q > 127 ? 127 : (q < -127 ? -127 : q);
        u.c8[e] = (char)q;
    }
    #pragma unroll
    for (int e = 0; e < 8; e++) {
        int q = (int)rintf(bf2f((unsigned short)b[e]) * inv);
        q = q > 127 ? 127 : (q < -127 ? -127 : q);
        u.c8[8 + e] = (char)q;
    }
    *(i32x4*)(orow + base) = u.v;
}

// ---------------- quantize bf16 rows -> dual-plane i8 (hi + lo residual) ----------------
__global__ __launch_bounds__(256) void k_quant2(
    const unsigned short* __restrict__ src, const unsigned int* __restrict__ smax,
    char* __restrict__ dst)
{
    const int c = blockIdx.x;
    const float s = __uint_as_float(smax[c]);
    const float inv = s > 0.f ? 127.0f / s : 0.f;
    const unsigned short* row = src + (size_t)c * NN;
    char* ohi = dst + (size_t)c * NN;
    char* olo = dst + (size_t)(NB * DOUT + c) * NN;
    const int base = threadIdx.x * 16;
    union { char c8[16]; i32x4 v; } uh, ul;
    #pragma unroll
    for (int e = 0; e < 16; e++) {
        float t = bf2f(row[base + e]) * inv;
        int qh = (int)rintf(t);
        qh = qh > 127 ? 127 : (qh < -127 ? -127 : qh);
        float r = (t - (float)qh) * 127.0f;
        int ql = (int)rintf(r);
        ql = ql > 127 ? 127 : (ql < -127 ? -127 : ql);
        uh.c8[e] = (char)qh;
        ul.c8[e] = (char)ql;
    }
    *(i32x4*)(ohi + base) = uh.v;
    *(i32x4*)(olo + base) = ul.v;
}

// ======== gemm1 (i8): 256x256, BK=128 i8, 8 waves; 8-phase quadrant schedule ========
__global__ __launch_bounds__(512, 2) void gemm8qi(
    const char* __restrict__ A, const char* __restrict__ Bt,
    unsigned short* __restrict__ H, const float* __restrict__ dinv,
    const unsigned int* __restrict__ smY, const float* __restrict__ bias)
{
    constexpr int KB = NN;         // 4096 bytes per row
    constexpr int NT = 32;         // K-tiles of 128 i8
    __shared__ __align__(16) char As[2][256 * 128];   // 32 KB each
    __shared__ __align__(16) char Bs[2][256 * 128];

    const int tid = threadIdx.x;
    const int lane = tid & 63;
    const int w = tid >> 6;
    const int wm = w >> 2, wn = w & 3;
    const int fr = lane & 15, kg = lane >> 4;

    const int bid = blockIdx.x;
    const int swz = (bid & 7) * 32 + (bid >> 3);
    const int bx = swz & 15, by = swz >> 4;
    const int c0 = bx * 256, j0 = by * 256;

    const char* Aj = A + (size_t)j0 * KB;
    const char* Bc = Bt + (size_t)c0 * KB;

    const int lr = tid >> 3, kcs = tid & 7;

#define STAGE_AQ(buf, q, kt) do { \
    int ra_ = (q) * 64 + lr; \
    int rb_ = ra_ + 128; \
    gload16(Aj + (size_t)ra_ * KB + (kt) + ((kcs ^ (ra_ & 7)) << 4), \
            &As[buf][(q) * 8192 + tid * 16]); \
    gload16(Aj + (size_t)rb_ * KB + (kt) + ((kcs ^ (rb_ & 7)) << 4), \
            &As[buf][(q) * 8192 + 16384 + tid * 16]); \
} while (0)
#define STAGE_BQ(buf, nh, kt) do { \
    int ca_ = tid, cb_ = tid + 512; \
    int r0_ = (ca_ >> 8) * 64 + (nh) * 32 + ((ca_ >> 3) & 31); \
    int r1_ = (cb_ >> 8) * 64 + (nh) * 32 + ((cb_ >> 3) & 31); \
    gload16(Bc + (size_t)r0_ * KB + (kt) + (((ca_ & 7) ^ (r0_ & 7)) << 4), \
            &Bs[buf][(ca_ >> 8) * 8192 + (nh) * 4096 + (ca_ & 255) * 16]); \
    gload16(Bc + (size_t)r1_ * KB + (kt) + (((cb_ & 7) ^ (r1_ & 7)) << 4), \
            &Bs[buf][(cb_ >> 8) * 8192 + (nh) * 4096 + (cb_ & 255) * 16]); \
} while (0)

    STAGE_AQ(0, 0, 0); STAGE_AQ(0, 1, 0);
    STAGE_BQ(0, 0, 0); STAGE_BQ(0, 1, 0);
    STAGE_BQ(1, 0, 128); STAGE_BQ(1, 1, 128);
    asm volatile("s_waitcnt vmcnt(4)" ::: "memory");
    bar();

    const int x0 = ((kg) ^ (fr & 7)) << 4;
    const int x1 = ((4 + kg) ^ (fr & 7)) << 4;
    int aOff[8], bOff[4];
    #pragma unroll
    for (int m = 0; m < 8; m++) aOff[m] = (wm * 128 + m * 16 + fr) * 128;
    #pragma unroll
    for (int n = 0; n < 4; n++) bOff[n] = (wn * 64 + n * 16 + fr) * 128;

    i32x4 acc[8][4] = {};
    const char* A0p = (const char*)As[0];
    const char* B0p = (const char*)Bs[0];
    const char* A1p = (const char*)As[1];
    const char* B1p = (const char*)Bs[1];

#define MFMA_Q(MB, NB_, AF0, AF1, BK0, BK1) do { \
    __builtin_amdgcn_s_setprio(1); \
    _Pragma("unroll") \
    for (int m = 0; m < 4; m++) { \
        _Pragma("unroll") \
        for (int n = 0; n < 2; n++) { \
            acc[(MB) + m][(NB_) + n] = __builtin_amdgcn_mfma_i32_16x16x64_i8( \
                AF0[m], BK0[n], acc[(MB) + m][(NB_) + n], 0, 0, 0); \
            acc[(MB) + m][(NB_) + n] = __builtin_amdgcn_mfma_i32_16x16x64_i8( \
                AF1[m], BK1[n], acc[(MB) + m][(NB_) + n], 0, 0, 0); \
        } \
    } \
    __builtin_amdgcn_s_setprio(0); \
} while (0)

    i32x4 af0[4], af1[4], b0k0[2], b0k1[2], b1k0[2], b1k1[2];

    for (int T = 0; T < NT; T += 2) {
        const bool s2 = (T + 2) < NT, s3 = (T + 3) < NT;
        const int kt1 = (T + 1) * 128, kt2 = (T + 2) * 128, kt3 = (T + 3) * 128;

        #pragma unroll
        for (int m = 0; m < 4; m++) { af0[m] = *(const i32x4*)(A0p + aOff[m] + x0);
                                      af1[m] = *(const i32x4*)(A0p + aOff[m] + x1); }
        #pragma unroll
        for (int n = 0; n < 2; n++) { b0k0[n] = *(const i32x4*)(B0p + bOff[n] + x0);
                                      b0k1[n] = *(const i32x4*)(B0p + bOff[n] + x1); }
        STAGE_AQ(1, 0, kt1);
        bar();
        MFMA_Q(0, 0, af0, af1, b0k0, b0k1);
        bar();

        #pragma unroll
        for (int n = 0; n < 2; n++) { b1k0[n] = *(const i32x4*)(B0p + bOff[n + 2] + x0);
                                      b1k1[n] = *(const i32x4*)(B0p + bOff[n + 2] + x1); }
        STAGE_AQ(1, 1, kt1);
        bar();
        MFMA_Q(0, 2, af0, af1, b1k0, b1k1);
        bar();

        #pragma unroll
        for (int m = 0; m < 4; m++) { af0[m] = *(const i32x4*)(A0p + aOff[m + 4] + x0);
                                      af1[m] = *(const i32x4*)(A0p + aOff[m + 4] + x1); }
        if (s2) STAGE_BQ(0, 0, kt2);
        bar();
        MFMA_Q(4, 0, af0, af1, b0k0, b0k1);
        bar();

        if (s2) { STAGE_BQ(0, 1, kt2);
                  asm volatile("s_waitcnt vmcnt(4)" ::: "memory"); }
        else    { asm volatile("s_waitcnt vmcnt(0)" ::: "memory"); }
        bar();
        MFMA_Q(4, 2, af0, af1, b1k0, b1k1);
        bar();

        #pragma unroll
        for (int m = 0; m < 4; m++) { af0[m] = *(const i32x4*)(A1p + aOff[m] + x0);
                                      af1[m] = *(const i32x4*)(A1p + aOff[m] + x1); }
        #pragma unroll
        for (int n = 0; n < 2; n++) { b0k0[n] = *(const i32x4*)(B1p + bOff[n] + x0);
                                      b0k1[n] = *(const i32x4*)(B1p + bOff[n] + x1); }
        if (s2) STAGE_AQ(0, 0, kt2);
        bar();
        MFMA_Q(0, 0, af0, af1, b0k0, b0k1);
        bar();

        #pragma unroll
        for (int n = 0; n < 2; n++) { b1k0[n] = *(const i32x4*)(B1p + bOff[n + 2] + x0);
                                      b1k1[n] = *(const i32x4*)(B1p + bOff[n + 2] + x1); }
        if (s2) STAGE_AQ(0, 1, kt2);
        bar();
        MFMA_Q(0, 2, af0, af1, b1k0, b1k1);
        bar();

        #pragma unroll
        for (int m = 0; m < 4; m++) { af0[m] = *(const i32x4*)(A1p + aOff[m + 4] + x0);
                                      af1[m] = *(const i32x4*)(A1p + aOff[m + 4] + x1); }
        if (s3) STAGE_BQ(1, 0, kt3);
        bar();
        MFMA_Q(4, 0, af0, af1, b0k0, b0k1);
        bar();

        if (s3) { STAGE_BQ(1, 1, kt3);
                  asm volatile("s_waitcnt vmcnt(4)" ::: "memory"); }
        else    { asm volatile("s_waitcnt vmcnt(0)" ::: "memory"); }
        bar();
        MFMA_Q(4, 2, af0, af1, b1k0, b1k1);
        bar();
    }
#undef MFMA_Q
#undef STAGE_AQ
#undef STAGE_BQ

    #pragma unroll
    for (int m = 0; m < 8; m++) {
        int rbase = j0 + wm * 128 + m * 16 + kg * 4;
        float dv[4];
        #pragma unroll
        for (int r = 0; r < 4; r++) dv[r] = dinv[rbase + r];
        #pragma unroll
        for (int n = 0; n < 4; n++) {
            int gcol = c0 + wn * 64 + n * 16 + fr;
            float bb = bias[gcol & (DH - 1)];
            float sc = __uint_as_float(smY[gcol]) * (1.0f / 127.0f);
            #pragma unroll
            for (int r = 0; r < 4; r++) {
                float v = (float)acc[m][n][r] * sc * dv[r] + bb;
                v = v > 0.f ? v : 0.f;
                H[(size_t)(rbase + r) * NN + gcol] = f2bf(v);
            }
        }
    }
}

// ---------- k_z2: MFMA ZT bf16 + per-row absmax ----------
__global__ __launch_bounds__(256) void k_z2(
    const unsigned short* __restrict__ H, const float* __restrict__ W2,
    const float* __restrict__ dinv, unsigned short* __restrict__ ZT,
    unsigned int* __restrict__ smZ)
{
    __shared__ __align__(16) unsigned short Hs[128 * DH];
    __shared__ __align__(16) unsigned short W2Ts[DOUT * DH];
    const int tid = threadIdx.x;
    const int j0 = blockIdx.x * 128, b = blockIdx.y;
    const unsigned short* Hb = H + (size_t)j0 * NN + b * DH;

    #pragma unroll
    for (int q = 0; q < 8; q++) {
        int cid = q * 256 + tid;
        int row = cid >> 4, kc = cid & 15;
        gload16(Hb + (size_t)row * NN + kc * 8, &Hs[cid * 8]);
    }
    #pragma unroll
    for (int q = 0; q < 16; q++) {
        int idx = q * 256 + tid;
        int f = idx >> 5, g = idx & 31;
        W2Ts[g * DH + f] = f2bf(W2[f * DOUT + g]);
    }
    __syncthreads();

    const int lane = tid & 63, w = tid >> 6;
    const int fr = lane & 15, kg = lane >> 4;
    f32x4 acc[2][2] = {};
    #pragma unroll
    for (int ks = 0; ks < 4; ks++) {
        s16x8 af[2], bf[2];
        #pragma unroll
        for (int mt = 0; mt < 2; mt++) {
            int row = w * 32 + mt * 16 + fr;
            af[mt] = *(const s16x8*)&Hs[row * DH + ks * 32 + kg * 8];
        }
        #pragma unroll
        for (int nt = 0; nt < 2; nt++) {
            int g = nt * 16 + fr;
            bf[nt] = *(const s16x8*)&W2Ts[g * DH + ks * 32 + kg * 8];
        }
        #pragma unroll
        for (int mt = 0; mt < 2; mt++)
            #pragma unroll
            for (int nt = 0; nt < 2; nt++)
                acc[mt][nt] = __builtin_amdgcn_mfma_f32_16x16x32_bf16(af[mt], bf[nt], acc[mt][nt], 0, 0, 0);
    }
    float am[2] = {0.f, 0.f};
    #pragma unroll
    for (int mt = 0; mt < 2; mt++) {
        int jbase = j0 + w * 32 + mt * 16 + kg * 4;
        float dv[4];
        #pragma unroll
        for (int r = 0; r < 4; r++) dv[r] = dinv[jbase + r];
        #pragma unroll
        for (int nt = 0; nt < 2; nt++) {
            int g = nt * 16 + fr;
            s16x4 pk;
            #pragma unroll
            for (int r = 0; r < 4; r++) {
                float v = acc[mt][nt][r] * dv[r];
                am[nt] = fmaxf(am[nt], fabsf(v));
                pk[r] = (short)f2bf(v);
            }
            *(s16x4*)(ZT + (size_t)(b * DOUT + g) * NN + jbase) = pk;
        }
    }
    #pragma unroll
    for (int nt = 0; nt < 2; nt++) {
        float mv = am[nt];
        mv = fmaxf(mv, __shfl_xor(mv, 16));
        mv = fmaxf(mv, __shfl_xor(mv, 32));
        if (kg == 0)
            atomicMax(&smZ[b * DOUT + nt * 16 + fr], __float_as_uint(mv));
    }
}

// ---------- gsm2d: gemm2 64x128 dual-plane i8, BK=128 (NT=32), fused softmax ----------
__global__ __launch_bounds__(256) void gsm2d(
    const char* __restrict__ Mi8, const char* __restrict__ Zq,
    float* __restrict__ out, const float* __restrict__ dinv,
    const unsigned int* __restrict__ smZ, const float* __restrict__ bias)
{
    constexpr int KB = NN;         // bytes per row
    constexpr int NT = 32;         // K-tiles of 128 bytes
    __shared__ __align__(16) char Asm[2][64 * 128];    // 2 x 8 KB
    __shared__ __align__(16) char Bhi[2][128 * 128];   // 2 x 16 KB
    __shared__ __align__(16) char Blo[2][128 * 128];   // 2 x 16 KB  (total 80 KB)
    const int tid = threadIdx.x;
    const int lane = tid & 63;
    const int w = tid >> 6;
    const int wm = w >> 1, wn = w & 1;     // 2 x 2 waves; per-wave 32 x 64
    const int c0 = blockIdx.x * 128;
    const int j0 = blockIdx.y * 64;
    const int fr = lane & 15, kg = lane >> 4;

    int srcA[2], srcB[4];
    #pragma unroll
    for (int q = 0; q < 2; q++) {
        int cid = q * 256 + tid;
        int row = cid >> 3, kc = cid & 7;
        srcA[q] = row * KB + ((kc ^ (row & 7)) << 4);
    }
    #pragma unroll
    for (int q = 0; q < 4; q++) {
        int cid = q * 256 + tid;
        int row = cid >> 3, kc = cid & 7;
        srcB[q] = row * KB + ((kc ^ (row & 7)) << 4);
    }
    const char* Abase = Mi8 + (size_t)j0 * KB;
    const char* Bh = Zq + (size_t)c0 * KB;
    const char* Bl = Zq + (size_t)(NB * DOUT + c0) * KB;

#define STAGE_T(buf, kt) do { \
    _Pragma("unroll") \
    for (int q = 0; q < 2; q++) \
        gload16(Abase + (kt) + srcA[q], &Asm[buf][(q * 256 + tid) * 16]); \
    _Pragma("unroll") \
    for (int q = 0; q < 4; q++) \
        gload16(Bh + (kt) + srcB[q], &Bhi[buf][(q * 256 + tid) * 16]); \
    _Pragma("unroll") \
    for (int q = 0; q < 4; q++) \
        gload16(Bl + (kt) + srcB[q], &Blo[buf][(q * 256 + tid) * 16]); } while (0)

    STAGE_T(0, 0);
    STAGE_T(1, 128);
    asm volatile("s_waitcnt vmcnt(10)" ::: "memory");
    bar();

    const int x0 = (kg ^ (fr & 7)) << 4;
    const int x1 = ((4 + kg) ^ (fr & 7)) << 4;
    int aOff[2], bOff[4];
    #pragma unroll
    for (int m = 0; m < 2; m++) aOff[m] = (wm * 32 + m * 16 + fr) * 128;
    #pragma unroll
    for (int n = 0; n < 4; n++) bOff[n] = (wn * 64 + n * 16 + fr) * 128;

    i32x4 afc[2][2], bhc[2][4], blc[2][4];
    #pragma unroll
    for (int ks = 0; ks < 2; ks++) {
        int xk = ks ? x1 : x0;
        #pragma unroll
        for (int m = 0; m < 2; m++) afc[ks][m] = *(const i32x4*)((const char*)Asm[0] + aOff[m] + xk);
        #pragma unroll
        for (int n = 0; n < 4; n++) {
            bhc[ks][n] = *(const i32x4*)((const char*)Bhi[0] + bOff[n] + xk);
            blc[ks][n] = *(const i32x4*)((const char*)Blo[0] + bOff[n] + xk);
        }
    }
    asm volatile("s_waitcnt lgkmcnt(0)" ::: "memory");
    bar();

    i32x4 ah[2][4] = {};
    i32x4 al[2][4] = {};

    for (int t = 0; t < NT; t++) {
        const int P = t & 1;
        const bool s1 = (t + 1) < NT, s2 = (t + 2) < NT;

        if (s2) STAGE_T(P, (t + 2) * 128);
        __builtin_amdgcn_s_setprio(1);
        #pragma unroll
        for (int m = 0; m < 2; m++)
            #pragma unroll
            for (int n = 0; n < 4; n++) {
                ah[m][n] = __builtin_amdgcn_mfma_i32_16x16x64_i8(afc[0][m], bhc[0][n], ah[m][n], 0, 0, 0);
                al[m][n] = __builtin_amdgcn_mfma_i32_16x16x64_i8(afc[0][m], blc[0][n], al[m][n], 0, 0, 0);
            }
        __builtin_amdgcn_s_setprio(0);
        if (s2) asm volatile("s_waitcnt vmcnt(10)" ::: "memory");
        else    asm volatile("s_waitcnt vmcnt(0)" ::: "memory");
        bar();

        i32x4 afn[2][2], bhn[2][4], bln[2][4];
        if (s1) {
            const char* Aq = (const char*)Asm[P ^ 1];
            const char* Bhq = (const char*)Bhi[P ^ 1];
            const char* Blq = (const char*)Blo[P ^ 1];
            #pragma unroll
            for (int ks = 0; ks < 2; ks++) {
                int xk = ks ? x1 : x0;
                #pragma unroll
                for (int m = 0; m < 2; m++) afn[ks][m] = *(const i32x4*)(Aq + aOff[m] + xk);
                #pragma unroll
                for (int n = 0; n < 4; n++) {
                    bhn[ks][n] = *(const i32x4*)(Bhq + bOff[n] + xk);
                    bln[ks][n] = *(const i32x4*)(Blq + bOff[n] + xk);
                }
            }
        }
        __builtin_amdgcn_s_setprio(1);
        #pragma unroll
        for (int m = 0; m < 2; m++)
            #pragma unroll
            for (int n = 0; n < 4; n++) {
                ah[m][n] = __builtin_amdgcn_mfma_i32_16x16x64_i8(afc[1][m], bhc[1][n], ah[m][n], 0, 0, 0);
                al[m][n] = __builtin_amdgcn_mfma_i32_16x16x64_i8(afc[1][m], blc[1][n], al[m][n], 0, 0, 0);
            }
        __builtin_amdgcn_s_setprio(0);
        asm volatile("s_waitcnt lgkmcnt(0)" ::: "memory");
        bar();
        if (s1) {
            #pragma unroll
            for (int ks = 0; ks < 2; ks++) {
                #pragma unroll
                for (int m = 0; m < 2; m++) afc[ks][m] = afn[ks][m];
                #pragma unroll
                for (int n = 0; n < 4; n++) { bhc[ks][n] = bhn[ks][n]; blc[ks][n] = bln[ks][n]; }
            }
        }
    }
#undef STAGE_T

    const float b_lo = bias[fr], b_hi = bias[fr + 16];
    #pragma unroll
    for (int m = 0; m < 2; m++) {
        int rbase = j0 + wm * 32 + m * 16 + kg * 4;
        float dv[4];
        #pragma unroll
        for (int r = 0; r < 4; r++) dv[r] = dinv[rbase + r];
        #pragma unroll
        for (int np = 0; np < 2; np++) {
            int bg = (c0 >> 5) + wn * 2 + np;
            float sc0 = __uint_as_float(smZ[c0 + wn * 64 + np * 32 + fr])      * (1.0f / 127.0f);
            float sc1 = __uint_as_float(smZ[c0 + wn * 64 + np * 32 + fr + 16]) * (1.0f / 127.0f);
            #pragma unroll
            for (int r = 0; r < 4; r++) {
                int row = rbase + r;
                float v0 = ((float)ah[m][np * 2][r]     + (float)al[m][np * 2][r]     * (1.0f / 127.0f)) * sc0 * dv[r] + b_lo;
                float v1 = ((float)ah[m][np * 2 + 1][r] + (float)al[m][np * 2 + 1][r] * (1.0f / 127.0f)) * sc1 * dv[r] + b_hi;
                float mx = fmaxf(v0, v1);
                #pragma unroll
                for (int d = 8; d; d >>= 1) mx = fmaxf(mx, __shfl_xor(mx, d));
                float e0 = expf(v0 - mx), e1 = expf(v1 - mx);
                float s = e0 + e1;
                #pragma unroll
                for (int d = 8; d; d >>= 1) s += __shfl_xor(s, d);
                float inv = 1.0f / s;
                size_t ob = ((size_t)bg * NN + row) * DOUT;
                out[ob + fr]      = e0 * inv;
                out[ob + fr + 16] = e1 * inv;
            }
        }
    }
}

extern "C" void kernel_launch(void* const* d_in, const int* in_sizes, int n_in,
                              void* d_out, int out_size, void* d_ws, size_t ws_size,
                              hipStream_t stream)
{
    (void)in_sizes; (void)n_in; (void)out_size; (void)ws_size;
    const float* x    = (const float*)d_in[0];
    const float* emb1 = (const float*)d_in[1];
    const float* emb2 = (const float*)d_in[2];
    const float* l1w  = (const float*)d_in[3];
    const float* l1b  = (const float*)d_in[4];
    const float* l2w  = (const float*)d_in[5];
    const float* l2b  = (const float*)d_in[6];
    const float* g1w  = (const float*)d_in[7];
    const float* g1b  = (const float*)d_in[8];
    const float* g2w  = (const float*)d_in[9];
    const float* g2b  = (const float*)d_in[10];
    float* out = (float*)d_out;

    char* w = (char*)d_ws;
    int* deg = (int*)w;                       w += NN * 4;
    float* dinv = (float*)w;                  w += NN * 4;
    unsigned int* smY = (unsigned int*)w;     w += NN * 4;
    unsigned int* smZ = (unsigned int*)w;     w += NB * DOUT * 4;
    char* Mi8 = (char*)w;                     w += (size_t)NN * NN;
    unsigned short* YT = (unsigned short*)w;  w += (size_t)NN * NN * 2;
    char* Yq = (char*)w;                      w += (size_t)NN * NN;
    unsigned short* H  = (unsigned short*)w;  w += (size_t)NN * NN * 2;
    unsigned short* ZT = (unsigned short*)w;  w += (size_t)(NB * DOUT) * NN * 2;
    // Ux/Vx live in YT's region (dead until k_y1m); ZTq2 (8MB) lives in Yq's
    // region (Yq dead after gemm8qi; k_quant2/gsm2d run after it).
    unsigned short* Ux = YT;
    unsigned short* Vx = YT + (size_t)NN * KADJ;
    char* ZTq2 = Yq;

    k_embuv<<<256, 256, 0, stream>>>(emb1, emb2, l1w, l1b, l2w, l2b, Ux, Vx, deg);
    gemm_adj8<<<256, 512, 0, stream>>>(Vx, Ux, Mi8, deg);
    k_dinv<<<16, 256, 0, stream>>>(deg, dinv, smY, smZ);
    k_y1m<<<dim3(32, 32), 256, 0, stream>>>(x, g1w, dinv, YT, smY);
    k_quant<<<NN, 256, 0, stream>>>(YT, smY, Yq);
    gemm8qi<<<256, 512, 0, stream>>>(Mi8, Yq, H, dinv, smY, g1b);
    k_z2<<<dim3(32, 32), 256, 0, stream>>>(H, g2w, dinv, ZT, smZ);
    k_quant2<<<NB * DOUT, 256, 0, stream>>>(ZT, smZ, ZTq2);
    gsm2d<<<dim3(8, 64), 256, 0, stream>>>(Mi8, ZTq2, out, dinv, smZ, g2b);
}

// Round 19
// 200.103 us; speedup vs baseline: 1.6077x; 1.0035x over previous
//
#include <hip/hip_runtime.h>

typedef float f32x4 __attribute__((ext_vector_type(4)));
typedef short s16x8 __attribute__((ext_vector_type(8)));
typedef short s16x4 __attribute__((ext_vector_type(4)));
typedef int i32x4 __attribute__((ext_vector_type(4)));

#define NN 4096
#define NB 32
#define DIN 64
#define DH 128
#define DOUT 32
#define DIM 40
#define KADJ 320   // 4 split-blocks x 80 = exact (u0+u1)(v0+v1); 320 % 64 == 0

__device__ __forceinline__ unsigned short f2bf(float f) {
    unsigned int u = __float_as_uint(f);
    unsigned int r = (u + 0x7FFFu + ((u >> 16) & 1u)) >> 16;
    return (unsigned short)r;
}
__device__ __forceinline__ float bf2f(unsigned short h) {
    return __uint_as_float(((unsigned int)h) << 16);
}
__device__ __forceinline__ void gload16(const void* g, void* l) {
    __builtin_amdgcn_global_load_lds(
        (const __attribute__((address_space(1))) unsigned int*)g,
        (__attribute__((address_space(3))) unsigned int*)l, 16, 0, 0);
}
__device__ __forceinline__ void bar() {
    asm volatile("" ::: "memory");
    __builtin_amdgcn_s_barrier();
    asm volatile("" ::: "memory");
}

// ---------------- fused: n1/n2 = tanh(3*(emb @ W + b)) -> 2-term bf16 split operands ----------------
__global__ __launch_bounds__(256) void k_embuv(
    const float* __restrict__ emb1, const float* __restrict__ emb2,
    const float* __restrict__ l1w, const float* __restrict__ l1b,
    const float* __restrict__ l2w, const float* __restrict__ l2b,
    unsigned short* __restrict__ Ux, unsigned short* __restrict__ Vx,
    int* __restrict__ deg)
{
    __shared__ float e1s[16 * DIM], e2s[16 * DIM];
    __shared__ float w1s[DIM * DIM], w2s[DIM * DIM], b1s[DIM], b2s[DIM];
    __shared__ unsigned short Ul[16][KADJ], Vl[16][KADJ];
    const int tid = threadIdx.x;
    const int node0 = blockIdx.x * 16;
    if (tid < 16) deg[node0 + tid] = 0;
    for (int i = tid; i < 16 * DIM; i += 256) {
        e1s[i] = emb1[node0 * DIM + i];
        e2s[i] = emb2[node0 * DIM + i];
    }
    for (int i = tid; i < DIM * DIM; i += 256) { w1s[i] = l1w[i]; w2s[i] = l2w[i]; }
    if (tid < DIM) { b1s[tid] = l1b[tid]; b2s[tid] = l2b[tid]; }
    __syncthreads();
    const int r = tid >> 4;
    const int k0 = (tid & 15) * 5;
    const int PMAP[4] = {0, 0, 1, 1};
    const int QMAP[4] = {0, 1, 0, 1};
    #pragma unroll
    for (int e = 0; e < 5; e++) {
        int k = k0 + e;
        int kp = (k < DIM) ? k : k - DIM;
        float acc1 = b1s[kp], acc2 = b2s[kp];
        for (int kk = 0; kk < DIM; kk++) {
            acc1 += e1s[r * DIM + kk] * w1s[kk * DIM + kp];
            acc2 += e2s[r * DIM + kk] * w2s[kk * DIM + kp];
        }
        float n1v = tanhf(3.0f * acc1), n2v = tanhf(3.0f * acc2);
        float a = (k < DIM) ? n1v : -n2v;
        float b = (k < DIM) ? n2v : n1v;
        unsigned short u0 = f2bf(a); float ra = a - bf2f(u0);
        unsigned short u1 = f2bf(ra);
        unsigned short v0 = f2bf(b); float rb = b - bf2f(v0);
        unsigned short v1 = f2bf(rb);
        unsigned short uu[2] = {u0, u1}, vv[2] = {v0, v1};
        #pragma unroll
        for (int bq = 0; bq < 4; bq++) {
            Ul[r][80 * bq + k] = uu[PMAP[bq]];
            Vl[r][80 * bq + k] = vv[QMAP[bq]];
        }
    }
    __syncthreads();
    for (int idx = tid; idx < 16 * KADJ / 8; idx += 256) {   // 640 chunks
        int rr = idx / 40, c8 = idx - rr * 40;
        size_t off = ((size_t)(node0 + rr)) * KADJ + c8 * 8;
        *(s16x8*)(Ux + off) = *(s16x8*)&Ul[rr][c8 * 8];
        *(s16x8*)(Vx + off) = *(s16x8*)&Vl[rr][c8 * 8];
    }
}

// ---------------- adjacency GEMM (bf16 operands), K=320, epilogue -> Mi8 + deg ----------------
__global__ __launch_bounds__(512, 2) void gemm_adj8(
    const unsigned short* __restrict__ A, const unsigned short* __restrict__ Bt,
    char* __restrict__ Mi8, int* __restrict__ deg)
{
    constexpr int K = KADJ;        // 320
    constexpr int NT = K / 64;     // 5 K-tiles
    __shared__ __align__(16) unsigned short As[2][256 * 64];
    __shared__ __align__(16) unsigned short Bs[2][256 * 64];

    const int tid = threadIdx.x;
    const int lane = tid & 63;
    const int w = tid >> 6;
    const int wm = w >> 2, wn = w & 3;
    const int fr = lane & 15, kg = lane >> 4;

    const int bid = blockIdx.x;
    const int swz = (bid & 7) * 32 + (bid >> 3);
    const int bx = swz & 15, by = swz >> 4;
    const int c0 = bx * 256, j0 = by * 256;

    const int cid0 = w * 128 + lane, cid1 = cid0 + 64;
    const int r0 = cid0 >> 3, k0c = cid0 & 7;
    const int r1 = cid1 >> 3, k1c = cid1 & 7;
    const int so0 = r0 * K + ((k0c ^ (r0 & 7)) << 3);
    const int so1 = r1 * K + ((k1c ^ (r1 & 7)) << 3);
    const int lb0 = (w * 2 + 0) * 512;
    const int lb1 = (w * 2 + 1) * 512;

    const unsigned short* Aj = A + (size_t)j0 * K;
    const unsigned short* Bc = Bt + (size_t)c0 * K;

#define STAGE_A(buf, half, kt) do { \
    const unsigned short* g_ = Aj + (size_t)((half) * 128) * K + (kt); \
    gload16(g_ + so0, &As[buf][(half) * 8192 + lb0]); \
    gload16(g_ + so1, &As[buf][(half) * 8192 + lb1]); } while (0)
#define STAGE_B(buf, half, kt) do { \
    const unsigned short* g_ = Bc + (size_t)((half) * 128) * K + (kt); \
    gload16(g_ + so0, &Bs[buf][(half) * 8192 + lb0]); \
    gload16(g_ + so1, &Bs[buf][(half) * 8192 + lb1]); } while (0)

    STAGE_A(0, 0, 0);  STAGE_A(0, 1, 0);
    STAGE_B(0, 0, 0);  STAGE_B(0, 1, 0);
    STAGE_A(1, 0, 64); STAGE_A(1, 1, 64);
    STAGE_B(1, 0, 64);
    asm volatile("s_waitcnt vmcnt(6)" ::: "memory");
    bar();

    const int x0 = ((kg) ^ (fr & 7)) << 4;
    const int x1 = ((4 + kg) ^ (fr & 7)) << 4;
    int aOff[8], bOff[4];
    #pragma unroll
    for (int m = 0; m < 8; m++) aOff[m] = (wm * 128 + m * 16 + fr) * 128;
    #pragma unroll
    for (int n = 0; n < 4; n++) bOff[n] = (wn * 64 + n * 16 + fr) * 128;

    s16x8 af0c[4], bf0c[4];
    #pragma unroll
    for (int m = 0; m < 4; m++) af0c[m] = *(const s16x8*)((const char*)As[0] + aOff[m] + x0);
    #pragma unroll
    for (int n = 0; n < 4; n++) bf0c[n] = *(const s16x8*)((const char*)Bs[0] + bOff[n] + x0);

    f32x4 acc[8][4] = {};

    for (int t = 0; t < NT; t++) {
        const int P = t & 1;
        const char* Ap = (const char*)As[P];
        const char* Bp = (const char*)Bs[P];
        const char* Aq = (const char*)As[P ^ 1];
        const char* Bq = (const char*)Bs[P ^ 1];
        const int kt1 = (t + 1) * 64, kt2 = (t + 2) * 64;
        const bool s1 = (t + 1) < NT, s2 = (t + 2) < NT;
        s16x8 af0h[4], af1l[4], af1h[4], bf1[4], af0n[4], bf0n[4];

        #pragma unroll
        for (int m = 0; m < 4; m++) af0h[m] = *(const s16x8*)(Ap + aOff[m + 4] + x0);
        #pragma unroll
        for (int m = 0; m < 4; m++) af1l[m] = *(const s16x8*)(Ap + aOff[m] + x1);
        if (s1) STAGE_B(P ^ 1, 1, kt1);
        __builtin_amdgcn_s_setprio(1);
        #pragma unroll
        for (int m = 0; m < 4; m++)
            #pragma unroll
            for (int n = 0; n < 4; n++)
                acc[m][n] = __builtin_amdgcn_mfma_f32_16x16x32_bf16(af0c[m], bf0c[n], acc[m][n], 0, 0, 0);
        __builtin_amdgcn_s_setprio(0);

        #pragma unroll
        for (int m = 0; m < 4; m++) af1h[m] = *(const s16x8*)(Ap + aOff[m + 4] + x1);
        #pragma unroll
        for (int n = 0; n < 4; n++) bf1[n] = *(const s16x8*)(Bp + bOff[n] + x1);
        __builtin_amdgcn_s_setprio(1);
        #pragma unroll
        for (int m = 4; m < 8; m++)
            #pragma unroll
            for (int n = 0; n < 4; n++)
                acc[m][n] = __builtin_amdgcn_mfma_f32_16x16x32_bf16(af0h[m - 4], bf0c[n], acc[m][n], 0, 0, 0);
        __builtin_amdgcn_s_setprio(0);
        asm volatile("s_waitcnt lgkmcnt(0)" ::: "memory");
        bar();

        __builtin_amdgcn_s_setprio(1);
        #pragma unroll
        for (int m = 0; m < 4; m++)
            #pragma unroll
            for (int n = 0; n < 4; n++)
                acc[m][n] = __builtin_amdgcn_mfma_f32_16x16x32_bf16(af1l[m], bf1[n], acc[m][n], 0, 0, 0);
        __builtin_amdgcn_s_setprio(0);
        if (s2) {
            STAGE_A(P, 0, kt2);
            STAGE_A(P, 1, kt2);
            STAGE_B(P, 0, kt2);
            asm volatile("s_waitcnt vmcnt(6)" ::: "memory");
        } else {
            asm volatile("s_waitcnt vmcnt(0)" ::: "memory");
        }
        bar();

        if (s1) {
            #pragma unroll
            for (int m = 0; m < 4; m++) af0n[m] = *(const s16x8*)(Aq + aOff[m] + x0);
            #pragma unroll
            for (int n = 0; n < 4; n++) bf0n[n] = *(const s16x8*)(Bq + bOff[n] + x0);
        }
        __builtin_amdgcn_s_setprio(1);
        #pragma unroll
        for (int m = 4; m < 8; m++)
            #pragma unroll
            for (int n = 0; n < 4; n++)
                acc[m][n] = __builtin_amdgcn_mfma_f32_16x16x32_bf16(af1h[m - 4], bf1[n], acc[m][n], 0, 0, 0);
        __builtin_amdgcn_s_setprio(0);
        if (s1) {
            #pragma unroll
            for (int m = 0; m < 4; m++) af0c[m] = af0n[m];
            #pragma unroll
            for (int n = 0; n < 4; n++) bf0c[n] = bf0n[n];
        }
    }
#undef STAGE_A
#undef STAGE_B

    #pragma unroll
    for (int m = 0; m < 8; m++) {
        int rbase = j0 + wm * 128 + m * 16 + kg * 4;
        #pragma unroll
        for (int r = 0; r < 4; r++) {
            int row = rbase + r;
            int cnt = 0;
            #pragma unroll
            for (int n = 0; n < 4; n++) {
                int col = c0 + wn * 64 + n * 16 + fr;
                bool bit = (acc[m][n][r] > 0.f) || (row == col);
                Mi8[(size_t)row * NN + col] = bit ? (char)1 : (char)0;
                cnt += bit ? 1 : 0;
            }
            cnt += __shfl_xor(cnt, 1);
            cnt += __shfl_xor(cnt, 2);
            cnt += __shfl_xor(cnt, 4);
            cnt += __shfl_xor(cnt, 8);
            if (fr == 0) atomicAdd(&deg[row], cnt);
        }
    }
}

__global__ void k_dinv(const int* __restrict__ deg, float* __restrict__ dinv) {
    int i = blockIdx.x * 256 + threadIdx.x;
    if (i < NN) dinv[i] = 1.0f / sqrtf((float)deg[i]);
}

// ---------------- k_y1m: MFMA YT bf16 (dinv folded) ----------------
__global__ __launch_bounds__(256) void k_y1m(
    const float* __restrict__ x, const float* __restrict__ W1,
    const float* __restrict__ dinv, unsigned short* __restrict__ YT)
{
    __shared__ __align__(16) unsigned short Xs[128 * 64];
    __shared__ __align__(16) unsigned short Ws[128 * 64];
    const int tid = threadIdx.x;
    const int i0 = blockIdx.x * 128, b = blockIdx.y;

    const float* xg = x + ((size_t)(b * NN + i0)) * DIN;
    #pragma unroll
    for (int q = 0; q < 8; q++) {
        int idx = q * 256 + tid;
        int row = idx >> 4, c4 = idx & 15;
        f32x4 v = *(const f32x4*)(xg + (size_t)row * DIN + c4 * 4);
        s16x4 pk;
        #pragma unroll
        for (int e = 0; e < 4; e++) pk[e] = (short)f2bf(v[e]);
        int chunk = (c4 >> 1) ^ (row & 7);
        *(s16x4*)((char*)Xs + row * 128 + (chunk << 4) + (c4 & 1) * 8) = pk;
    }
    #pragma unroll
    for (int q = 0; q < 8; q++) {
        int idx = q * 256 + tid;
        int k = idx >> 5, f4 = (idx & 31) * 4;
        f32x4 v = ((const f32x4*)W1)[idx];
        #pragma unroll
        for (int e = 0; e < 4; e++) {
            int f = f4 + e;
            int chunk = (k >> 3) ^ (f & 7);
            *(unsigned short*)((char*)Ws + f * 128 + (chunk << 4) + (k & 7) * 2) = f2bf(v[e]);
        }
    }
    __syncthreads();

    const int lane = tid & 63, w = tid >> 6;
    const int wm = w >> 1, wn = w & 1;
    const int fr = lane & 15, kg = lane >> 4;
    f32x4 acc[4][4] = {};
    #pragma unroll
    for (int ks = 0; ks < 2; ks++) {
        int kc = ks * 4 + kg;
        s16x8 af[4], bf[4];
        #pragma unroll
        for (int mt = 0; mt < 4; mt++) {
            int row = wm * 64 + mt * 16 + fr;
            af[mt] = *(const s16x8*)((const char*)Xs + row * 128 + ((kc ^ (row & 7)) << 4));
        }
        #pragma unroll
        for (int nt = 0; nt < 4; nt++) {
            int f = wn * 64 + nt * 16 + fr;
            bf[nt] = *(const s16x8*)((const char*)Ws + f * 128 + ((kc ^ (f & 7)) << 4));
        }
        #pragma unroll
        for (int mt = 0; mt < 4; mt++)
            #pragma unroll
            for (int nt = 0; nt < 4; nt++)
                acc[mt][nt] = __builtin_amdgcn_mfma_f32_16x16x32_bf16(af[mt], bf[nt], acc[mt][nt], 0, 0, 0);
    }
    #pragma unroll
    for (int mt = 0; mt < 4; mt++) {
        int ibase = i0 + wm * 64 + mt * 16 + kg * 4;
        float dv[4];
        #pragma unroll
        for (int r = 0; r < 4; r++) dv[r] = dinv[ibase + r];
        #pragma unroll
        for (int nt = 0; nt < 4; nt++) {
            int f = wn * 64 + nt * 16 + fr;
            s16x4 pk;
            #pragma unroll
            for (int r = 0; r < 4; r++)
                pk[r] = (short)f2bf(acc[mt][nt][r] * dv[r]);
            *(s16x4*)(YT + (size_t)(b * DH + f) * NN + ibase) = pk;
        }
    }
}

// ---------------- self-scaling quantize: bf16 row -> i8 + smax[c] ----------------
__global__ __launch_bounds__(256) void k_quant(
    const unsigned short* __restrict__ src, unsigned int* __restrict__ smax,
    char* __restrict__ dst)
{
    __shared__ float wmax[4];
    const int c = blockIdx.x;
    const unsigned short* row = src + (size_t)c * NN;
    char* orow = dst + (size_t)c * NN;
    const int base = threadIdx.x * 16;
    float v[16];
    float m = 0.f;
    #pragma unroll
    for (int e = 0; e < 16; e++) {
        v[e] = bf2f(row[base + e]);
        m = fmaxf(m, fabsf(v[e]));
    }
    #pragma unroll
    for (int d = 32; d; d >>= 1) m = fmaxf(m, __shfl_xor(m, d));
    if ((threadIdx.x & 63) == 0) wmax[threadIdx.x >> 6] = m;
    __syncthreads();
    const float s = fmaxf(fmaxf(wmax[0], wmax[1]), fmaxf(wmax[2], wmax[3]));
    const float inv = s > 0.f ? 127.0f / s : 0.f;
    union { char c8[16]; i32x4 vv; } u;
    #pragma unroll
    for (int e = 0; e < 16; e++) {
        int q = (int)rintf(v[e] * inv);
        q = q > 127 ? 127 : (q < -127 ? -127 : q);
        u.c8[e] = (char)q;
    }
    *(i32x4*)(orow + base) = u.vv;
    if (threadIdx.x == 0) smax[c] = __float_as_uint(s);
}

// ---------------- self-scaling dual-plane quantize: bf16 row -> i8 hi+lo + smax[c] ----------------
__global__ __launch_bounds__(256) void k_quant2(
    const unsigned short* __restrict__ src, unsigned int* __restrict__ smax,
    char* __restrict__ dst)
{
    __shared__ float wmax[4];
    const int c = blockIdx.x;
    const unsigned short* row = src + (size_t)c * NN;
    char* ohi = dst + (size_t)c * NN;
    char* olo = dst + (size_t)(NB * DOUT + c) * NN;
    const int base = threadIdx.x * 16;
    float v[16];
    float m = 0.f;
    #pragma unroll
    for (int e = 0; e < 16; e++) {
        v[e] = bf2f(row[base + e]);
        m = fmaxf(m, fabsf(v[e]));
    }
    #pragma unroll
    for (int d = 32; d; d >>= 1) m = fmaxf(m, __shfl_xor(m, d));
    if ((threadIdx.x & 63) == 0) wmax[threadIdx.x >> 6] = m;
    __syncthreads();
    const float s = fmaxf(fmaxf(wmax[0], wmax[1]), fmaxf(wmax[2], wmax[3]));
    const float inv = s > 0.f ? 127.0f / s : 0.f;
    union { char c8[16]; i32x4 vv; } uh, ul;
    #pragma unroll
    for (int e = 0; e < 16; e++) {
        float t = v[e] * inv;
        int qh = (int)rintf(t);
        qh = qh > 127 ? 127 : (qh < -127 ? -127 : qh);
        float r = (t - (float)qh) * 127.0f;
        int ql = (int)rintf(r);
        ql = ql > 127 ? 127 : (ql < -127 ? -127 : ql);
        uh.c8[e] = (char)qh;
        ul.c8[e] = (char)ql;
    }
    *(i32x4*)(ohi + base) = uh.vv;
    *(i32x4*)(olo + base) = ul.vv;
    if (threadIdx.x == 0) smax[c] = __float_as_uint(s);
}

// ======== gemm1 (i8): 256x256, BK=128 i8, 8 waves; 8-phase quadrant schedule ========
__global__ __launch_bounds__(512, 2) void gemm8qi(
    const char* __restrict__ A, const char* __restrict__ Bt,
    unsigned short* __restrict__ H, const float* __restrict__ dinv,
    const unsigned int* __restrict__ smY, const float* __restrict__ bias)
{
    constexpr int KB = NN;         // 4096 bytes per row
    constexpr int NT = 32;         // K-tiles of 128 i8
    __shared__ __align__(16) char As[2][256 * 128];   // 32 KB each
    __shared__ __align__(16) char Bs[2][256 * 128];

    const int tid = threadIdx.x;
    const int lane = tid & 63;
    const int w = tid >> 6;
    const int wm = w >> 2, wn = w & 3;
    const int fr = lane & 15, kg = lane >> 4;

    const int bid = blockIdx.x;
    const int swz = (bid & 7) * 32 + (bid >> 3);
    const int bx = swz & 15, by = swz >> 4;
    const int c0 = bx * 256, j0 = by * 256;

    const char* Aj = A + (size_t)j0 * KB;
    const char* Bc = Bt + (size_t)c0 * KB;

    const int lr = tid >> 3, kcs = tid & 7;

#define STAGE_AQ(buf, q, kt) do { \
    int ra_ = (q) * 64 + lr; \
    int rb_ = ra_ + 128; \
    gload16(Aj + (size_t)ra_ * KB + (kt) + ((kcs ^ (ra_ & 7)) << 4), \
            &As[buf][(q) * 8192 + tid * 16]); \
    gload16(Aj + (size_t)rb_ * KB + (kt) + ((kcs ^ (rb_ & 7)) << 4), \
            &As[buf][(q) * 8192 + 16384 + tid * 16]); \
} while (0)
#define STAGE_BQ(buf, nh, kt) do { \
    int ca_ = tid, cb_ = tid + 512; \
    int r0_ = (ca_ >> 8) * 64 + (nh) * 32 + ((ca_ >> 3) & 31); \
    int r1_ = (cb_ >> 8) * 64 + (nh) * 32 + ((cb_ >> 3) & 31); \
    gload16(Bc + (size_t)r0_ * KB + (kt) + (((ca_ & 7) ^ (r0_ & 7)) << 4), \
            &Bs[buf][(ca_ >> 8) * 8192 + (nh) * 4096 + (ca_ & 255) * 16]); \
    gload16(Bc + (size_t)r1_ * KB + (kt) + (((cb_ & 7) ^ (r1_ & 7)) << 4), \
            &Bs[buf][(cb_ >> 8) * 8192 + (nh) * 4096 + (cb_ & 255) * 16]); \
} while (0)

    STAGE_AQ(0, 0, 0); STAGE_AQ(0, 1, 0);
    STAGE_BQ(0, 0, 0); STAGE_BQ(0, 1, 0);
    STAGE_BQ(1, 0, 128); STAGE_BQ(1, 1, 128);
    asm volatile("s_waitcnt vmcnt(4)" ::: "memory");
    bar();

    const int x0 = ((kg) ^ (fr & 7)) << 4;
    const int x1 = ((4 + kg) ^ (fr & 7)) << 4;
    int aOff[8], bOff[4];
    #pragma unroll
    for (int m = 0; m < 8; m++) aOff[m] = (wm * 128 + m * 16 + fr) * 128;
    #pragma unroll
    for (int n = 0; n < 4; n++) bOff[n] = (wn * 64 + n * 16 + fr) * 128;

    i32x4 acc[8][4] = {};
    const char* A0p = (const char*)As[0];
    const char* B0p = (const char*)Bs[0];
    const char* A1p = (const char*)As[1];
    const char* B1p = (const char*)Bs[1];

#define MFMA_Q(MB, NB_, AF0, AF1, BK0, BK1) do { \
    __builtin_amdgcn_s_setprio(1); \
    _Pragma("unroll") \
    for (int m = 0; m < 4; m++) { \
        _Pragma("unroll") \
        for (int n = 0; n < 2; n++) { \
            acc[(MB) + m][(NB_) + n] = __builtin_amdgcn_mfma_i32_16x16x64_i8( \
                AF0[m], BK0[n], acc[(MB) + m][(NB_) + n], 0, 0, 0); \
            acc[(MB) + m][(NB_) + n] = __builtin_amdgcn_mfma_i32_16x16x64_i8( \
                AF1[m], BK1[n], acc[(MB) + m][(NB_) + n], 0, 0, 0); \
        } \
    } \
    __builtin_amdgcn_s_setprio(0); \
} while (0)

    i32x4 af0[4], af1[4], b0k0[2], b0k1[2], b1k0[2], b1k1[2];

    for (int T = 0; T < NT; T += 2) {
        const bool s2 = (T + 2) < NT, s3 = (T + 3) < NT;
        const int kt1 = (T + 1) * 128, kt2 = (T + 2) * 128, kt3 = (T + 3) * 128;

        #pragma unroll
        for (int m = 0; m < 4; m++) { af0[m] = *(const i32x4*)(A0p + aOff[m] + x0);
                                      af1[m] = *(const i32x4*)(A0p + aOff[m] + x1); }
        #pragma unroll
        for (int n = 0; n < 2; n++) { b0k0[n] = *(const i32x4*)(B0p + bOff[n] + x0);
                                      b0k1[n] = *(const i32x4*)(B0p + bOff[n] + x1); }
        STAGE_AQ(1, 0, kt1);
        bar();
        MFMA_Q(0, 0, af0, af1, b0k0, b0k1);
        bar();

        #pragma unroll
        for (int n = 0; n < 2; n++) { b1k0[n] = *(const i32x4*)(B0p + bOff[n + 2] + x0);
                                      b1k1[n] = *(const i32x4*)(B0p + bOff[n + 2] + x1); }
        STAGE_AQ(1, 1, kt1);
        bar();
        MFMA_Q(0, 2, af0, af1, b1k0, b1k1);
        bar();

        #pragma unroll
        for (int m = 0; m < 4; m++) { af0[m] = *(const i32x4*)(A0p + aOff[m + 4] + x0);
                                      af1[m] = *(const i32x4*)(A0p + aOff[m + 4] + x1); }
        if (s2) STAGE_BQ(0, 0, kt2);
        bar();
        MFMA_Q(4, 0, af0, af1, b0k0, b0k1);
        bar();

        if (s2) { STAGE_BQ(0, 1, kt2);
                  asm volatile("s_waitcnt vmcnt(4)" ::: "memory"); }
        else    { asm volatile("s_waitcnt vmcnt(0)" ::: "memory"); }
        bar();
        MFMA_Q(4, 2, af0, af1, b1k0, b1k1);
        bar();

        #pragma unroll
        for (int m = 0; m < 4; m++) { af0[m] = *(const i32x4*)(A1p + aOff[m] + x0);
                                      af1[m] = *(const i32x4*)(A1p + aOff[m] + x1); }
        #pragma unroll
        for (int n = 0; n < 2; n++) { b0k0[n] = *(const i32x4*)(B1p + bOff[n] + x0);
                                      b0k1[n] = *(const i32x4*)(B1p + bOff[n] + x1); }
        if (s2) STAGE_AQ(0, 0, kt2);
        bar();
        MFMA_Q(0, 0, af0, af1, b0k0, b0k1);
        bar();

        #pragma unroll
        for (int n = 0; n < 2; n++) { b1k0[n] = *(const i32x4*)(B1p + bOff[n + 2] + x0);
                                      b1k1[n] = *(const i32x4*)(B1p + bOff[n + 2] + x1); }
        if (s2) STAGE_AQ(0, 1, kt2);
        bar();
        MFMA_Q(0, 2, af0, af1, b1k0, b1k1);
        bar();

        #pragma unroll
        for (int m = 0; m < 4; m++) { af0[m] = *(const i32x4*)(A1p + aOff[m + 4] + x0);
                                      af1[m] = *(const i32x4*)(A1p + aOff[m + 4] + x1); }
        if (s3) STAGE_BQ(1, 0, kt3);
        bar();
        MFMA_Q(4, 0, af0, af1, b0k0, b0k1);
        bar();

        if (s3) { STAGE_BQ(1, 1, kt3);
                  asm volatile("s_waitcnt vmcnt(4)" ::: "memory"); }
        else    { asm volatile("s_waitcnt vmcnt(0)" ::: "memory"); }
        bar();
        MFMA_Q(4, 2, af0, af1, b1k0, b1k1);
        bar();
    }
#undef MFMA_Q
#undef STAGE_AQ
#undef STAGE_BQ

    #pragma unroll
    for (int m = 0; m < 8; m++) {
        int rbase = j0 + wm * 128 + m * 16 + kg * 4;
        float dv[4];
        #pragma unroll
        for (int r = 0; r < 4; r++) dv[r] = dinv[rbase + r];
        #pragma unroll
        for (int n = 0; n < 4; n++) {
            int gcol = c0 + wn * 64 + n * 16 + fr;
            float bb = bias[gcol & (DH - 1)];
            float sc = __uint_as_float(smY[gcol]) * (1.0f / 127.0f);
            #pragma unroll
            for (int r = 0; r < 4; r++) {
                float v = (float)acc[m][n][r] * sc * dv[r] + bb;
                v = v > 0.f ? v : 0.f;
                H[(size_t)(rbase + r) * NN + gcol] = f2bf(v);
            }
        }
    }
}

// ---------- k_z2: MFMA-based ZT = dinv_j * (H_b @ W2) (bf16) ----------
__global__ __launch_bounds__(256) void k_z2(
    const unsigned short* __restrict__ H, const float* __restrict__ W2,
    const float* __restrict__ dinv, unsigned short* __restrict__ ZT)
{
    __shared__ __align__(16) unsigned short Hs[128 * DH];
    __shared__ __align__(16) unsigned short W2Ts[DOUT * DH];
    const int tid = threadIdx.x;
    const int j0 = blockIdx.x * 128, b = blockIdx.y;
    const unsigned short* Hb = H + (size_t)j0 * NN + b * DH;

    #pragma unroll
    for (int q = 0; q < 8; q++) {
        int cid = q * 256 + tid;
        int row = cid >> 4, kc = cid & 15;
        gload16(Hb + (size_t)row * NN + kc * 8, &Hs[cid * 8]);
    }
    #pragma unroll
    for (int q = 0; q < 16; q++) {
        int idx = q * 256 + tid;
        int f = idx >> 5, g = idx & 31;
        W2Ts[g * DH + f] = f2bf(W2[f * DOUT + g]);
    }
    __syncthreads();

    const int lane = tid & 63, w = tid >> 6;
    const int fr = lane & 15, kg = lane >> 4;
    f32x4 acc[2][2] = {};
    #pragma unroll
    for (int ks = 0; ks < 4; ks++) {
        s16x8 af[2], bf[2];
        #pragma unroll
        for (int mt = 0; mt < 2; mt++) {
            int row = w * 32 + mt * 16 + fr;
            af[mt] = *(const s16x8*)&Hs[row * DH + ks * 32 + kg * 8];
        }
        #pragma unroll
        for (int nt = 0; nt < 2; nt++) {
            int g = nt * 16 + fr;
            bf[nt] = *(const s16x8*)&W2Ts[g * DH + ks * 32 + kg * 8];
        }
        #pragma unroll
        for (int mt = 0; mt < 2; mt++)
            #pragma unroll
            for (int nt = 0; nt < 2; nt++)
                acc[mt][nt] = __builtin_amdgcn_mfma_f32_16x16x32_bf16(af[mt], bf[nt], acc[mt][nt], 0, 0, 0);
    }
    #pragma unroll
    for (int mt = 0; mt < 2; mt++) {
        int jbase = j0 + w * 32 + mt * 16 + kg * 4;
        float dv[4];
        #pragma unroll
        for (int r = 0; r < 4; r++) dv[r] = dinv[jbase + r];
        #pragma unroll
        for (int nt = 0; nt < 2; nt++) {
            int g = nt * 16 + fr;
            s16x4 pk;
            #pragma unroll
            for (int r = 0; r < 4; r++)
                pk[r] = (short)f2bf(acc[mt][nt][r] * dv[r]);
            *(s16x4*)(ZT + (size_t)(b * DOUT + g) * NN + jbase) = pk;
        }
    }
}

// ---------- gsm2d: gemm2 64x128 dual-plane i8, BK=128 (NT=32), fused softmax ----------
__global__ __launch_bounds__(256) void gsm2d(
    const char* __restrict__ Mi8, const char* __restrict__ Zq,
    float* __restrict__ out, const float* __restrict__ dinv,
    const unsigned int* __restrict__ smZ, const float* __restrict__ bias)
{
    constexpr int KB = NN;         // bytes per row
    constexpr int NT = 32;         // K-tiles of 128 bytes
    __shared__ __align__(16) char Asm[2][64 * 128];    // 2 x 8 KB
    __shared__ __align__(16) char Bhi[2][128 * 128];   // 2 x 16 KB
    __shared__ __align__(16) char Blo[2][128 * 128];   // 2 x 16 KB  (total 80 KB)
    const int tid = threadIdx.x;
    const int lane = tid & 63;
    const int w = tid >> 6;
    const int wm = w >> 1, wn = w & 1;     // 2 x 2 waves; per-wave 32 x 64
    const int c0 = blockIdx.x * 128;
    const int j0 = blockIdx.y * 64;
    const int fr = lane & 15, kg = lane >> 4;

    int srcA[2], srcB[4];
    #pragma unroll
    for (int q = 0; q < 2; q++) {
        int cid = q * 256 + tid;
        int row = cid >> 3, kc = cid & 7;
        srcA[q] = row * KB + ((kc ^ (row & 7)) << 4);
    }
    #pragma unroll
    for (int q = 0; q < 4; q++) {
        int cid = q * 256 + tid;
        int row = cid >> 3, kc = cid & 7;
        srcB[q] = row * KB + ((kc ^ (row & 7)) << 4);
    }
    const char* Abase = Mi8 + (size_t)j0 * KB;
    const char* Bh = Zq + (size_t)c0 * KB;
    const char* Bl = Zq + (size_t)(NB * DOUT + c0) * KB;

#define STAGE_T(buf, kt) do { \
    _Pragma("unroll") \
    for (int q = 0; q < 2; q++) \
        gload16(Abase + (kt) + srcA[q], &Asm[buf][(q * 256 + tid) * 16]); \
    _Pragma("unroll") \
    for (int q = 0; q < 4; q++) \
        gload16(Bh + (kt) + srcB[q], &Bhi[buf][(q * 256 + tid) * 16]); \
    _Pragma("unroll") \
    for (int q = 0; q < 4; q++) \
        gload16(Bl + (kt) + srcB[q], &Blo[buf][(q * 256 + tid) * 16]); } while (0)

    STAGE_T(0, 0);
    STAGE_T(1, 128);
    asm volatile("s_waitcnt vmcnt(10)" ::: "memory");
    bar();

    const int x0 = (kg ^ (fr & 7)) << 4;
    const int x1 = ((4 + kg) ^ (fr & 7)) << 4;
    int aOff[2], bOff[4];
    #pragma unroll
    for (int m = 0; m < 2; m++) aOff[m] = (wm * 32 + m * 16 + fr) * 128;
    #pragma unroll
    for (int n = 0; n < 4; n++) bOff[n] = (wn * 64 + n * 16 + fr) * 128;

    i32x4 afc[2][2], bhc[2][4], blc[2][4];
    #pragma unroll
    for (int ks = 0; ks < 2; ks++) {
        int xk = ks ? x1 : x0;
        #pragma unroll
        for (int m = 0; m < 2; m++) afc[ks][m] = *(const i32x4*)((const char*)Asm[0] + aOff[m] + xk);
        #pragma unroll
        for (int n = 0; n < 4; n++) {
            bhc[ks][n] = *(const i32x4*)((const char*)Bhi[0] + bOff[n] + xk);
            blc[ks][n] = *(const i32x4*)((const char*)Blo[0] + bOff[n] + xk);
        }
    }
    asm volatile("s_waitcnt lgkmcnt(0)" ::: "memory");
    bar();

    i32x4 ah[2][4] = {};
    i32x4 al[2][4] = {};

    for (int t = 0; t < NT; t++) {
        const int P = t & 1;
        const bool s1 = (t + 1) < NT, s2 = (t + 2) < NT;

        if (s2) STAGE_T(P, (t + 2) * 128);
        __builtin_amdgcn_s_setprio(1);
        #pragma unroll
        for (int m = 0; m < 2; m++)
            #pragma unroll
            for (int n = 0; n < 4; n++) {
                ah[m][n] = __builtin_amdgcn_mfma_i32_16x16x64_i8(afc[0][m], bhc[0][n], ah[m][n], 0, 0, 0);
                al[m][n] = __builtin_amdgcn_mfma_i32_16x16x64_i8(afc[0][m], blc[0][n], al[m][n], 0, 0, 0);
            }
        __builtin_amdgcn_s_setprio(0);
        if (s2) asm volatile("s_waitcnt vmcnt(10)" ::: "memory");
        else    asm volatile("s_waitcnt vmcnt(0)" ::: "memory");
        bar();

        i32x4 afn[2][2], bhn[2][4], bln[2][4];
        if (s1) {
            const char* Aq = (const char*)Asm[P ^ 1];
            const char* Bhq = (const char*)Bhi[P ^ 1];
            const char* Blq = (const char*)Blo[P ^ 1];
            #pragma unroll
            for (int ks = 0; ks < 2; ks++) {
                int xk = ks ? x1 : x0;
                #pragma unroll
                for (int m = 0; m < 2; m++) afn[ks][m] = *(const i32x4*)(Aq + aOff[m] + xk);
                #pragma unroll
                for (int n = 0; n < 4; n++) {
                    bhn[ks][n] = *(const i32x4*)(Bhq + bOff[n] + xk);
                    bln[ks][n] = *(const i32x4*)(Blq + bOff[n] + xk);
                }
            }
        }
        __builtin_amdgcn_s_setprio(1);
        #pragma unroll
        for (int m = 0; m < 2; m++)
            #pragma unroll
            for (int n = 0; n < 4; n++) {
                ah[m][n] = __builtin_amdgcn_mfma_i32_16x16x64_i8(afc[1][m], bhc[1][n], ah[m][n], 0, 0, 0);
                al[m][n] = __builtin_amdgcn_mfma_i32_16x16x64_i8(afc[1][m], blc[1][n], al[m][n], 0, 0, 0);
            }
        __builtin_amdgcn_s_setprio(0);
        asm volatile("s_waitcnt lgkmcnt(0)" ::: "memory");
        bar();
        if (s1) {
            #pragma unroll
            for (int ks = 0; ks < 2; ks++) {
                #pragma unroll
                for (int m = 0; m < 2; m++) afc[ks][m] = afn[ks][m];
                #pragma unroll
                for (int n = 0; n < 4; n++) { bhc[ks][n] = bhn[ks][n]; blc[ks][n] = bln[ks][n]; }
            }
        }
    }
#undef STAGE_T

    const float b_lo = bias[fr], b_hi = bias[fr + 16];
    #pragma unroll
    for (int m = 0; m < 2; m++) {
        int rbase = j0 + wm * 32 + m * 16 + kg * 4;
        float dv[4];
        #pragma unroll
        for (int r = 0; r < 4; r++) dv[r] = dinv[rbase + r];
        #pragma unroll
        for (int np = 0; np < 2; np++) {
            int bg = (c0 >> 5) + wn * 2 + np;
            float sc0 = __uint_as_float(smZ[c0 + wn * 64 + np * 32 + fr])      * (1.0f / 127.0f);
            float sc1 = __uint_as_float(smZ[c0 + wn * 64 + np * 32 + fr + 16]) * (1.0f / 127.0f);
            #pragma unroll
            for (int r = 0; r < 4; r++) {
                int row = rbase + r;
                float v0 = ((float)ah[m][np * 2][r]     + (float)al[m][np * 2][r]     * (1.0f / 127.0f)) * sc0 * dv[r] + b_lo;
                float v1 = ((float)ah[m][np * 2 + 1][r] + (float)al[m][np * 2 + 1][r] * (1.0f / 127.0f)) * sc1 * dv[r] + b_hi;
                float mx = fmaxf(v0, v1);
                #pragma unroll
                for (int d = 8; d; d >>= 1) mx = fmaxf(mx, __shfl_xor(mx, d));
                float e0 = expf(v0 - mx), e1 = expf(v1 - mx);
                float s = e0 + e1;
                #pragma unroll
                for (int d = 8; d; d >>= 1) s += __shfl_xor(s, d);
                float inv = 1.0f / s;
                size_t ob = ((size_t)bg * NN + row) * DOUT;
                out[ob + fr]      = e0 * inv;
                out[ob + fr + 16] = e1 * inv;
            }
        }
    }
}

extern "C" void kernel_launch(void* const* d_in, const int* in_sizes, int n_in,
                              void* d_out, int out_size, void* d_ws, size_t ws_size,
                              hipStream_t stream)
{
    (void)in_sizes; (void)n_in; (void)out_size; (void)ws_size;
    const float* x    = (const float*)d_in[0];
    const float* emb1 = (const float*)d_in[1];
    const float* emb2 = (const float*)d_in[2];
    const float* l1w  = (const float*)d_in[3];
    const float* l1b  = (const float*)d_in[4];
    const float* l2w  = (const float*)d_in[5];
    const float* l2b  = (const float*)d_in[6];
    const float* g1w  = (const float*)d_in[7];
    const float* g1b  = (const float*)d_in[8];
    const float* g2w  = (const float*)d_in[9];
    const float* g2b  = (const float*)d_in[10];
    float* out = (float*)d_out;

    char* w = (char*)d_ws;
    int* deg = (int*)w;                       w += NN * 4;
    float* dinv = (float*)w;                  w += NN * 4;
    unsigned int* smY = (unsigned int*)w;     w += NN * 4;
    unsigned int* smZ = (unsigned int*)w;     w += NB * DOUT * 4;
    char* Mi8 = (char*)w;                     w += (size_t)NN * NN;
    unsigned short* YT = (unsigned short*)w;  w += (size_t)NN * NN * 2;
    char* Yq = (char*)w;                      w += (size_t)NN * NN;
    unsigned short* H  = (unsigned short*)w;  w += (size_t)NN * NN * 2;
    unsigned short* ZT = (unsigned short*)w;  w += (size_t)(NB * DOUT) * NN * 2;
    // Ux/Vx live in YT's region (dead until k_y1m); ZTq2 (8MB) lives in Yq's
    // region (Yq dead after gemm8qi; k_quant2/gsm2d run after it).
    unsigned short* Ux = YT;
    unsigned short* Vx = YT + (size_t)NN * KADJ;
    char* ZTq2 = Yq;

    k_embuv<<<256, 256, 0, stream>>>(emb1, emb2, l1w, l1b, l2w, l2b, Ux, Vx, deg);
    gemm_adj8<<<256, 512, 0, stream>>>(Vx, Ux, Mi8, deg);
    k_dinv<<<16, 256, 0, stream>>>(deg, dinv);
    k_y1m<<<dim3(32, 32), 256, 0, stream>>>(x, g1w, dinv, YT);
    k_quant<<<NN, 256, 0, stream>>>(YT, smY, Yq);
    gemm8qi<<<256, 512, 0, stream>>>(Mi8, Yq, H, dinv, smY, g1b);
    k_z2<<<dim3(32, 32), 256, 0, stream>>>(H, g2w, dinv, ZT);
    k_quant2<<<NB * DOUT, 256, 0, stream>>>(ZT, smZ, ZTq2);
    gsm2d<<<dim3(8, 64), 256, 0, stream>>>(Mi8, ZTq2, out, dinv, smZ, g2b);
}